// Round 1
// baseline (3363.661 us; speedup 1.0000x reference)
//
#include <hip/hip_runtime.h>
#include <math.h>

#define NPT 2048
#define CH 64
constexpr int TDEG = 18;   // Taylor degree for exp(L/16)

// ---------------------------------------------------------------- geometry ---
__global__ __launch_bounds__(256) void pg_row_geom(
    const float* __restrict__ pos, const float* __restrict__ adj,
    float* __restrict__ raw, float* __restrict__ Hc,
    float* __restrict__ sumA, float* __restrict__ sumAD)
{
  __shared__ float sp[NPT * 3];
  __shared__ float red[256 * 6];
  int i = blockIdx.x, t = threadIdx.x;
  for (int j = t; j < NPT * 3; j += 256) sp[j] = pos[j];
  __syncthreads();
  float px = sp[3 * i], py = sp[3 * i + 1], pz = sp[3 * i + 2];
  float s0 = 0, s1 = 0, s2 = 0, ax = 0, ay = 0, az = 0;
  for (int j = t; j < NPT; j += 256) {
    float a = adj[(size_t)i * NPT + j];
    if (a != 0.0f) {
      float dx = sp[3 * j] - px, dy = sp[3 * j + 1] - py, dz = sp[3 * j + 2] - pz;
      float d2 = dx * dx + dy * dy + dz * dz + 1e-12f;
      float d = sqrtf(d2);
      s0 += a; s1 += a * d; s2 += a * d2;
      ax += a * sp[3 * j]; ay += a * sp[3 * j + 1]; az += a * sp[3 * j + 2];
    }
  }
  red[t * 6 + 0] = s0; red[t * 6 + 1] = s1; red[t * 6 + 2] = s2;
  red[t * 6 + 3] = ax; red[t * 6 + 4] = ay; red[t * 6 + 5] = az;
  __syncthreads();
  for (int s = 128; s > 0; s >>= 1) {
    if (t < s)
      for (int q = 0; q < 6; q++) red[t * 6 + q] += red[(t + s) * 6 + q];
    __syncthreads();
  }
  if (t == 0) {
    s0 = red[0]; s1 = red[1]; s2 = red[2]; ax = red[3]; ay = red[4]; az = red[5];
    float degc = fmaxf(s0, 1.0f);
    float dxm = ax / degc - px, dym = ay / degc - py, dzm = az / degc - pz;
    float H = 0.5f * sqrtf(dxm * dxm + dym * dym + dzm * dzm);
    float r = s1 / degc;
    float var = (s2 - 2.0f * r * s1 + r * r * s0) / degc;
    float sdev = sqrtf(var + 1e-12f);
    float k1 = H + sdev, k2 = H - sdev;
    raw[i * 6 + 0] = H;
    raw[i * 6 + 1] = k1 * k2;
    raw[i * 6 + 2] = k1;
    raw[i * 6 + 3] = k2;
    raw[i * 6 + 4] = 0.6366197723675814f * atanf((k1 + k2) / (k1 - k2 + 1e-6f));
    raw[i * 6 + 5] = sqrtf(0.5f * (k1 * k1 + k2 * k2));
    Hc[i] = H;
    sumA[i] = s0; sumAD[i] = s1;
  }
}

__global__ __launch_bounds__(256) void pg_build_csr(
    const float* __restrict__ adj, int* __restrict__ nbr, int* __restrict__ cnt)
{
  __shared__ int cs[256];
  __shared__ int offs[257];
  int i = blockIdx.x, t = threadIdx.x;
  size_t base = (size_t)i * NPT + t * 8;
  float av[8];
  int c = 0;
  for (int u = 0; u < 8; u++) { av[u] = adj[base + u]; c += (av[u] != 0.0f); }
  cs[t] = c;
  __syncthreads();
  if (t == 0) {
    offs[0] = 0;
    for (int q = 0; q < 256; q++) offs[q + 1] = offs[q] + cs[q];
  }
  __syncthreads();
  int o = offs[t], w = 0;
  for (int u = 0; u < 8; u++)
    if (av[u] != 0.0f) { int p = o + w; if (p < 64) nbr[i * 64 + p] = t * 8 + u; w++; }
  if (t == 0) cnt[i] = min(offs[256], 64);
}

__global__ __launch_bounds__(256) void pg_stats(
    const float* __restrict__ raw, const float* __restrict__ sumA,
    const float* __restrict__ sumAD, float* __restrict__ stats)
{
  __shared__ float red[256];
  __shared__ float mean6[6];
  int t = threadIdx.x;
  float sa = 0, sad = 0;
  for (int j = t; j < NPT; j += 256) { sa += sumA[j]; sad += sumAD[j]; }
  red[t] = sa; __syncthreads();
  for (int s = 128; s > 0; s >>= 1) { if (t < s) red[t] += red[t + s]; __syncthreads(); }
  float totA = red[0]; __syncthreads();
  red[t] = sad; __syncthreads();
  for (int s = 128; s > 0; s >>= 1) { if (t < s) red[t] += red[t + s]; __syncthreads(); }
  float totAD = red[0]; __syncthreads();
  if (t == 0) {
    float sigma = fmaxf(totAD / fmaxf(totA, 1.0f), 1e-6f);
    stats[0] = 1.0f / (2.0f * sigma * sigma);
    stats[1] = sigma;
  }
  for (int q = 0; q < 6; q++) {
    float s = 0;
    for (int j = t; j < NPT; j += 256) s += raw[j * 6 + q];
    red[t] = s; __syncthreads();
    for (int k = 128; k > 0; k >>= 1) { if (t < k) red[t] += red[t + k]; __syncthreads(); }
    if (t == 0) mean6[q] = red[0] / (float)NPT;
    __syncthreads();
  }
  for (int q = 0; q < 6; q++) {
    float m = mean6[q], s = 0;
    for (int j = t; j < NPT; j += 256) { float d = raw[j * 6 + q] - m; s += d * d; }
    red[t] = s; __syncthreads();
    for (int k = 128; k > 0; k >>= 1) { if (t < k) red[t] += red[t + k]; __syncthreads(); }
    if (t == 0) {
      float sd = sqrtf(red[0] / (float)(NPT - 1));
      stats[2 + q] = m;
      stats[8 + q] = 1.0f / fmaxf(sd, 1e-6f);
    }
    __syncthreads();
  }
}

__global__ __launch_bounds__(64) void pg_wdeg(
    const float* __restrict__ pos, const int* __restrict__ nbr, const int* __restrict__ cnt,
    const float* __restrict__ stats, float* __restrict__ nbrw, float* __restrict__ wdeg,
    float* __restrict__ invdeg, float* __restrict__ Dis, float* __restrict__ cvec)
{
  int i = blockIdx.x, t = threadIdx.x;
  int n = cnt[i];
  float inv2s2 = stats[0];
  float px = pos[3 * i], py = pos[3 * i + 1], pz = pos[3 * i + 2];
  float w = 0.0f;
  if (t < n) {
    int j = nbr[i * 64 + t];
    float dx = pos[3 * j] - px, dy = pos[3 * j + 1] - py, dz = pos[3 * j + 2] - pz;
    float d2 = dx * dx + dy * dy + dz * dz + 1e-12f;
    w = expf(-d2 * inv2s2);
    nbrw[i * 64 + t] = w;
  }
  float s = w;
  for (int off = 1; off < 64; off <<= 1) s += __shfl_xor(s, off);
  if (t == 0) {
    float md = fmaxf(s, 1e-8f);
    wdeg[i] = s;
    invdeg[i] = 1.0f / md;
    float di = 1.0f / sqrtf(md);
    Dis[i] = di;
    cvec[i] = di * di * s;
  }
}

__global__ __launch_bounds__(64) void pg_curv_mlp(
    const float* __restrict__ pos, const float* __restrict__ raw, const float* __restrict__ stats,
    const float* __restrict__ Wc1, const float* __restrict__ bc1,
    const float* __restrict__ Wc2, const float* __restrict__ bc2,
    const float* __restrict__ Win, const float* __restrict__ b_in, float* __restrict__ h)
{
  __shared__ float feat[19];
  __shared__ float nraw[6];
  __shared__ float hid[32];
  int i = blockIdx.x, t = threadIdx.x;
  if (t < 3) feat[t] = pos[3 * i + t];
  if (t < 6) nraw[t] = (raw[i * 6 + t] - stats[2 + t]) * stats[8 + t];
  __syncthreads();
  if (t < 32) {
    float a = bc1[t];
    for (int k = 0; k < 6; k++) a += nraw[k] * Wc1[k * 32 + t];
    hid[t] = a / (1.0f + expf(-a));
  }
  __syncthreads();
  if (t < 16) {
    float a = bc2[t];
    for (int k = 0; k < 32; k++) a += hid[k] * Wc2[k * 16 + t];
    feat[3 + t] = a;
  }
  __syncthreads();
  float a = b_in[t];
  for (int k = 0; k < 19; k++) a += feat[k] * Win[k * CH + t];
  h[i * CH + t] = a;
}

// ----------------------------------------------------------------- expm(tL) ---
__global__ __launch_bounds__(256) void pg_taylor_init(
    const int* __restrict__ nbr, const int* __restrict__ cnt,
    const float* __restrict__ nbrw, const float* __restrict__ wdeg, float* __restrict__ Y)
{
  int i = blockIdx.x, t = threadIdx.x;
  size_t ro = (size_t)i * NPT;
  const float c0 = 1.0f / (16.0f * (float)TDEG);
  for (int j = t; j < NPT; j += 256) Y[ro + j] = 0.0f;
  __syncthreads();
  int n = cnt[i];
  if (t < n) Y[ro + nbr[i * 64 + t]] = nbrw[i * 64 + t] * c0;
  if (t == 0) Y[ro + i] = 1.0f - wdeg[i] * c0;
}

__global__ __launch_bounds__(256) void pg_horner(
    const int* __restrict__ nbr, const int* __restrict__ cnt,
    const float* __restrict__ nbrw, const float* __restrict__ wdeg,
    const float* __restrict__ Yin, float* __restrict__ Yout, float invc)
{
  __shared__ int snb[64];
  __shared__ float swt[64];
  int i = blockIdx.x, t = threadIdx.x;
  if (t < 64) { snb[t] = nbr[i * 64 + t]; swt[t] = nbrw[i * 64 + t]; }
  __syncthreads();
  int n = cnt[i];
  float wd = wdeg[i];
  size_t ro = (size_t)i * NPT;
  for (int c = t; c < NPT; c += 256) {
    float acc = -wd * Yin[ro + c];
    for (int q = 0; q < n; q++) acc += swt[q] * Yin[(size_t)snb[q] * NPT + c];
    Yout[ro + c] = ((c == i) ? 1.0f : 0.0f) + acc * invc;
  }
}

__global__ __launch_bounds__(256) void pg_sgemm(
    const float* __restrict__ A, const float* __restrict__ B, float* __restrict__ Cm)
{
  __shared__ float As[8][128];
  __shared__ float Bs[8][128];
  int tid = threadIdx.x;
  int bx = blockIdx.x, by = blockIdx.y;
  int tx = tid & 15, ty = tid >> 4;
  int arow = tid >> 1, acol = (tid & 1) * 4;
  int brow = tid >> 5, bcol = (tid & 31) * 4;
  const float* Ap = A + (size_t)(by * 128 + arow) * NPT + acol;
  const float* Bp = B + (size_t)brow * NPT + bx * 128 + bcol;
  float acc[8][8];
#pragma unroll
  for (int a = 0; a < 8; a++)
#pragma unroll
    for (int b = 0; b < 8; b++) acc[a][b] = 0.0f;
  for (int k0 = 0; k0 < NPT; k0 += 8) {
    float4 av = *(const float4*)(Ap + k0);
    float4 bv = *(const float4*)(Bp + (size_t)k0 * NPT);
    As[acol + 0][arow] = av.x; As[acol + 1][arow] = av.y;
    As[acol + 2][arow] = av.z; As[acol + 3][arow] = av.w;
    *(float4*)(&Bs[brow][bcol]) = bv;
    __syncthreads();
#pragma unroll
    for (int kk = 0; kk < 8; kk++) {
      float a0[8], b0[8];
      *(float4*)(a0) = *(const float4*)(&As[kk][ty * 8]);
      *(float4*)(a0 + 4) = *(const float4*)(&As[kk][ty * 8 + 4]);
      *(float4*)(b0) = *(const float4*)(&Bs[kk][tx * 8]);
      *(float4*)(b0 + 4) = *(const float4*)(&Bs[kk][tx * 8 + 4]);
#pragma unroll
      for (int um = 0; um < 8; um++)
#pragma unroll
        for (int un = 0; un < 8; un++) acc[um][un] += a0[um] * b0[un];
    }
    __syncthreads();
  }
  for (int um = 0; um < 8; um++) {
    float* cp = Cm + (size_t)(by * 128 + ty * 8 + um) * NPT + bx * 128 + tx * 8;
    float4 c0 = {acc[um][0], acc[um][1], acc[um][2], acc[um][3]};
    float4 c1 = {acc[um][4], acc[um][5], acc[um][6], acc[um][7]};
    *(float4*)cp = c0;
    *(float4*)(cp + 4) = c1;
  }
}

// E(2048x2048) @ X(2048x64): 8 rows per 512-thread block
__global__ __launch_bounds__(512) void pg_eapply(
    const float* __restrict__ E, const float* __restrict__ X, float* __restrict__ Y)
{
  int t = threadIdx.x;
  int r = t >> 6, c = t & 63;
  int i = blockIdx.x * 8 + r;
  const float* Er = E + (size_t)i * NPT;
  float acc = 0.0f;
  for (int j = 0; j < NPT; j += 4) {
    float4 e = *(const float4*)(Er + j);
    acc += e.x * X[(j + 0) * CH + c] + e.y * X[(j + 1) * CH + c]
         + e.z * X[(j + 2) * CH + c] + e.w * X[(j + 3) * CH + c];
  }
  Y[i * CH + c] = acc;
}

// ------------------------------------------------------------------- layers ---
__global__ __launch_bounds__(64) void pg_csrP(
    const int* __restrict__ nbr, const int* __restrict__ cnt, const float* __restrict__ nbrw,
    const float* __restrict__ invdeg, const float* __restrict__ h, float* __restrict__ out)
{
  __shared__ int snb[64];
  __shared__ float swt[64];
  int i = blockIdx.x, t = threadIdx.x;
  snb[t] = nbr[i * 64 + t];
  swt[t] = nbrw[i * 64 + t];
  __syncthreads();
  int n = cnt[i];
  float acc = 0.0f;
  for (int q = 0; q < n; q++) acc += swt[q] * h[snb[q] * CH + t];
  out[i * CH + t] = acc * invdeg[i];
}

__global__ __launch_bounds__(64) void pg_csrL(
    const int* __restrict__ nbr, const int* __restrict__ cnt, const float* __restrict__ nbrw,
    const float* __restrict__ Dis, const float* __restrict__ cvec,
    const float* __restrict__ h, float* __restrict__ out)
{
  __shared__ int snb[64];
  __shared__ float swt[64];
  int i = blockIdx.x, t = threadIdx.x;
  int n = cnt[i];
  int j = (t < n) ? nbr[i * 64 + t] : 0;
  snb[t] = j;
  swt[t] = (t < n) ? nbrw[i * 64 + t] * Dis[j] : 0.0f;
  __syncthreads();
  float acc = 0.0f;
  for (int q = 0; q < n; q++) acc += swt[q] * h[snb[q] * CH + t];
  out[i * CH + t] = acc * Dis[i] - cvec[i] * h[i * CH + t];
}

__global__ __launch_bounds__(64) void pg_conv(
    const float* __restrict__ h, const float* __restrict__ ph,
    const float* __restrict__ Ws, const float* __restrict__ bs,
    const float* __restrict__ Wn, const float* __restrict__ bn,
    const float* __restrict__ cres, float* __restrict__ out)
{
  __shared__ float sh[64], sp2[64];
  int i = blockIdx.x, t = threadIdx.x;
  sh[t] = h[i * CH + t];
  sp2[t] = ph[i * CH + t];
  __syncthreads();
  float a = bs[t] + bn[t] + 0.1f * cres[0] * sh[t];
  for (int k = 0; k < 64; k++) a += sh[k] * Ws[k * CH + t] + sp2[k] * Wn[k * CH + t];
  out[i * CH + t] = a / (1.0f + expf(-a));
}

__global__ __launch_bounds__(64) void pg_difffuse(
    const float* __restrict__ h2, const float* __restrict__ hd,
    const float* __restrict__ dW, const float* __restrict__ db, float* __restrict__ out)
{
  __shared__ float sh[3][64];
  int i = blockIdx.x, t = threadIdx.x;
  for (int s = 0; s < 3; s++) sh[s][t] = hd[(size_t)s * NPT * CH + i * CH + t];
  __syncthreads();
  float a = h2[i * CH + t] + db[t];
  for (int s = 0; s < 3; s++) {
    const float* w = dW + s * CH * CH;
    for (int k = 0; k < 64; k++) a += sh[s][k] * w[k * CH + t];
  }
  out[i * CH + t] = a;
}

__global__ __launch_bounds__(64) void pg_tanhmm(
    const float* __restrict__ h, const float* __restrict__ W1,
    const float* __restrict__ b1, float* __restrict__ out)
{
  __shared__ float sh[64];
  int i = blockIdx.x, t = threadIdx.x;
  sh[t] = h[i * CH + t];
  __syncthreads();
  float a = b1[t];
  for (int k = 0; k < 64; k++) a += sh[k] * W1[k * CH + t];
  out[i * CH + t] = tanhf(a);
}

__global__ __launch_bounds__(64) void pg_rdln(
    const float* __restrict__ h3, const float* __restrict__ tT, const float* __restrict__ tL,
    const float* __restrict__ rdc, const float* __restrict__ W2, const float* __restrict__ b2,
    const float* __restrict__ g, const float* __restrict__ b, float* __restrict__ hio)
{
  __shared__ float st[64];
  int i = blockIdx.x, t = threadIdx.x;
  st[t] = tT[i * CH + t];
  __syncthreads();
  float react = b2[t];
  for (int k = 0; k < 64; k++) react += st[k] * W2[k * CH + t];
  float x = h3[i * CH + t] + 0.1f * (rdc[t] * tL[i * CH + t] + react) + hio[i * CH + t];
  float s = x;
  for (int off = 1; off < 64; off <<= 1) s += __shfl_xor(s, off);
  float mu = s * (1.0f / 64.0f);
  float d = x - mu;
  float v = d * d;
  for (int off = 1; off < 64; off <<= 1) v += __shfl_xor(v, off);
  v *= (1.0f / 64.0f);
  hio[i * CH + t] = d * (1.0f / sqrtf(v + 1e-5f)) * g[t] + b[t];
}

// ---------------------------------------------------------------- attention ---
__global__ __launch_bounds__(64) void pg_qkv(
    const float* __restrict__ h,
    const float* __restrict__ Wq, const float* __restrict__ bq,
    const float* __restrict__ Wk, const float* __restrict__ bk,
    const float* __restrict__ Wv, const float* __restrict__ bv,
    float* __restrict__ q, float* __restrict__ kb, float* __restrict__ vb)
{
  __shared__ float sh[64];
  int i = blockIdx.x, t = threadIdx.x;
  sh[t] = h[i * CH + t];
  __syncthreads();
  float aq = bq[t], ak = bk[t], avv = bv[t];
  for (int k = 0; k < 64; k++) {
    float x = sh[k];
    aq += x * Wq[k * CH + t];
    ak += x * Wk[k * CH + t];
    avv += x * Wv[k * CH + t];
  }
  q[i * CH + t] = aq;
  kb[i * CH + t] = ak;
  vb[i * CH + t] = avv;
}

__global__ __launch_bounds__(256) void pg_attn(
    const float* __restrict__ q, const float* __restrict__ kb, const float* __restrict__ vb,
    const float* __restrict__ adj, const float* __restrict__ Hc,
    const float* __restrict__ beta, float* __restrict__ av)
{
  int i = blockIdx.x;
  int t = threadIdx.x;
  int head = t >> 6, lane = t & 63;
  float sp_b = logf(1.0f + expf(beta[head]));
  float hci = Hc[i];
  const float* qp = q + i * CH + head * 16;
  float qr[16];
#pragma unroll
  for (int d = 0; d < 16; d++) qr[d] = qp[d];
  float mx = -1e30f, den = 0.0f;
  float vac[16];
#pragma unroll
  for (int d = 0; d < 16; d++) vac[d] = 0.0f;
  for (int m = lane; m < NPT; m += 64) {
    float a = adj[(size_t)i * NPT + m];
    if (a != 0.0f || m == i) {
      const float* kp = kb + m * CH + head * 16;
      float sc = 0.0f;
#pragma unroll
      for (int d = 0; d < 16; d++) sc += qr[d] * kp[d];
      sc *= 0.25f;
      sc -= sp_b * fabsf(hci - Hc[m]);
      float nm = fmaxf(mx, sc);
      float corr = expf(mx - nm);
      float p = expf(sc - nm);
      den = den * corr + p;
      const float* vp = vb + m * CH + head * 16;
#pragma unroll
      for (int d = 0; d < 16; d++) vac[d] = vac[d] * corr + p * vp[d];
      mx = nm;
    }
  }
  for (int off = 32; off > 0; off >>= 1) {
    float omx = __shfl_down(mx, off);
    float oden = __shfl_down(den, off);
    float ov[16];
#pragma unroll
    for (int d = 0; d < 16; d++) ov[d] = __shfl_down(vac[d], off);
    float nm = fmaxf(mx, omx);
    float c1 = expf(mx - nm), c2 = expf(omx - nm);
    den = den * c1 + oden * c2;
#pragma unroll
    for (int d = 0; d < 16; d++) vac[d] = vac[d] * c1 + ov[d] * c2;
    mx = nm;
  }
  if (lane == 0) {
    float inv = 1.0f / den;
    float* o = av + i * CH + head * 16;
    for (int d = 0; d < 16; d++) o[d] = vac[d] * inv;
  }
}

__global__ __launch_bounds__(64) void pg_out(
    const float* __restrict__ h, const float* __restrict__ av,
    const float* __restrict__ Wo, const float* __restrict__ bo,
    const float* __restrict__ Wout, const float* __restrict__ bout, float* __restrict__ out)
{
  __shared__ float sa[64];
  int i = blockIdx.x, t = threadIdx.x;
  sa[t] = av[i * CH + t];
  __syncthreads();
  float a = h[i * CH + t] + bo[t];
  for (int k = 0; k < 64; k++) a += sa[k] * Wo[k * CH + t];
  float s = a * Wout[t];
  for (int off = 1; off < 64; off <<= 1) s += __shfl_xor(s, off);
  if (t == 0) out[i] = s + bout[0];
}

// ------------------------------------------------------------------- launch ---
extern "C" void kernel_launch(void* const* d_in, const int* in_sizes, int n_in,
                              void* d_out, int out_size, void* d_ws, size_t ws_size,
                              hipStream_t stream)
{
  const float* pos   = (const float*)d_in[0];
  const float* adj   = (const float*)d_in[1];
  const float* Wc1   = (const float*)d_in[2];
  const float* bc1   = (const float*)d_in[3];
  const float* Wc2   = (const float*)d_in[4];
  const float* bc2   = (const float*)d_in[5];
  const float* Win   = (const float*)d_in[6];
  const float* b_in  = (const float*)d_in[7];
  const float* cWs   = (const float*)d_in[8];
  const float* cbs   = (const float*)d_in[9];
  const float* cWn   = (const float*)d_in[10];
  const float* cbn   = (const float*)d_in[11];
  const float* cres  = (const float*)d_in[12];
  const float* dW    = (const float*)d_in[13];
  const float* db    = (const float*)d_in[14];
  const float* rW1   = (const float*)d_in[15];
  const float* rb1   = (const float*)d_in[16];
  const float* rW2   = (const float*)d_in[17];
  const float* rb2   = (const float*)d_in[18];
  const float* rdc   = (const float*)d_in[19];
  const float* lng   = (const float*)d_in[20];
  const float* lnb   = (const float*)d_in[21];
  const float* Wq    = (const float*)d_in[22];
  const float* bq    = (const float*)d_in[23];
  const float* Wk    = (const float*)d_in[24];
  const float* bk    = (const float*)d_in[25];
  const float* Wv    = (const float*)d_in[26];
  const float* bv    = (const float*)d_in[27];
  const float* Wo    = (const float*)d_in[28];
  const float* bo    = (const float*)d_in[29];
  const float* abeta = (const float*)d_in[30];
  const float* Wout  = (const float*)d_in[31];
  const float* bout  = (const float*)d_in[32];

  const size_t NNe = (size_t)NPT * NPT;
  const size_t NC  = (size_t)NPT * CH;
  float* ws = (float*)d_ws;
  float* E05 = ws;
  float* E2  = ws + NNe;
  float* E8  = ws + 2 * NNe;
  float* M0  = ws + 3 * NNe;
  float* M1  = ws + 4 * NNe;
  float* h   = ws + 5 * NNe;
  float* tP  = h + NC;
  float* tA  = tP + NC;
  float* tB  = tA + NC;
  float* tT  = tB + NC;
  float* tL  = tT + NC;
  float* hd  = tL + NC;           // 3*NC
  float* q   = hd + 3 * NC;
  float* kbf = q + NC;
  float* vbf = kbf + NC;
  float* av  = vbf + NC;
  float* raw = av + NC;           // NPT*6 (padded to NC slot)
  float* sm  = raw + NC;
  float* sumA   = sm;
  float* sumAD  = sm + NPT;
  float* wdeg   = sm + 2 * NPT;
  float* invdeg = sm + 3 * NPT;
  float* Dis    = sm + 4 * NPT;
  float* cvec   = sm + 5 * NPT;
  float* Hc     = sm + 6 * NPT;
  float* stats  = sm + 7 * NPT;   // 16 floats used
  int*   nbr    = (int*)(sm + 8 * NPT);
  int*   cnt    = nbr + NPT * 64;
  float* nbrw   = (float*)(cnt + NPT);

  size_t need_bytes = ((5 * NNe + 14 * NC + 8 * (size_t)NPT) + (size_t)NPT * 64 + NPT
                       + (size_t)NPT * 64 + 64) * 4;
  if (ws_size < need_bytes) return;  // insufficient scratch; bail (will show as mismatch)

  // geometry + curvature features
  pg_row_geom<<<NPT, 256, 0, stream>>>(pos, adj, raw, Hc, sumA, sumAD);
  pg_build_csr<<<NPT, 256, 0, stream>>>(adj, nbr, cnt);
  pg_stats<<<1, 256, 0, stream>>>(raw, sumA, sumAD, stats);
  pg_wdeg<<<NPT, 64, 0, stream>>>(pos, nbr, cnt, stats, nbrw, wdeg, invdeg, Dis, cvec);
  pg_curv_mlp<<<NPT, 64, 0, stream>>>(pos, raw, stats, Wc1, bc1, Wc2, bc2, Win, b_in, h);

  // heat kernels exp(t*L) via Taylor(L/16) + repeated squaring
  pg_taylor_init<<<NPT, 256, 0, stream>>>(nbr, cnt, nbrw, wdeg, M0);
  float* cur = M0;
  float* nxt = M1;
  for (int k = TDEG - 1; k >= 1; k--) {
    pg_horner<<<NPT, 256, 0, stream>>>(nbr, cnt, nbrw, wdeg, cur, nxt, 1.0f / (16.0f * (float)k));
    float* tmp = cur; cur = nxt; nxt = tmp;
  }
  dim3 g16(16, 16);
  pg_sgemm<<<g16, 256, 0, stream>>>(cur, cur, nxt);   // exp(L/8)
  pg_sgemm<<<g16, 256, 0, stream>>>(nxt, nxt, cur);   // exp(L/4)
  pg_sgemm<<<g16, 256, 0, stream>>>(cur, cur, E05);   // exp(L/2)
  pg_sgemm<<<g16, 256, 0, stream>>>(E05, E05, cur);   // exp(L)
  pg_sgemm<<<g16, 256, 0, stream>>>(cur, cur, E2);    // exp(2L)
  pg_sgemm<<<g16, 256, 0, stream>>>(E2, E2, cur);     // exp(4L)
  pg_sgemm<<<g16, 256, 0, stream>>>(cur, cur, E8);    // exp(8L)

  // NL layers
  for (int i = 0; i < 4; i++) {
    pg_csrP<<<NPT, 64, 0, stream>>>(nbr, cnt, nbrw, invdeg, h, tP);
    pg_conv<<<NPT, 64, 0, stream>>>(h, tP, cWs + i * 4096, cbs + i * 64,
                                    cWn + i * 4096, cbn + i * 64, cres + i, tA);
    float* h3 = tA;
    if ((i & 1) == 0) {
      int j = i >> 1;
      pg_eapply<<<NPT / 8, 512, 0, stream>>>(E05, tA, hd);
      pg_eapply<<<NPT / 8, 512, 0, stream>>>(E2, tA, hd + NC);
      pg_eapply<<<NPT / 8, 512, 0, stream>>>(E8, tA, hd + 2 * NC);
      pg_difffuse<<<NPT, 64, 0, stream>>>(tA, hd, dW + j * 3 * 4096, db + j * 64, tB);
      h3 = tB;
    }
    pg_tanhmm<<<NPT, 64, 0, stream>>>(h3, rW1 + i * 4096, rb1 + i * 64, tT);
    pg_csrL<<<NPT, 64, 0, stream>>>(nbr, cnt, nbrw, Dis, cvec, h3, tL);
    pg_rdln<<<NPT, 64, 0, stream>>>(h3, tT, tL, rdc + i * 64, rW2 + i * 4096,
                                    rb2 + i * 64, lng + i * 64, lnb + i * 64, h);
  }

  // attention + output
  pg_qkv<<<NPT, 64, 0, stream>>>(h, Wq, bq, Wk, bk, Wv, bv, q, kbf, vbf);
  pg_attn<<<NPT, 256, 0, stream>>>(q, kbf, vbf, adj, Hc, abeta, av);
  pg_out<<<NPT, 64, 0, stream>>>(h, av, Wo, bo, Wout, bout, (float*)d_out);
}

// Round 2
// 1582.196 us; speedup vs baseline: 2.1259x; 2.1259x over previous
//
#include <hip/hip_runtime.h>
#include <math.h>

#define NPT 2048
#define CH 64
constexpr int TDEG = 18;   // Taylor degree for exp(L/16)

typedef __bf16 bf16_t;
typedef __bf16 bf16x8 __attribute__((ext_vector_type(8)));
typedef __bf16 bf16x4_t __attribute__((ext_vector_type(4)));
typedef float f32x4 __attribute__((ext_vector_type(4)));

__device__ __forceinline__ void gl_lds16(const void* g, void* l) {
  __builtin_amdgcn_global_load_lds(
      (const __attribute__((address_space(1))) void*)g,
      (__attribute__((address_space(3))) void*)l, 16, 0, 0);
}

// ---------------------------------------------------------------- geometry ---
__global__ __launch_bounds__(256) void pg_row_geom(
    const float* __restrict__ pos, const float* __restrict__ adj,
    float* __restrict__ raw, float* __restrict__ Hc,
    float* __restrict__ sumA, float* __restrict__ sumAD)
{
  __shared__ float sp[NPT * 3];
  __shared__ float red[256 * 6];
  int i = blockIdx.x, t = threadIdx.x;
  for (int j = t; j < NPT * 3; j += 256) sp[j] = pos[j];
  __syncthreads();
  float px = sp[3 * i], py = sp[3 * i + 1], pz = sp[3 * i + 2];
  float s0 = 0, s1 = 0, s2 = 0, ax = 0, ay = 0, az = 0;
  for (int j = t; j < NPT; j += 256) {
    float a = adj[(size_t)i * NPT + j];
    if (a != 0.0f) {
      float dx = sp[3 * j] - px, dy = sp[3 * j + 1] - py, dz = sp[3 * j + 2] - pz;
      float d2 = dx * dx + dy * dy + dz * dz + 1e-12f;
      float d = sqrtf(d2);
      s0 += a; s1 += a * d; s2 += a * d2;
      ax += a * sp[3 * j]; ay += a * sp[3 * j + 1]; az += a * sp[3 * j + 2];
    }
  }
  red[t * 6 + 0] = s0; red[t * 6 + 1] = s1; red[t * 6 + 2] = s2;
  red[t * 6 + 3] = ax; red[t * 6 + 4] = ay; red[t * 6 + 5] = az;
  __syncthreads();
  for (int s = 128; s > 0; s >>= 1) {
    if (t < s)
      for (int q = 0; q < 6; q++) red[t * 6 + q] += red[(t + s) * 6 + q];
    __syncthreads();
  }
  if (t == 0) {
    s0 = red[0]; s1 = red[1]; s2 = red[2]; ax = red[3]; ay = red[4]; az = red[5];
    float degc = fmaxf(s0, 1.0f);
    float dxm = ax / degc - px, dym = ay / degc - py, dzm = az / degc - pz;
    float H = 0.5f * sqrtf(dxm * dxm + dym * dym + dzm * dzm);
    float r = s1 / degc;
    float var = (s2 - 2.0f * r * s1 + r * r * s0) / degc;
    float sdev = sqrtf(var + 1e-12f);
    float k1 = H + sdev, k2 = H - sdev;
    raw[i * 6 + 0] = H;
    raw[i * 6 + 1] = k1 * k2;
    raw[i * 6 + 2] = k1;
    raw[i * 6 + 3] = k2;
    raw[i * 6 + 4] = 0.6366197723675814f * atanf((k1 + k2) / (k1 - k2 + 1e-6f));
    raw[i * 6 + 5] = sqrtf(0.5f * (k1 * k1 + k2 * k2));
    Hc[i] = H;
    sumA[i] = s0; sumAD[i] = s1;
  }
}

__global__ __launch_bounds__(256) void pg_build_csr(
    const float* __restrict__ adj, int* __restrict__ nbr, int* __restrict__ cnt)
{
  __shared__ int cs[256];
  __shared__ int offs[257];
  int i = blockIdx.x, t = threadIdx.x;
  size_t base = (size_t)i * NPT + t * 8;
  float av[8];
  int c = 0;
  for (int u = 0; u < 8; u++) { av[u] = adj[base + u]; c += (av[u] != 0.0f); }
  cs[t] = c;
  __syncthreads();
  if (t == 0) {
    offs[0] = 0;
    for (int q = 0; q < 256; q++) offs[q + 1] = offs[q] + cs[q];
  }
  __syncthreads();
  int o = offs[t], w = 0;
  for (int u = 0; u < 8; u++)
    if (av[u] != 0.0f) { int p = o + w; if (p < 64) nbr[i * 64 + p] = t * 8 + u; w++; }
  if (t == 0) cnt[i] = min(offs[256], 64);
}

__global__ __launch_bounds__(256) void pg_stats(
    const float* __restrict__ raw, const float* __restrict__ sumA,
    const float* __restrict__ sumAD, float* __restrict__ stats)
{
  __shared__ float red[256];
  __shared__ float mean6[6];
  int t = threadIdx.x;
  float sa = 0, sad = 0;
  for (int j = t; j < NPT; j += 256) { sa += sumA[j]; sad += sumAD[j]; }
  red[t] = sa; __syncthreads();
  for (int s = 128; s > 0; s >>= 1) { if (t < s) red[t] += red[t + s]; __syncthreads(); }
  float totA = red[0]; __syncthreads();
  red[t] = sad; __syncthreads();
  for (int s = 128; s > 0; s >>= 1) { if (t < s) red[t] += red[t + s]; __syncthreads(); }
  float totAD = red[0]; __syncthreads();
  if (t == 0) {
    float sigma = fmaxf(totAD / fmaxf(totA, 1.0f), 1e-6f);
    stats[0] = 1.0f / (2.0f * sigma * sigma);
    stats[1] = sigma;
  }
  for (int q = 0; q < 6; q++) {
    float s = 0;
    for (int j = t; j < NPT; j += 256) s += raw[j * 6 + q];
    red[t] = s; __syncthreads();
    for (int k = 128; k > 0; k >>= 1) { if (t < k) red[t] += red[t + k]; __syncthreads(); }
    if (t == 0) mean6[q] = red[0] / (float)NPT;
    __syncthreads();
  }
  for (int q = 0; q < 6; q++) {
    float m = mean6[q], s = 0;
    for (int j = t; j < NPT; j += 256) { float d = raw[j * 6 + q] - m; s += d * d; }
    red[t] = s; __syncthreads();
    for (int k = 128; k > 0; k >>= 1) { if (t < k) red[t] += red[t + k]; __syncthreads(); }
    if (t == 0) {
      float sd = sqrtf(red[0] / (float)(NPT - 1));
      stats[2 + q] = m;
      stats[8 + q] = 1.0f / fmaxf(sd, 1e-6f);
    }
    __syncthreads();
  }
}

__global__ __launch_bounds__(64) void pg_wdeg(
    const float* __restrict__ pos, const int* __restrict__ nbr, const int* __restrict__ cnt,
    const float* __restrict__ stats, float* __restrict__ nbrw, float* __restrict__ wdeg,
    float* __restrict__ invdeg, float* __restrict__ Dis, float* __restrict__ cvec)
{
  int i = blockIdx.x, t = threadIdx.x;
  int n = cnt[i];
  float inv2s2 = stats[0];
  float px = pos[3 * i], py = pos[3 * i + 1], pz = pos[3 * i + 2];
  float w = 0.0f;
  if (t < n) {
    int j = nbr[i * 64 + t];
    float dx = pos[3 * j] - px, dy = pos[3 * j + 1] - py, dz = pos[3 * j + 2] - pz;
    float d2 = dx * dx + dy * dy + dz * dz + 1e-12f;
    w = expf(-d2 * inv2s2);
    nbrw[i * 64 + t] = w;
  }
  float s = w;
  for (int off = 1; off < 64; off <<= 1) s += __shfl_xor(s, off);
  if (t == 0) {
    float md = fmaxf(s, 1e-8f);
    wdeg[i] = s;
    invdeg[i] = 1.0f / md;
    float di = 1.0f / sqrtf(md);
    Dis[i] = di;
    cvec[i] = di * di * s;
  }
}

__global__ __launch_bounds__(64) void pg_curv_mlp(
    const float* __restrict__ pos, const float* __restrict__ raw, const float* __restrict__ stats,
    const float* __restrict__ Wc1, const float* __restrict__ bc1,
    const float* __restrict__ Wc2, const float* __restrict__ bc2,
    const float* __restrict__ Win, const float* __restrict__ b_in, float* __restrict__ h)
{
  __shared__ float feat[19];
  __shared__ float nraw[6];
  __shared__ float hid[32];
  int i = blockIdx.x, t = threadIdx.x;
  if (t < 3) feat[t] = pos[3 * i + t];
  if (t < 6) nraw[t] = (raw[i * 6 + t] - stats[2 + t]) * stats[8 + t];
  __syncthreads();
  if (t < 32) {
    float a = bc1[t];
    for (int k = 0; k < 6; k++) a += nraw[k] * Wc1[k * 32 + t];
    hid[t] = a / (1.0f + expf(-a));
  }
  __syncthreads();
  if (t < 16) {
    float a = bc2[t];
    for (int k = 0; k < 32; k++) a += hid[k] * Wc2[k * 16 + t];
    feat[3 + t] = a;
  }
  __syncthreads();
  float a = b_in[t];
  for (int k = 0; k < 19; k++) a += feat[k] * Win[k * CH + t];
  h[i * CH + t] = a;
}

// ----------------------------------------------------------------- expm(tL) ---
__global__ __launch_bounds__(256) void pg_taylor_init(
    const int* __restrict__ nbr, const int* __restrict__ cnt,
    const float* __restrict__ nbrw, const float* __restrict__ wdeg, float* __restrict__ Y)
{
  int i = blockIdx.x, t = threadIdx.x;
  size_t ro = (size_t)i * NPT;
  const float c0 = 1.0f / (16.0f * (float)TDEG);
  for (int j = t; j < NPT; j += 256) Y[ro + j] = 0.0f;
  __syncthreads();
  int n = cnt[i];
  if (t < n) Y[ro + nbr[i * 64 + t]] = nbrw[i * 64 + t] * c0;
  if (t == 0) Y[ro + i] = 1.0f - wdeg[i] * c0;
}

__global__ __launch_bounds__(256) void pg_horner(
    const int* __restrict__ nbr, const int* __restrict__ cnt,
    const float* __restrict__ nbrw, const float* __restrict__ wdeg,
    const float* __restrict__ Yin, float* __restrict__ Yout, float invc)
{
  __shared__ int snb[64];
  __shared__ float swt[64];
  int i = blockIdx.x, t = threadIdx.x;
  if (t < 64) { snb[t] = nbr[i * 64 + t]; swt[t] = nbrw[i * 64 + t]; }
  __syncthreads();
  int n = cnt[i];
  float wd = wdeg[i];
  size_t ro = (size_t)i * NPT;
  for (int c = t; c < NPT; c += 256) {
    float acc = -wd * Yin[ro + c];
    for (int q = 0; q < n; q++) acc += swt[q] * Yin[(size_t)snb[q] * NPT + c];
    Yout[ro + c] = ((c == i) ? 1.0f : 0.0f) + acc * invc;
  }
}

// split f32 matrix into bf16 hi/lo planes + transposed hi/lo planes
__global__ __launch_bounds__(256) void pg_split_t(
    const float* __restrict__ A,
    bf16_t* __restrict__ Ah, bf16_t* __restrict__ Al,
    bf16_t* __restrict__ ATh, bf16_t* __restrict__ ATl)
{
  __shared__ float sA[64 * 65];
  int t = threadIdx.x;
  int by = blockIdx.y, bx = blockIdx.x;
#pragma unroll
  for (int it = 0; it < 4; it++) {
    int r = (t >> 4) + it * 16;
    int c4 = (t & 15) * 4;
    const float* src = A + (size_t)(by * 64 + r) * NPT + bx * 64 + c4;
    float4 v = *(const float4*)src;
    sA[r * 65 + c4 + 0] = v.x; sA[r * 65 + c4 + 1] = v.y;
    sA[r * 65 + c4 + 2] = v.z; sA[r * 65 + c4 + 3] = v.w;
    float vv[4] = {v.x, v.y, v.z, v.w};
    bf16x4_t hv, lv;
#pragma unroll
    for (int q = 0; q < 4; q++) {
      __bf16 hb = (__bf16)vv[q];
      hv[q] = hb;
      lv[q] = (__bf16)(vv[q] - (float)hb);
    }
    size_t o = (size_t)(by * 64 + r) * NPT + bx * 64 + c4;
    *(bf16x4_t*)(Ah + o) = hv;
    *(bf16x4_t*)(Al + o) = lv;
  }
  __syncthreads();
#pragma unroll
  for (int it = 0; it < 4; it++) {
    int rr = (t >> 4) + it * 16;   // AT row (= original col)
    int c4 = (t & 15) * 4;         // AT col (= original row)
    bf16x4_t hv, lv;
#pragma unroll
    for (int q = 0; q < 4; q++) {
      float v = sA[(c4 + q) * 65 + rr];
      __bf16 hb = (__bf16)v;
      hv[q] = hb;
      lv[q] = (__bf16)(v - (float)hb);
    }
    size_t o = (size_t)(bx * 64 + rr) * NPT + by * 64 + c4;
    *(bf16x4_t*)(ATh + o) = hv;
    *(bf16x4_t*)(ATl + o) = lv;
  }
}

// fused 3-term split-bf16 squaring: C = A*A with A given as (h,l) row-major
// and (Th,Tl) transposed row-major. Writes C (h,l) and optionally C^T (h,l).
__global__ __launch_bounds__(256) void pg_sq(
    const bf16_t* __restrict__ Ah, const bf16_t* __restrict__ Al,
    const bf16_t* __restrict__ ATh, const bf16_t* __restrict__ ATl,
    bf16_t* __restrict__ Ch, bf16_t* __restrict__ Cl,
    bf16_t* __restrict__ CTh, bf16_t* __restrict__ CTl)
{
  __shared__ __align__(16) char smem[131072];  // 2 bufs x 4 planes x 16 KB
  const int t = threadIdx.x;
  const int w = t >> 6, l = t & 63;
  const int lrow = l & 15, lhi = l >> 4;
  // XCD-chunked bijective swizzle (256 blocks, 8 XCDs)
  int bid = blockIdx.x;
  int sbid = (bid & 7) * 32 + (bid >> 3);
  const int by = sbid >> 4, bx = sbid & 15;
  const int wr = w >> 1, wc = w & 1;

  // staging source offsets (pre-swizzled global source, linear LDS dest)
  int offA[4], offB[4];
#pragma unroll
  for (int it = 0; it < 4; it++) {
    int o = it * 4096 + t * 16;
    int r = o >> 7;
    int cb = (o & 127) ^ ((r & 7) << 4);
    offA[it] = (by * 128 + r) * (NPT * 2) + cb;
    offB[it] = (bx * 128 + r) * (NPT * 2) + cb;
  }
  // fragment LDS offsets (with read-side swizzle)
  int aoff[4][2], boff[4][2];
#pragma unroll
  for (int m = 0; m < 4; m++) {
    int arow = wr * 64 + m * 16 + lrow;
    int brow = wc * 64 + m * 16 + lrow;
#pragma unroll
    for (int kk = 0; kk < 2; kk++) {
      int kb = kk * 64 + lhi * 16;
      aoff[m][kk] = arow * 128 + (kb ^ ((arow & 7) << 4));
      boff[m][kk] = brow * 128 + (kb ^ ((brow & 7) << 4));
    }
  }

  f32x4 acc[4][4];
#pragma unroll
  for (int m = 0; m < 4; m++)
#pragma unroll
    for (int n = 0; n < 4; n++) acc[m][n] = (f32x4){0.f, 0.f, 0.f, 0.f};

  const int lofs_w = w << 10;
  // prologue: stage k-step 0 into buf 0
#pragma unroll
  for (int it = 0; it < 4; it++) {
    int lo = it * 4096 + lofs_w;
    gl_lds16((const char*)Ah  + offA[it], smem + lo);
    gl_lds16((const char*)Al  + offA[it], smem + 16384 + lo);
    gl_lds16((const char*)ATh + offB[it], smem + 32768 + lo);
    gl_lds16((const char*)ATl + offB[it], smem + 49152 + lo);
  }
  __syncthreads();

  for (int ks = 0; ks < NPT / 64; ks++) {
    if (ks + 1 < NPT / 64) {
      char* nbuf = smem + ((ks + 1) & 1) * 65536;
      size_t kadv = (size_t)(ks + 1) * 128;
#pragma unroll
      for (int it = 0; it < 4; it++) {
        int lo = it * 4096 + lofs_w;
        gl_lds16((const char*)Ah  + offA[it] + kadv, nbuf + lo);
        gl_lds16((const char*)Al  + offA[it] + kadv, nbuf + 16384 + lo);
        gl_lds16((const char*)ATh + offB[it] + kadv, nbuf + 32768 + lo);
        gl_lds16((const char*)ATl + offB[it] + kadv, nbuf + 49152 + lo);
      }
    }
    const char* cbuf = smem + (ks & 1) * 65536;
#pragma unroll
    for (int kk = 0; kk < 2; kk++) {
      bf16x8 bhf[4], blf[4];
#pragma unroll
      for (int n = 0; n < 4; n++) {
        bhf[n] = *(const bf16x8*)(cbuf + 32768 + boff[n][kk]);
        blf[n] = *(const bf16x8*)(cbuf + 49152 + boff[n][kk]);
      }
#pragma unroll
      for (int m = 0; m < 4; m++) {
        bf16x8 ah = *(const bf16x8*)(cbuf + aoff[m][kk]);
        bf16x8 al = *(const bf16x8*)(cbuf + 16384 + aoff[m][kk]);
#pragma unroll
        for (int n = 0; n < 4; n++) {
          acc[m][n] = __builtin_amdgcn_mfma_f32_16x16x32_bf16(al, bhf[n], acc[m][n], 0, 0, 0);
          acc[m][n] = __builtin_amdgcn_mfma_f32_16x16x32_bf16(ah, blf[n], acc[m][n], 0, 0, 0);
          acc[m][n] = __builtin_amdgcn_mfma_f32_16x16x32_bf16(ah, bhf[n], acc[m][n], 0, 0, 0);
        }
      }
    }
    __syncthreads();
  }

  // epilogue
  const int gr0 = by * 128 + wr * 64 + lhi * 4;
  const int gc0 = bx * 128 + wc * 64 + lrow;
#pragma unroll
  for (int m = 0; m < 4; m++) {
#pragma unroll
    for (int n = 0; n < 4; n++) {
      int gc = gc0 + n * 16;
      bf16x4_t hv, lv;
#pragma unroll
      for (int r = 0; r < 4; r++) {
        float c = acc[m][n][r];
        __bf16 hb = (__bf16)c;
        __bf16 lb = (__bf16)(c - (float)hb);
        hv[r] = hb; lv[r] = lb;
        size_t o = (size_t)(gr0 + m * 16 + r) * NPT + gc;
        Ch[o] = hb;
        Cl[o] = lb;
      }
      if (CTh) {
        size_t o = (size_t)gc * NPT + gr0 + m * 16;
        *(bf16x4_t*)(CTh + o) = hv;
        *(bf16x4_t*)(CTl + o) = lv;
      }
    }
  }
}

// legacy f32 SGEMM (fallback path when workspace is small)
__global__ __launch_bounds__(256) void pg_sgemm(
    const float* __restrict__ A, const float* __restrict__ B, float* __restrict__ Cm)
{
  __shared__ float As[8][128];
  __shared__ float Bs[8][128];
  int tid = threadIdx.x;
  int bx = blockIdx.x, by = blockIdx.y;
  int tx = tid & 15, ty = tid >> 4;
  int arow = tid >> 1, acol = (tid & 1) * 4;
  int brow = tid >> 5, bcol = (tid & 31) * 4;
  const float* Ap = A + (size_t)(by * 128 + arow) * NPT + acol;
  const float* Bp = B + (size_t)brow * NPT + bx * 128 + bcol;
  float acc[8][8];
#pragma unroll
  for (int a = 0; a < 8; a++)
#pragma unroll
    for (int b = 0; b < 8; b++) acc[a][b] = 0.0f;
  for (int k0 = 0; k0 < NPT; k0 += 8) {
    float4 av = *(const float4*)(Ap + k0);
    float4 bv = *(const float4*)(Bp + (size_t)k0 * NPT);
    As[acol + 0][arow] = av.x; As[acol + 1][arow] = av.y;
    As[acol + 2][arow] = av.z; As[acol + 3][arow] = av.w;
    *(float4*)(&Bs[brow][bcol]) = bv;
    __syncthreads();
#pragma unroll
    for (int kk = 0; kk < 8; kk++) {
      float a0[8], b0[8];
      *(float4*)(a0) = *(const float4*)(&As[kk][ty * 8]);
      *(float4*)(a0 + 4) = *(const float4*)(&As[kk][ty * 8 + 4]);
      *(float4*)(b0) = *(const float4*)(&Bs[kk][tx * 8]);
      *(float4*)(b0 + 4) = *(const float4*)(&Bs[kk][tx * 8 + 4]);
#pragma unroll
      for (int um = 0; um < 8; um++)
#pragma unroll
        for (int un = 0; un < 8; un++) acc[um][un] += a0[um] * b0[un];
    }
    __syncthreads();
  }
  for (int um = 0; um < 8; um++) {
    float* cp = Cm + (size_t)(by * 128 + ty * 8 + um) * NPT + bx * 128 + tx * 8;
    float4 c0 = {acc[um][0], acc[um][1], acc[um][2], acc[um][3]};
    float4 c1 = {acc[um][4], acc[um][5], acc[um][6], acc[um][7]};
    *(float4*)cp = c0;
    *(float4*)(cp + 4) = c1;
  }
}

// E(2048x2048, f32) @ X(2048x64): legacy fallback
__global__ __launch_bounds__(512) void pg_eapply(
    const float* __restrict__ E, const float* __restrict__ X, float* __restrict__ Y)
{
  int t = threadIdx.x;
  int r = t >> 6, c = t & 63;
  int i = blockIdx.x * 8 + r;
  const float* Er = E + (size_t)i * NPT;
  float acc = 0.0f;
  for (int j = 0; j < NPT; j += 4) {
    float4 e = *(const float4*)(Er + j);
    acc += e.x * X[(j + 0) * CH + c] + e.y * X[(j + 1) * CH + c]
         + e.z * X[(j + 2) * CH + c] + e.w * X[(j + 3) * CH + c];
  }
  Y[i * CH + c] = acc;
}

// E given as bf16 hi+lo planes; X staged in LDS by 512-row chunks
__global__ __launch_bounds__(512) void pg_eapply_hl(
    const bf16_t* __restrict__ Eh, const bf16_t* __restrict__ El,
    const float* __restrict__ X, float* __restrict__ Y)
{
  __shared__ float Xs[512 * CH];  // 128 KB
  int t = threadIdx.x;
  int r = t >> 6, c = t & 63;
  int i = blockIdx.x * 8 + r;
  float acc = 0.0f;
  for (int j0 = 0; j0 < NPT; j0 += 512) {
    __syncthreads();
    for (int u = t * 4; u < 512 * CH; u += 512 * 4)
      *(float4*)(&Xs[u]) = *(const float4*)(&X[j0 * CH + u]);
    __syncthreads();
    const bf16_t* ehp = Eh + (size_t)i * NPT + j0;
    const bf16_t* elp = El + (size_t)i * NPT + j0;
    for (int jj = 0; jj < 512; jj += 4) {
      bf16x4_t eh = *(const bf16x4_t*)(ehp + jj);
      bf16x4_t el = *(const bf16x4_t*)(elp + jj);
      acc += ((float)eh[0] + (float)el[0]) * Xs[(jj + 0) * CH + c]
           + ((float)eh[1] + (float)el[1]) * Xs[(jj + 1) * CH + c]
           + ((float)eh[2] + (float)el[2]) * Xs[(jj + 2) * CH + c]
           + ((float)eh[3] + (float)el[3]) * Xs[(jj + 3) * CH + c];
    }
  }
  Y[(size_t)i * CH + c] = acc;
}

// ------------------------------------------------------------------- layers ---
__global__ __launch_bounds__(64) void pg_csrP(
    const int* __restrict__ nbr, const int* __restrict__ cnt, const float* __restrict__ nbrw,
    const float* __restrict__ invdeg, const float* __restrict__ h, float* __restrict__ out)
{
  __shared__ int snb[64];
  __shared__ float swt[64];
  int i = blockIdx.x, t = threadIdx.x;
  snb[t] = nbr[i * 64 + t];
  swt[t] = nbrw[i * 64 + t];
  __syncthreads();
  int n = cnt[i];
  float acc = 0.0f;
  for (int q = 0; q < n; q++) acc += swt[q] * h[snb[q] * CH + t];
  out[i * CH + t] = acc * invdeg[i];
}

__global__ __launch_bounds__(64) void pg_csrL(
    const int* __restrict__ nbr, const int* __restrict__ cnt, const float* __restrict__ nbrw,
    const float* __restrict__ Dis, const float* __restrict__ cvec,
    const float* __restrict__ h, float* __restrict__ out)
{
  __shared__ int snb[64];
  __shared__ float swt[64];
  int i = blockIdx.x, t = threadIdx.x;
  int n = cnt[i];
  int j = (t < n) ? nbr[i * 64 + t] : 0;
  snb[t] = j;
  swt[t] = (t < n) ? nbrw[i * 64 + t] * Dis[j] : 0.0f;
  __syncthreads();
  float acc = 0.0f;
  for (int q = 0; q < n; q++) acc += swt[q] * h[snb[q] * CH + t];
  out[i * CH + t] = acc * Dis[i] - cvec[i] * h[i * CH + t];
}

__global__ __launch_bounds__(64) void pg_conv(
    const float* __restrict__ h, const float* __restrict__ ph,
    const float* __restrict__ Ws, const float* __restrict__ bs,
    const float* __restrict__ Wn, const float* __restrict__ bn,
    const float* __restrict__ cres, float* __restrict__ out)
{
  __shared__ float sh[64], sp2[64];
  int i = blockIdx.x, t = threadIdx.x;
  sh[t] = h[i * CH + t];
  sp2[t] = ph[i * CH + t];
  __syncthreads();
  float a = bs[t] + bn[t] + 0.1f * cres[0] * sh[t];
  for (int k = 0; k < 64; k++) a += sh[k] * Ws[k * CH + t] + sp2[k] * Wn[k * CH + t];
  out[i * CH + t] = a / (1.0f + expf(-a));
}

__global__ __launch_bounds__(64) void pg_difffuse(
    const float* __restrict__ h2, const float* __restrict__ hd,
    const float* __restrict__ dW, const float* __restrict__ db, float* __restrict__ out)
{
  __shared__ float sh[3][64];
  int i = blockIdx.x, t = threadIdx.x;
  for (int s = 0; s < 3; s++) sh[s][t] = hd[(size_t)s * NPT * CH + i * CH + t];
  __syncthreads();
  float a = h2[i * CH + t] + db[t];
  for (int s = 0; s < 3; s++) {
    const float* w = dW + s * CH * CH;
    for (int k = 0; k < 64; k++) a += sh[s][k] * w[k * CH + t];
  }
  out[i * CH + t] = a;
}

__global__ __launch_bounds__(64) void pg_tanhmm(
    const float* __restrict__ h, const float* __restrict__ W1,
    const float* __restrict__ b1, float* __restrict__ out)
{
  __shared__ float sh[64];
  int i = blockIdx.x, t = threadIdx.x;
  sh[t] = h[i * CH + t];
  __syncthreads();
  float a = b1[t];
  for (int k = 0; k < 64; k++) a += sh[k] * W1[k * CH + t];
  out[i * CH + t] = tanhf(a);
}

__global__ __launch_bounds__(64) void pg_rdln(
    const float* __restrict__ h3, const float* __restrict__ tT, const float* __restrict__ tL,
    const float* __restrict__ rdc, const float* __restrict__ W2, const float* __restrict__ b2,
    const float* __restrict__ g, const float* __restrict__ b, float* __restrict__ hio)
{
  __shared__ float st[64];
  int i = blockIdx.x, t = threadIdx.x;
  st[t] = tT[i * CH + t];
  __syncthreads();
  float react = b2[t];
  for (int k = 0; k < 64; k++) react += st[k] * W2[k * CH + t];
  float x = h3[i * CH + t] + 0.1f * (rdc[t] * tL[i * CH + t] + react) + hio[i * CH + t];
  float s = x;
  for (int off = 1; off < 64; off <<= 1) s += __shfl_xor(s, off);
  float mu = s * (1.0f / 64.0f);
  float d = x - mu;
  float v = d * d;
  for (int off = 1; off < 64; off <<= 1) v += __shfl_xor(v, off);
  v *= (1.0f / 64.0f);
  hio[i * CH + t] = d * (1.0f / sqrtf(v + 1e-5f)) * g[t] + b[t];
}

// ---------------------------------------------------------------- attention ---
__global__ __launch_bounds__(64) void pg_qkv(
    const float* __restrict__ h,
    const float* __restrict__ Wq, const float* __restrict__ bq,
    const float* __restrict__ Wk, const float* __restrict__ bk,
    const float* __restrict__ Wv, const float* __restrict__ bv,
    float* __restrict__ q, float* __restrict__ kb, float* __restrict__ vb)
{
  __shared__ float sh[64];
  int i = blockIdx.x, t = threadIdx.x;
  sh[t] = h[i * CH + t];
  __syncthreads();
  float aq = bq[t], ak = bk[t], avv = bv[t];
  for (int k = 0; k < 64; k++) {
    float x = sh[k];
    aq += x * Wq[k * CH + t];
    ak += x * Wk[k * CH + t];
    avv += x * Wv[k * CH + t];
  }
  q[i * CH + t] = aq;
  kb[i * CH + t] = ak;
  vb[i * CH + t] = avv;
}

__global__ __launch_bounds__(256) void pg_attn(
    const float* __restrict__ q, const float* __restrict__ kb, const float* __restrict__ vb,
    const float* __restrict__ adj, const float* __restrict__ Hc,
    const float* __restrict__ beta, float* __restrict__ av)
{
  int i = blockIdx.x;
  int t = threadIdx.x;
  int head = t >> 6, lane = t & 63;
  float sp_b = logf(1.0f + expf(beta[head]));
  float hci = Hc[i];
  const float* qp = q + i * CH + head * 16;
  float qr[16];
#pragma unroll
  for (int d = 0; d < 16; d++) qr[d] = qp[d];
  float mx = -1e30f, den = 0.0f;
  float vac[16];
#pragma unroll
  for (int d = 0; d < 16; d++) vac[d] = 0.0f;
  for (int m = lane; m < NPT; m += 64) {
    float a = adj[(size_t)i * NPT + m];
    if (a != 0.0f || m == i) {
      const float* kp = kb + m * CH + head * 16;
      float sc = 0.0f;
#pragma unroll
      for (int d = 0; d < 16; d++) sc += qr[d] * kp[d];
      sc *= 0.25f;
      sc -= sp_b * fabsf(hci - Hc[m]);
      float nm = fmaxf(mx, sc);
      float corr = expf(mx - nm);
      float p = expf(sc - nm);
      den = den * corr + p;
      const float* vp = vb + m * CH + head * 16;
#pragma unroll
      for (int d = 0; d < 16; d++) vac[d] = vac[d] * corr + p * vp[d];
      mx = nm;
    }
  }
  for (int off = 32; off > 0; off >>= 1) {
    float omx = __shfl_down(mx, off);
    float oden = __shfl_down(den, off);
    float ov[16];
#pragma unroll
    for (int d = 0; d < 16; d++) ov[d] = __shfl_down(vac[d], off);
    float nm = fmaxf(mx, omx);
    float c1 = expf(mx - nm), c2 = expf(omx - nm);
    den = den * c1 + oden * c2;
#pragma unroll
    for (int d = 0; d < 16; d++) vac[d] = vac[d] * c1 + ov[d] * c2;
    mx = nm;
  }
  if (lane == 0) {
    float inv = 1.0f / den;
    float* o = av + i * CH + head * 16;
    for (int d = 0; d < 16; d++) o[d] = vac[d] * inv;
  }
}

__global__ __launch_bounds__(64) void pg_out(
    const float* __restrict__ h, const float* __restrict__ av,
    const float* __restrict__ Wo, const float* __restrict__ bo,
    const float* __restrict__ Wout, const float* __restrict__ bout, float* __restrict__ out)
{
  __shared__ float sa[64];
  int i = blockIdx.x, t = threadIdx.x;
  sa[t] = av[i * CH + t];
  __syncthreads();
  float a = h[i * CH + t] + bo[t];
  for (int k = 0; k < 64; k++) a += sa[k] * Wo[k * CH + t];
  float s = a * Wout[t];
  for (int off = 1; off < 64; off <<= 1) s += __shfl_xor(s, off);
  if (t == 0) out[i] = s + bout[0];
}

// ------------------------------------------------------------------- launch ---
extern "C" void kernel_launch(void* const* d_in, const int* in_sizes, int n_in,
                              void* d_out, int out_size, void* d_ws, size_t ws_size,
                              hipStream_t stream)
{
  const float* pos   = (const float*)d_in[0];
  const float* adj   = (const float*)d_in[1];
  const float* Wc1   = (const float*)d_in[2];
  const float* bc1   = (const float*)d_in[3];
  const float* Wc2   = (const float*)d_in[4];
  const float* bc2   = (const float*)d_in[5];
  const float* Win   = (const float*)d_in[6];
  const float* b_in  = (const float*)d_in[7];
  const float* cWs   = (const float*)d_in[8];
  const float* cbs   = (const float*)d_in[9];
  const float* cWn   = (const float*)d_in[10];
  const float* cbn   = (const float*)d_in[11];
  const float* cres  = (const float*)d_in[12];
  const float* dW    = (const float*)d_in[13];
  const float* db    = (const float*)d_in[14];
  const float* rW1   = (const float*)d_in[15];
  const float* rb1   = (const float*)d_in[16];
  const float* rW2   = (const float*)d_in[17];
  const float* rb2   = (const float*)d_in[18];
  const float* rdc   = (const float*)d_in[19];
  const float* lng   = (const float*)d_in[20];
  const float* lnb   = (const float*)d_in[21];
  const float* Wq    = (const float*)d_in[22];
  const float* bq    = (const float*)d_in[23];
  const float* Wk    = (const float*)d_in[24];
  const float* bk    = (const float*)d_in[25];
  const float* Wv    = (const float*)d_in[26];
  const float* bv    = (const float*)d_in[27];
  const float* Wo    = (const float*)d_in[28];
  const float* bo    = (const float*)d_in[29];
  const float* abeta = (const float*)d_in[30];
  const float* Wout  = (const float*)d_in[31];
  const float* bout  = (const float*)d_in[32];

  const size_t NNe = (size_t)NPT * NPT;
  const size_t NC  = (size_t)NPT * CH;
  const size_t MB  = 1024 * 1024;
  const size_t PLANE = NNe * 2;  // bytes per bf16 plane (8 MB)

  // small-region byte size (shared by both paths)
  const size_t small_bytes = (14 * NC + 8 * (size_t)NPT) * 4 + (size_t)NPT * 64 * 4
                           + (size_t)NPT * 4 + (size_t)NPT * 64 * 4 + 256;
  const size_t need_bf16 = 112 * MB + small_bytes;
  const size_t need_old  = 5 * NNe * 4 + small_bytes;
  bool use_bf16 = (ws_size >= need_bf16);
  if (!use_bf16 && ws_size < need_old) return;

  char* base = (char*)d_ws;

  // bf16-path layout
  bf16_t* E05h = (bf16_t*)(base + 0 * PLANE);
  bf16_t* E05l = (bf16_t*)(base + 1 * PLANE);
  bf16_t* E2h  = (bf16_t*)(base + 2 * PLANE);
  bf16_t* E2l  = (bf16_t*)(base + 3 * PLANE);
  bf16_t* E8h  = (bf16_t*)(base + 4 * PLANE);
  bf16_t* E8l  = (bf16_t*)(base + 5 * PLANE);
  bf16_t* SAh  = (bf16_t*)(base + 6 * PLANE);
  bf16_t* SAl  = (bf16_t*)(base + 7 * PLANE);
  bf16_t* SATh = (bf16_t*)(base + 8 * PLANE);
  bf16_t* SATl = (bf16_t*)(base + 9 * PLANE);
  bf16_t* SBh  = (bf16_t*)(base + 10 * PLANE);
  bf16_t* SBl  = (bf16_t*)(base + 11 * PLANE);
  bf16_t* SBTh = (bf16_t*)(base + 12 * PLANE);
  bf16_t* SBTl = (bf16_t*)(base + 13 * PLANE);

  float *M0, *M1, *E05f = nullptr, *E2f = nullptr, *E8f = nullptr, *sm_base;
  if (use_bf16) {
    M0 = (float*)(base + 10 * PLANE);   // SB region reused for horner
    M1 = (float*)(base + 12 * PLANE);
    sm_base = (float*)(base + 112 * MB);
  } else {
    E05f = (float*)base;
    E2f  = E05f + NNe;
    E8f  = E2f + NNe;
    M0   = E8f + NNe;
    M1   = M0 + NNe;
    sm_base = M1 + NNe;
  }

  float* h   = sm_base;
  float* tP  = h + NC;
  float* tA  = tP + NC;
  float* tB  = tA + NC;
  float* tT  = tB + NC;
  float* tL  = tT + NC;
  float* hd  = tL + NC;           // 3*NC
  float* q   = hd + 3 * NC;
  float* kbf = q + NC;
  float* vbf = kbf + NC;
  float* av  = vbf + NC;
  float* raw = av + NC;           // NPT*6 (padded to NC slot)
  float* sm  = raw + NC;
  float* sumA   = sm;
  float* sumAD  = sm + NPT;
  float* wdeg   = sm + 2 * NPT;
  float* invdeg = sm + 3 * NPT;
  float* Dis    = sm + 4 * NPT;
  float* cvec   = sm + 5 * NPT;
  float* Hc     = sm + 6 * NPT;
  float* stats  = sm + 7 * NPT;   // 16 floats used
  int*   nbr    = (int*)(sm + 8 * NPT);
  int*   cnt    = nbr + NPT * 64;
  float* nbrw   = (float*)(cnt + NPT);

  // geometry + curvature features
  pg_row_geom<<<NPT, 256, 0, stream>>>(pos, adj, raw, Hc, sumA, sumAD);
  pg_build_csr<<<NPT, 256, 0, stream>>>(adj, nbr, cnt);
  pg_stats<<<1, 256, 0, stream>>>(raw, sumA, sumAD, stats);
  pg_wdeg<<<NPT, 64, 0, stream>>>(pos, nbr, cnt, stats, nbrw, wdeg, invdeg, Dis, cvec);
  pg_curv_mlp<<<NPT, 64, 0, stream>>>(pos, raw, stats, Wc1, bc1, Wc2, bc2, Win, b_in, h);

  // T = exp(L/16) via sparse Taylor-Horner
  pg_taylor_init<<<NPT, 256, 0, stream>>>(nbr, cnt, nbrw, wdeg, M0);
  float* cur = M0;
  float* nxt = M1;
  for (int k = TDEG - 1; k >= 1; k--) {
    pg_horner<<<NPT, 256, 0, stream>>>(nbr, cnt, nbrw, wdeg, cur, nxt, 1.0f / (16.0f * (float)k));
    float* tmp = cur; cur = nxt; nxt = tmp;
  }

  if (use_bf16) {
    dim3 g32(32, 32);
    pg_split_t<<<g32, 256, 0, stream>>>(cur, SAh, SAl, SATh, SATl);
    // squaring chain: SA=exp(L/16) -> ... -> exp(8L)
    pg_sq<<<256, 256, 0, stream>>>(SAh, SAl, SATh, SATl, SBh, SBl, SBTh, SBTl);     // L/8
    pg_sq<<<256, 256, 0, stream>>>(SBh, SBl, SBTh, SBTl, SAh, SAl, SATh, SATl);     // L/4
    pg_sq<<<256, 256, 0, stream>>>(SAh, SAl, SATh, SATl, E05h, E05l, SBTh, SBTl);   // L/2
    pg_sq<<<256, 256, 0, stream>>>(E05h, E05l, SBTh, SBTl, SAh, SAl, SATh, SATl);   // L
    pg_sq<<<256, 256, 0, stream>>>(SAh, SAl, SATh, SATl, E2h, E2l, SBTh, SBTl);     // 2L
    pg_sq<<<256, 256, 0, stream>>>(E2h, E2l, SBTh, SBTl, SAh, SAl, SATh, SATl);     // 4L
    pg_sq<<<256, 256, 0, stream>>>(SAh, SAl, SATh, SATl, E8h, E8l, nullptr, nullptr); // 8L
  } else {
    dim3 g16(16, 16);
    pg_sgemm<<<g16, 256, 0, stream>>>(cur, cur, nxt);    // exp(L/8)
    pg_sgemm<<<g16, 256, 0, stream>>>(nxt, nxt, cur);    // exp(L/4)
    pg_sgemm<<<g16, 256, 0, stream>>>(cur, cur, E05f);   // exp(L/2)
    pg_sgemm<<<g16, 256, 0, stream>>>(E05f, E05f, cur);  // exp(L)
    pg_sgemm<<<g16, 256, 0, stream>>>(cur, cur, E2f);    // exp(2L)
    pg_sgemm<<<g16, 256, 0, stream>>>(E2f, E2f, cur);    // exp(4L)
    pg_sgemm<<<g16, 256, 0, stream>>>(cur, cur, E8f);    // exp(8L)
  }

  // NL layers
  for (int i = 0; i < 4; i++) {
    pg_csrP<<<NPT, 64, 0, stream>>>(nbr, cnt, nbrw, invdeg, h, tP);
    pg_conv<<<NPT, 64, 0, stream>>>(h, tP, cWs + i * 4096, cbs + i * 64,
                                    cWn + i * 4096, cbn + i * 64, cres + i, tA);
    float* h3 = tA;
    if ((i & 1) == 0) {
      int j = i >> 1;
      if (use_bf16) {
        pg_eapply_hl<<<NPT / 8, 512, 0, stream>>>(E05h, E05l, tA, hd);
        pg_eapply_hl<<<NPT / 8, 512, 0, stream>>>(E2h, E2l, tA, hd + NC);
        pg_eapply_hl<<<NPT / 8, 512, 0, stream>>>(E8h, E8l, tA, hd + 2 * NC);
      } else {
        pg_eapply<<<NPT / 8, 512, 0, stream>>>(E05f, tA, hd);
        pg_eapply<<<NPT / 8, 512, 0, stream>>>(E2f, tA, hd + NC);
        pg_eapply<<<NPT / 8, 512, 0, stream>>>(E8f, tA, hd + 2 * NC);
      }
      pg_difffuse<<<NPT, 64, 0, stream>>>(tA, hd, dW + j * 3 * 4096, db + j * 64, tB);
      h3 = tB;
    }
    pg_tanhmm<<<NPT, 64, 0, stream>>>(h3, rW1 + i * 4096, rb1 + i * 64, tT);
    pg_csrL<<<NPT, 64, 0, stream>>>(nbr, cnt, nbrw, Dis, cvec, h3, tL);
    pg_rdln<<<NPT, 64, 0, stream>>>(h3, tT, tL, rdc + i * 64, rW2 + i * 4096,
                                    rb2 + i * 64, lng + i * 64, lnb + i * 64, h);
  }

  // attention + output
  pg_qkv<<<NPT, 64, 0, stream>>>(h, Wq, bq, Wk, bk, Wv, bv, q, kbf, vbf);
  pg_attn<<<NPT, 256, 0, stream>>>(q, kbf, vbf, adj, Hc, abeta, av);
  pg_out<<<NPT, 64, 0, stream>>>(h, av, Wo, bo, Wout, bout, (float*)d_out);
}

// Round 3
// 1429.307 us; speedup vs baseline: 2.3534x; 1.1070x over previous
//
#include <hip/hip_runtime.h>
#include <math.h>

#define NPT 2048
#define CH 64
constexpr int TDEG = 12;        // Taylor degree for exp(L/32)
constexpr float SCL = 32.0f;    // scaling denominator

typedef __bf16 bf16_t;
typedef __bf16 bf16x8 __attribute__((ext_vector_type(8)));
typedef __bf16 bf16x4_t __attribute__((ext_vector_type(4)));
typedef float f32x4 __attribute__((ext_vector_type(4)));

__device__ __forceinline__ void gl_lds16(const void* g, void* l) {
  __builtin_amdgcn_global_load_lds(
      (const __attribute__((address_space(1))) void*)g,
      (__attribute__((address_space(3))) void*)l, 16, 0, 0);
}

// ------------------------------------------------- geometry + CSR (one scan) ---
__global__ __launch_bounds__(256) void pg_geom_csr(
    const float* __restrict__ pos, const float* __restrict__ adj,
    float* __restrict__ raw, float* __restrict__ Hc,
    float* __restrict__ sumA, float* __restrict__ sumAD,
    int* __restrict__ nbr, int* __restrict__ cnt)
{
  __shared__ float sp[NPT * 3];
  __shared__ float red[256 * 6];
  __shared__ int wsum[4];
  int i = blockIdx.x, t = threadIdx.x;
  for (int j = t; j < NPT * 3; j += 256) sp[j] = pos[j];
  __syncthreads();
  float px = sp[3 * i], py = sp[3 * i + 1], pz = sp[3 * i + 2];

  size_t base = (size_t)i * NPT + t * 8;
  float av[8];
  int c = 0;
  for (int u = 0; u < 8; u++) { av[u] = adj[base + u]; c += (av[u] != 0.0f); }
  // wave-level inclusive scan
  int sc = c;
  int lane = t & 63;
  for (int off = 1; off < 64; off <<= 1) {
    int v = __shfl_up(sc, off);
    if (lane >= off) sc += v;
  }
  if (lane == 63) wsum[t >> 6] = sc;
  __syncthreads();
  int wprefix = 0;
  for (int w = 0; w < (t >> 6); w++) wprefix += wsum[w];
  int o = wprefix + sc - c;
  int wr = 0;
  for (int u = 0; u < 8; u++)
    if (av[u] != 0.0f) { int p = o + wr; if (p < 64) nbr[i * 64 + p] = t * 8 + u; wr++; }

  // geometry sums from the same entries
  float s0 = 0, s1 = 0, s2 = 0, ax = 0, ay = 0, az = 0;
  for (int u = 0; u < 8; u++) {
    if (av[u] != 0.0f) {
      int j = t * 8 + u;
      float dx = sp[3 * j] - px, dy = sp[3 * j + 1] - py, dz = sp[3 * j + 2] - pz;
      float d2 = dx * dx + dy * dy + dz * dz + 1e-12f;
      float d = sqrtf(d2);
      s0 += 1.0f; s1 += d; s2 += d2;
      ax += sp[3 * j]; ay += sp[3 * j + 1]; az += sp[3 * j + 2];
    }
  }
  red[t * 6 + 0] = s0; red[t * 6 + 1] = s1; red[t * 6 + 2] = s2;
  red[t * 6 + 3] = ax; red[t * 6 + 4] = ay; red[t * 6 + 5] = az;
  __syncthreads();
  for (int s = 128; s > 0; s >>= 1) {
    if (t < s)
      for (int q = 0; q < 6; q++) red[t * 6 + q] += red[(t + s) * 6 + q];
    __syncthreads();
  }
  if (t == 0) {
    s0 = red[0]; s1 = red[1]; s2 = red[2]; ax = red[3]; ay = red[4]; az = red[5];
    float degc = fmaxf(s0, 1.0f);
    float dxm = ax / degc - px, dym = ay / degc - py, dzm = az / degc - pz;
    float H = 0.5f * sqrtf(dxm * dxm + dym * dym + dzm * dzm);
    float r = s1 / degc;
    float var = (s2 - 2.0f * r * s1 + r * r * s0) / degc;
    float sdev = sqrtf(var + 1e-12f);
    float k1 = H + sdev, k2 = H - sdev;
    raw[i * 6 + 0] = H;
    raw[i * 6 + 1] = k1 * k2;
    raw[i * 6 + 2] = k1;
    raw[i * 6 + 3] = k2;
    raw[i * 6 + 4] = 0.6366197723675814f * atanf((k1 + k2) / (k1 - k2 + 1e-6f));
    raw[i * 6 + 5] = sqrtf(0.5f * (k1 * k1 + k2 * k2));
    Hc[i] = H;
    sumA[i] = s0; sumAD[i] = s1;
    int tot = wsum[0] + wsum[1] + wsum[2] + wsum[3];
    cnt[i] = min(tot, 64);
  }
}

__global__ __launch_bounds__(256) void pg_stats(
    const float* __restrict__ raw, const float* __restrict__ sumA,
    const float* __restrict__ sumAD, float* __restrict__ stats)
{
  __shared__ float red[256];
  __shared__ float mean6[6];
  int t = threadIdx.x;
  float sa = 0, sad = 0;
  for (int j = t; j < NPT; j += 256) { sa += sumA[j]; sad += sumAD[j]; }
  red[t] = sa; __syncthreads();
  for (int s = 128; s > 0; s >>= 1) { if (t < s) red[t] += red[t + s]; __syncthreads(); }
  float totA = red[0]; __syncthreads();
  red[t] = sad; __syncthreads();
  for (int s = 128; s > 0; s >>= 1) { if (t < s) red[t] += red[t + s]; __syncthreads(); }
  float totAD = red[0]; __syncthreads();
  if (t == 0) {
    float sigma = fmaxf(totAD / fmaxf(totA, 1.0f), 1e-6f);
    stats[0] = 1.0f / (2.0f * sigma * sigma);
    stats[1] = sigma;
  }
  for (int q = 0; q < 6; q++) {
    float s = 0;
    for (int j = t; j < NPT; j += 256) s += raw[j * 6 + q];
    red[t] = s; __syncthreads();
    for (int k = 128; k > 0; k >>= 1) { if (t < k) red[t] += red[t + k]; __syncthreads(); }
    if (t == 0) mean6[q] = red[0] / (float)NPT;
    __syncthreads();
  }
  for (int q = 0; q < 6; q++) {
    float m = mean6[q], s = 0;
    for (int j = t; j < NPT; j += 256) { float d = raw[j * 6 + q] - m; s += d * d; }
    red[t] = s; __syncthreads();
    for (int k = 128; k > 0; k >>= 1) { if (t < k) red[t] += red[t + k]; __syncthreads(); }
    if (t == 0) {
      float sd = sqrtf(red[0] / (float)(NPT - 1));
      stats[2 + q] = m;
      stats[8 + q] = 1.0f / fmaxf(sd, 1e-6f);
    }
    __syncthreads();
  }
}

__global__ __launch_bounds__(64) void pg_wdeg(
    const float* __restrict__ pos, const int* __restrict__ nbr, const int* __restrict__ cnt,
    const float* __restrict__ stats, int2* __restrict__ pack, float* __restrict__ wdeg,
    float* __restrict__ invdeg, float* __restrict__ Dis, float* __restrict__ cvec)
{
  int i = blockIdx.x, t = threadIdx.x;
  int n = cnt[i];
  float inv2s2 = stats[0];
  float px = pos[3 * i], py = pos[3 * i + 1], pz = pos[3 * i + 2];
  float w = 0.0f;
  int j = 0;
  if (t < n) {
    j = nbr[i * 64 + t];
    float dx = pos[3 * j] - px, dy = pos[3 * j + 1] - py, dz = pos[3 * j + 2] - pz;
    float d2 = dx * dx + dy * dy + dz * dz + 1e-12f;
    w = expf(-d2 * inv2s2);
  }
  pack[i * 64 + t] = make_int2(j, __float_as_int(w));
  float s = w;
  for (int off = 1; off < 64; off <<= 1) s += __shfl_xor(s, off);
  if (t == 0) {
    float md = fmaxf(s, 1e-8f);
    wdeg[i] = s;
    invdeg[i] = 1.0f / md;
    float di = 1.0f / sqrtf(md);
    Dis[i] = di;
    cvec[i] = di * di * s;
  }
}

__global__ __launch_bounds__(64) void pg_curv_mlp(
    const float* __restrict__ pos, const float* __restrict__ raw, const float* __restrict__ stats,
    const float* __restrict__ Wc1, const float* __restrict__ bc1,
    const float* __restrict__ Wc2, const float* __restrict__ bc2,
    const float* __restrict__ Win, const float* __restrict__ b_in, float* __restrict__ h)
{
  __shared__ float feat[19];
  __shared__ float nraw[6];
  __shared__ float hid[32];
  int i = blockIdx.x, t = threadIdx.x;
  if (t < 3) feat[t] = pos[3 * i + t];
  if (t < 6) nraw[t] = (raw[i * 6 + t] - stats[2 + t]) * stats[8 + t];
  __syncthreads();
  if (t < 32) {
    float a = bc1[t];
    for (int k = 0; k < 6; k++) a += nraw[k] * Wc1[k * 32 + t];
    hid[t] = a / (1.0f + expf(-a));
  }
  __syncthreads();
  if (t < 16) {
    float a = bc2[t];
    for (int k = 0; k < 32; k++) a += hid[k] * Wc2[k * 16 + t];
    feat[3 + t] = a;
  }
  __syncthreads();
  float a = b_in[t];
  for (int k = 0; k < 19; k++) a += feat[k] * Win[k * CH + t];
  h[i * CH + t] = a;
}

// --------------------------- exp(L/32): XCD-striped Taylor-Horner in column bands
// grid 512: stripe s = b&7 (256 cols, pinned to XCD s), row-group g = b>>3 (32 rows)
__global__ __launch_bounds__(256) void pg_tinit(
    const int2* __restrict__ pack, const int* __restrict__ cnt,
    const float* __restrict__ wdeg, float* __restrict__ Y)
{
  int b = blockIdx.x;
  int s = b & 7, g = b >> 3;
  int col = s * 256 + threadIdx.x;
  const float c0 = 1.0f / (SCL * (float)TDEG);
  for (int r = g * 32; r < g * 32 + 32; r++) {
    int n = cnt[r];
    float v = 0.0f;
    for (int q = 0; q < n; q++) {
      int2 p = pack[r * 64 + q];
      if (p.x == col) v = __int_as_float(p.y);
    }
    float val = (col == r) ? (1.0f - wdeg[r] * c0) : (v * c0);
    Y[(size_t)r * NPT + col] = val;
  }
}

template <bool LAST>
__global__ __launch_bounds__(256) void pg_h2(
    const int2* __restrict__ pack, const int* __restrict__ cnt,
    const float* __restrict__ wdeg, const float* __restrict__ Yin,
    float* __restrict__ Yout, float invc,
    bf16_t* __restrict__ Th, bf16_t* __restrict__ Tl)
{
  int b = blockIdx.x;
  int s = b & 7, g = b >> 3;
  int col = s * 256 + threadIdx.x;
  for (int r = g * 32; r < g * 32 + 32; r++) {
    int n = cnt[r];
    float wd = wdeg[r];
    float acc0 = -wd * Yin[(size_t)r * NPT + col];
    float acc1 = 0.0f;
    int q = 0;
    for (; q + 1 < n; q += 2) {
      int2 p0 = pack[r * 64 + q];
      int2 p1 = pack[r * 64 + q + 1];
      acc0 += __int_as_float(p0.y) * Yin[(size_t)p0.x * NPT + col];
      acc1 += __int_as_float(p1.y) * Yin[(size_t)p1.x * NPT + col];
    }
    if (q < n) {
      int2 p0 = pack[r * 64 + q];
      acc0 += __int_as_float(p0.y) * Yin[(size_t)p0.x * NPT + col];
    }
    float val = ((r == col) ? 1.0f : 0.0f) + (acc0 + acc1) * invc;
    if (LAST) {
      __bf16 hb = (__bf16)val;
      Th[(size_t)r * NPT + col] = hb;
      Tl[(size_t)r * NPT + col] = (__bf16)(val - (float)hb);
    } else {
      Yout[(size_t)r * NPT + col] = val;
    }
  }
}

// ------------- symmetric squaring: C = A*A, A symmetric, split-bf16 3-term MFMA
__global__ __launch_bounds__(256) void pg_sq(
    const bf16_t* __restrict__ Ah, const bf16_t* __restrict__ Al,
    bf16_t* __restrict__ Ch, bf16_t* __restrict__ Cl)
{
  __shared__ __align__(16) char smem[131072];  // 2 bufs x 4 tiles x 16 KB
  const int t = threadIdx.x;
  const int w = t >> 6, l = t & 63;
  const int lrow = l & 15, lhi = l >> 4;
  int bid = blockIdx.x;
  int sbid = (bid & 7) * 32 + (bid >> 3);
  const int by = sbid >> 4, bx = sbid & 15;
  const int wr = w >> 1, wc = w & 1;

  int offA[4], offB[4];
#pragma unroll
  for (int it = 0; it < 4; it++) {
    int o = it * 4096 + t * 16;
    int r = o >> 7;
    int cb = (o & 127) ^ ((r & 7) << 4);
    offA[it] = (by * 128 + r) * (NPT * 2) + cb;
    offB[it] = (bx * 128 + r) * (NPT * 2) + cb;
  }
  int aoff[4][2], boff[4][2];
#pragma unroll
  for (int m = 0; m < 4; m++) {
    int arow = wr * 64 + m * 16 + lrow;
    int brow = wc * 64 + m * 16 + lrow;
#pragma unroll
    for (int kk = 0; kk < 2; kk++) {
      int kb = kk * 64 + lhi * 16;
      aoff[m][kk] = arow * 128 + (kb ^ ((arow & 7) << 4));
      boff[m][kk] = brow * 128 + (kb ^ ((brow & 7) << 4));
    }
  }

  f32x4 acc[4][4];
#pragma unroll
  for (int m = 0; m < 4; m++)
#pragma unroll
    for (int n = 0; n < 4; n++) acc[m][n] = (f32x4){0.f, 0.f, 0.f, 0.f};

  const int lofs_w = w << 10;
#pragma unroll
  for (int it = 0; it < 4; it++) {
    int lo = it * 4096 + lofs_w;
    gl_lds16((const char*)Ah + offA[it], smem + lo);
    gl_lds16((const char*)Al + offA[it], smem + 16384 + lo);
    gl_lds16((const char*)Ah + offB[it], smem + 32768 + lo);
    gl_lds16((const char*)Al + offB[it], smem + 49152 + lo);
  }
  __syncthreads();

  for (int ks = 0; ks < NPT / 64; ks++) {
    if (ks + 1 < NPT / 64) {
      char* nbuf = smem + ((ks + 1) & 1) * 65536;
      size_t kadv = (size_t)(ks + 1) * 128;
#pragma unroll
      for (int it = 0; it < 4; it++) {
        int lo = it * 4096 + lofs_w;
        gl_lds16((const char*)Ah + offA[it] + kadv, nbuf + lo);
        gl_lds16((const char*)Al + offA[it] + kadv, nbuf + 16384 + lo);
        gl_lds16((const char*)Ah + offB[it] + kadv, nbuf + 32768 + lo);
        gl_lds16((const char*)Al + offB[it] + kadv, nbuf + 49152 + lo);
      }
    }
    const char* cbuf = smem + (ks & 1) * 65536;
#pragma unroll
    for (int kk = 0; kk < 2; kk++) {
      bf16x8 bhf[4], blf[4];
#pragma unroll
      for (int n = 0; n < 4; n++) {
        bhf[n] = *(const bf16x8*)(cbuf + 32768 + boff[n][kk]);
        blf[n] = *(const bf16x8*)(cbuf + 49152 + boff[n][kk]);
      }
#pragma unroll
      for (int m = 0; m < 4; m++) {
        bf16x8 ah = *(const bf16x8*)(cbuf + aoff[m][kk]);
        bf16x8 al = *(const bf16x8*)(cbuf + 16384 + aoff[m][kk]);
#pragma unroll
        for (int n = 0; n < 4; n++) {
          acc[m][n] = __builtin_amdgcn_mfma_f32_16x16x32_bf16(al, bhf[n], acc[m][n], 0, 0, 0);
          acc[m][n] = __builtin_amdgcn_mfma_f32_16x16x32_bf16(ah, blf[n], acc[m][n], 0, 0, 0);
          acc[m][n] = __builtin_amdgcn_mfma_f32_16x16x32_bf16(ah, bhf[n], acc[m][n], 0, 0, 0);
        }
      }
    }
    __syncthreads();
  }

  const int gr0 = by * 128 + wr * 64 + lhi * 4;
  const int gc0 = bx * 128 + wc * 64 + lrow;
#pragma unroll
  for (int m = 0; m < 4; m++) {
#pragma unroll
    for (int n = 0; n < 4; n++) {
      int gc = gc0 + n * 16;
#pragma unroll
      for (int r = 0; r < 4; r++) {
        float c = acc[m][n][r];
        __bf16 hb = (__bf16)c;
        size_t o = (size_t)(gr0 + m * 16 + r) * NPT + gc;
        Ch[o] = hb;
        Cl[o] = (__bf16)(c - (float)hb);
      }
    }
  }
}

// ------------------- X (2048x64 f32) -> XT hi/lo bf16 (64x2048), LDS transpose ---
__global__ __launch_bounds__(256) void pg_splitx(
    const float* __restrict__ X, bf16_t* __restrict__ XTh, bf16_t* __restrict__ XTl)
{
  __shared__ float sX[64][65];
  int t = threadIdx.x;
  int r0 = blockIdx.x * 64;
  for (int u = 0; u < 16; u++) {
    int idx = u * 256 + t;           // 0..4095
    int r = idx >> 6, c = idx & 63;
    sX[r][c] = X[(size_t)(r0 + r) * CH + c];
  }
  __syncthreads();
  // write XT rows: c = row of XT, 64 consecutive r per wavefront-ish
  int c = t >> 6;         // 0..3
  int rr = t & 63;        // 0..63
  for (int cc = c; cc < 64; cc += 4) {
    float v = sX[rr][cc];
    __bf16 hb = (__bf16)v;
    XTh[(size_t)cc * NPT + r0 + rr] = hb;
    XTl[(size_t)cc * NPT + r0 + rr] = (__bf16)(v - (float)hb);
  }
}

// ---------- hd[scale] = E_scale @ X  via MFMA; grid (32 row-blocks, 3 scales) ---
__global__ __launch_bounds__(256) void pg_emm(
    const bf16_t* __restrict__ E05h, const bf16_t* __restrict__ E05l,
    const bf16_t* __restrict__ E2h,  const bf16_t* __restrict__ E2l,
    const bf16_t* __restrict__ E8h,  const bf16_t* __restrict__ E8l,
    const bf16_t* __restrict__ XTh,  const bf16_t* __restrict__ XTl,
    float* __restrict__ hd)
{
  __shared__ __align__(16) char smem[65536];  // 2 bufs x 4 tiles x 8 KB
  const int t = threadIdx.x;
  const int w = t >> 6, l = t & 63;
  const int lrow = l & 15, lhi = l >> 4;
  const int scale = blockIdx.y;
  const bf16_t* Eh = (scale == 0) ? E05h : (scale == 1) ? E2h : E8h;
  const bf16_t* El = (scale == 0) ? E05l : (scale == 1) ? E2l : E8l;
  const int rb = blockIdx.x;  // 64-row block

  int offA[2], offB[2];
#pragma unroll
  for (int it = 0; it < 2; it++) {
    int o = it * 4096 + t * 16;
    int r = o >> 7;
    int cb = (o & 127) ^ ((r & 7) << 4);
    offA[it] = (rb * 64 + r) * (NPT * 2) + cb;
    offB[it] = r * (NPT * 2) + cb;
  }
  int aoff[2], boff[4][2];
  {
    int arow = w * 16 + lrow;
#pragma unroll
    for (int kk = 0; kk < 2; kk++) {
      int kb = kk * 64 + lhi * 16;
      aoff[kk] = arow * 128 + (kb ^ ((arow & 7) << 4));
    }
  }
#pragma unroll
  for (int n = 0; n < 4; n++) {
    int brow = n * 16 + lrow;
#pragma unroll
    for (int kk = 0; kk < 2; kk++) {
      int kb = kk * 64 + lhi * 16;
      boff[n][kk] = brow * 128 + (kb ^ ((brow & 7) << 4));
    }
  }

  f32x4 acc[4];
#pragma unroll
  for (int n = 0; n < 4; n++) acc[n] = (f32x4){0.f, 0.f, 0.f, 0.f};

  const int lofs_w = w << 10;
#pragma unroll
  for (int it = 0; it < 2; it++) {
    int lo = it * 4096 + lofs_w;
    gl_lds16((const char*)Eh  + offA[it], smem + lo);
    gl_lds16((const char*)El  + offA[it], smem + 8192 + lo);
    gl_lds16((const char*)XTh + offB[it], smem + 16384 + lo);
    gl_lds16((const char*)XTl + offB[it], smem + 24576 + lo);
  }
  __syncthreads();

  for (int ks = 0; ks < NPT / 64; ks++) {
    if (ks + 1 < NPT / 64) {
      char* nbuf = smem + ((ks + 1) & 1) * 32768;
      size_t kadv = (size_t)(ks + 1) * 128;
#pragma unroll
      for (int it = 0; it < 2; it++) {
        int lo = it * 4096 + lofs_w;
        gl_lds16((const char*)Eh  + offA[it] + kadv, nbuf + lo);
        gl_lds16((const char*)El  + offA[it] + kadv, nbuf + 8192 + lo);
        gl_lds16((const char*)XTh + offB[it] + kadv, nbuf + 16384 + lo);
        gl_lds16((const char*)XTl + offB[it] + kadv, nbuf + 24576 + lo);
      }
    }
    const char* cbuf = smem + (ks & 1) * 32768;
#pragma unroll
    for (int kk = 0; kk < 2; kk++) {
      bf16x8 ah = *(const bf16x8*)(cbuf + aoff[kk]);
      bf16x8 al = *(const bf16x8*)(cbuf + 8192 + aoff[kk]);
#pragma unroll
      for (int n = 0; n < 4; n++) {
        bf16x8 bh = *(const bf16x8*)(cbuf + 16384 + boff[n][kk]);
        bf16x8 bl = *(const bf16x8*)(cbuf + 24576 + boff[n][kk]);
        acc[n] = __builtin_amdgcn_mfma_f32_16x16x32_bf16(al, bh, acc[n], 0, 0, 0);
        acc[n] = __builtin_amdgcn_mfma_f32_16x16x32_bf16(ah, bl, acc[n], 0, 0, 0);
        acc[n] = __builtin_amdgcn_mfma_f32_16x16x32_bf16(ah, bh, acc[n], 0, 0, 0);
      }
    }
    __syncthreads();
  }

  float* Y = hd + (size_t)scale * NPT * CH;
  const int gr0 = rb * 64 + w * 16 + lhi * 4;
#pragma unroll
  for (int n = 0; n < 4; n++) {
    int gc = n * 16 + lrow;
#pragma unroll
    for (int r = 0; r < 4; r++)
      Y[(size_t)(gr0 + r) * CH + gc] = acc[n][r];
  }
}

// ------------------------------------------------------------------- layers ---
__global__ __launch_bounds__(64) void pg_convP(
    const int2* __restrict__ pack, const int* __restrict__ cnt,
    const float* __restrict__ invdeg, const float* __restrict__ h,
    const float* __restrict__ Ws, const float* __restrict__ bs,
    const float* __restrict__ Wn, const float* __restrict__ bn,
    const float* __restrict__ cres, float* __restrict__ out)
{
  __shared__ float sh[64], sp2[64];
  int i = blockIdx.x, t = threadIdx.x;
  sh[t] = h[i * CH + t];
  int n = cnt[i];
  float acc = 0.0f;
  for (int q = 0; q < n; q++) {
    int2 p = pack[i * 64 + q];
    acc += __int_as_float(p.y) * h[(size_t)p.x * CH + t];
  }
  sp2[t] = acc * invdeg[i];
  __syncthreads();
  float a = bs[t] + bn[t] + 0.1f * cres[0] * sh[t];
  for (int k = 0; k < 64; k++) a += sh[k] * Ws[k * CH + t] + sp2[k] * Wn[k * CH + t];
  out[i * CH + t] = a / (1.0f + expf(-a));
}

__global__ __launch_bounds__(64) void pg_difffuse(
    const float* __restrict__ h2, const float* __restrict__ hd,
    const float* __restrict__ dW, const float* __restrict__ db, float* __restrict__ out)
{
  __shared__ float sh[3][64];
  int i = blockIdx.x, t = threadIdx.x;
  for (int s = 0; s < 3; s++) sh[s][t] = hd[(size_t)s * NPT * CH + i * CH + t];
  __syncthreads();
  float a = h2[i * CH + t] + db[t];
  for (int s = 0; s < 3; s++) {
    const float* w = dW + s * CH * CH;
    for (int k = 0; k < 64; k++) a += sh[s][k] * w[k * CH + t];
  }
  out[i * CH + t] = a;
}

// fused tanh-matvec + normalized-Laplacian gather + reaction-diffusion + LN
__global__ __launch_bounds__(64) void pg_tlr(
    const int2* __restrict__ pack, const int* __restrict__ cnt,
    const float* __restrict__ Dis, const float* __restrict__ cvec,
    const float* __restrict__ h3,
    const float* __restrict__ W1, const float* __restrict__ b1,
    const float* __restrict__ W2, const float* __restrict__ b2,
    const float* __restrict__ rdc,
    const float* __restrict__ g, const float* __restrict__ b,
    float* __restrict__ hio)
{
  __shared__ float sh[64], st[64];
  int i = blockIdx.x, t = threadIdx.x;
  sh[t] = h3[i * CH + t];
  __syncthreads();
  float a = b1[t];
  for (int k = 0; k < 64; k++) a += sh[k] * W1[k * CH + t];
  st[t] = tanhf(a);
  // L_norm @ h3 (gather)
  int n = cnt[i];
  float accL = 0.0f;
  for (int q = 0; q < n; q++) {
    int2 p = pack[i * 64 + q];
    accL += __int_as_float(p.y) * Dis[p.x] * h3[(size_t)p.x * CH + t];
  }
  float tLv = accL * Dis[i] - cvec[i] * sh[t];
  __syncthreads();
  float react = b2[t];
  for (int k = 0; k < 64; k++) react += st[k] * W2[k * CH + t];
  float x = sh[t] + 0.1f * (rdc[t] * tLv + react) + hio[i * CH + t];
  float s = x;
  for (int off = 1; off < 64; off <<= 1) s += __shfl_xor(s, off);
  float mu = s * (1.0f / 64.0f);
  float d = x - mu;
  float v = d * d;
  for (int off = 1; off < 64; off <<= 1) v += __shfl_xor(v, off);
  v *= (1.0f / 64.0f);
  hio[i * CH + t] = d * (1.0f / sqrtf(v + 1e-5f)) * g[t] + b[t];
}

// ---------------------------------------------------------------- attention ---
__global__ __launch_bounds__(64) void pg_qkv(
    const float* __restrict__ h,
    const float* __restrict__ Wq, const float* __restrict__ bq,
    const float* __restrict__ Wk, const float* __restrict__ bk,
    const float* __restrict__ Wv, const float* __restrict__ bv,
    float* __restrict__ q, float* __restrict__ kb, float* __restrict__ vb)
{
  __shared__ float sh[64];
  int i = blockIdx.x, t = threadIdx.x;
  sh[t] = h[i * CH + t];
  __syncthreads();
  float aq = bq[t], ak = bk[t], avv = bv[t];
  for (int k = 0; k < 64; k++) {
    float x = sh[k];
    aq += x * Wq[k * CH + t];
    ak += x * Wk[k * CH + t];
    avv += x * Wv[k * CH + t];
  }
  q[i * CH + t] = aq;
  kb[i * CH + t] = ak;
  vb[i * CH + t] = avv;
}

// CSR-masked attention + output projection + final linear, fused
__global__ __launch_bounds__(256) void pg_attn_out(
    const float* __restrict__ q, const float* __restrict__ kb, const float* __restrict__ vb,
    const int* __restrict__ nbr, const int* __restrict__ cnt,
    const float* __restrict__ Hc, const float* __restrict__ beta,
    const float* __restrict__ h,
    const float* __restrict__ Wo, const float* __restrict__ bo,
    const float* __restrict__ Wout, const float* __restrict__ bout,
    float* __restrict__ out)
{
  __shared__ float av_s[64];
  int i = blockIdx.x;
  int t = threadIdx.x;
  int head = t >> 6, lane = t & 63;
  float sp_b = logf(1.0f + expf(beta[head]));
  float hci = Hc[i];
  const float* qp = q + i * CH + head * 16;
  float qr[16];
#pragma unroll
  for (int d = 0; d < 16; d++) qr[d] = qp[d];
  int n = cnt[i];
  int K = n + 1;  // neighbors + self
  float mx = -1e30f, den = 0.0f;
  float vac[16];
#pragma unroll
  for (int d = 0; d < 16; d++) vac[d] = 0.0f;
  for (int m = lane; m < K; m += 64) {
    int j = (m == n) ? i : nbr[i * 64 + m];
    const float* kp = kb + (size_t)j * CH + head * 16;
    float sc = 0.0f;
#pragma unroll
    for (int d = 0; d < 16; d++) sc += qr[d] * kp[d];
    sc *= 0.25f;
    sc -= sp_b * fabsf(hci - Hc[j]);
    float nm = fmaxf(mx, sc);
    float corr = expf(mx - nm);
    float p = expf(sc - nm);
    den = den * corr + p;
    const float* vp = vb + (size_t)j * CH + head * 16;
#pragma unroll
    for (int d = 0; d < 16; d++) vac[d] = vac[d] * corr + p * vp[d];
    mx = nm;
  }
  for (int off = 32; off > 0; off >>= 1) {
    float omx = __shfl_down(mx, off);
    float oden = __shfl_down(den, off);
    float ov[16];
#pragma unroll
    for (int d = 0; d < 16; d++) ov[d] = __shfl_down(vac[d], off);
    float nm = fmaxf(mx, omx);
    float c1 = expf(mx - nm), c2 = expf(omx - nm);
    den = den * c1 + oden * c2;
#pragma unroll
    for (int d = 0; d < 16; d++) vac[d] = vac[d] * c1 + ov[d] * c2;
    mx = nm;
  }
  if (lane == 0) {
    float inv = 1.0f / den;
    for (int d = 0; d < 16; d++) av_s[head * 16 + d] = vac[d] * inv;
  }
  __syncthreads();
  if (t < 64) {
    float a = h[i * CH + t] + bo[t];
    for (int k = 0; k < 64; k++) a += av_s[k] * Wo[k * CH + t];
    float s = a * Wout[t];
    for (int off = 1; off < 64; off <<= 1) s += __shfl_xor(s, off);
    if (t == 0) out[i] = s + bout[0];
  }
}

// ------------------------------------------------------------------- launch ---
extern "C" void kernel_launch(void* const* d_in, const int* in_sizes, int n_in,
                              void* d_out, int out_size, void* d_ws, size_t ws_size,
                              hipStream_t stream)
{
  const float* pos   = (const float*)d_in[0];
  const float* adj   = (const float*)d_in[1];
  const float* Wc1   = (const float*)d_in[2];
  const float* bc1   = (const float*)d_in[3];
  const float* Wc2   = (const float*)d_in[4];
  const float* bc2   = (const float*)d_in[5];
  const float* Win   = (const float*)d_in[6];
  const float* b_in  = (const float*)d_in[7];
  const float* cWs   = (const float*)d_in[8];
  const float* cbs   = (const float*)d_in[9];
  const float* cWn   = (const float*)d_in[10];
  const float* cbn   = (const float*)d_in[11];
  const float* cres  = (const float*)d_in[12];
  const float* dW    = (const float*)d_in[13];
  const float* db    = (const float*)d_in[14];
  const float* rW1   = (const float*)d_in[15];
  const float* rb1   = (const float*)d_in[16];
  const float* rW2   = (const float*)d_in[17];
  const float* rb2   = (const float*)d_in[18];
  const float* rdc   = (const float*)d_in[19];
  const float* lng   = (const float*)d_in[20];
  const float* lnb   = (const float*)d_in[21];
  const float* Wq    = (const float*)d_in[22];
  const float* bq    = (const float*)d_in[23];
  const float* Wk    = (const float*)d_in[24];
  const float* bk    = (const float*)d_in[25];
  const float* Wv    = (const float*)d_in[26];
  const float* bv    = (const float*)d_in[27];
  const float* Wo    = (const float*)d_in[28];
  const float* bo    = (const float*)d_in[29];
  const float* abeta = (const float*)d_in[30];
  const float* Wout  = (const float*)d_in[31];
  const float* bout  = (const float*)d_in[32];

  const size_t NNe = (size_t)NPT * NPT;
  const size_t NC  = (size_t)NPT * CH;
  const size_t P   = NNe * 2;   // bytes per bf16 plane (8 MB)

  char* base = (char*)d_ws;
  bf16_t* E05h = (bf16_t*)(base + 0 * P);
  bf16_t* E05l = (bf16_t*)(base + 1 * P);
  bf16_t* E2h  = (bf16_t*)(base + 2 * P);
  bf16_t* E2l  = (bf16_t*)(base + 3 * P);
  bf16_t* E8h  = (bf16_t*)(base + 4 * P);
  bf16_t* E8l  = (bf16_t*)(base + 5 * P);
  bf16_t* SAh  = (bf16_t*)(base + 6 * P);
  bf16_t* SAl  = (bf16_t*)(base + 7 * P);
  bf16_t* SBh  = (bf16_t*)(base + 8 * P);   // aliases M0 (dead by then)
  bf16_t* SBl  = (bf16_t*)(base + 9 * P);
  float*  M0   = (float*)(base + 8 * P);    // 16 MB
  float*  M1   = (float*)(base + 10 * P);   // 16 MB
  bf16_t* XTh  = (bf16_t*)(base + 12 * P);
  bf16_t* XTl  = (bf16_t*)(base + 12 * P + NPT * CH * 2);
  float*  smb  = (float*)(base + 12 * P + 1024 * 1024);

  float* h   = smb;
  float* tA  = h + NC;
  float* tB  = tA + NC;
  float* hd  = tB + NC;        // 3*NC
  float* q   = hd + 3 * NC;
  float* kbf = q + NC;
  float* vbf = kbf + NC;
  float* raw = vbf + NC;       // NPT*6 padded to NC... use 8*NPT slot below
  float* sm  = raw + 8 * NPT;
  float* sumA   = sm;
  float* sumAD  = sm + NPT;
  float* wdeg   = sm + 2 * NPT;
  float* invdeg = sm + 3 * NPT;
  float* Dis    = sm + 4 * NPT;
  float* cvec   = sm + 5 * NPT;
  float* Hc     = sm + 6 * NPT;
  float* stats  = sm + 7 * NPT;
  int*   nbr    = (int*)(sm + 8 * NPT);        // NPT*64
  int*   cnt    = nbr + (size_t)NPT * 64;
  int2*  pack   = (int2*)(cnt + NPT);          // NPT*64 int2

  size_t need = 12 * P + 1024 * 1024
              + (9 * NC + 16 * (size_t)NPT) * 4
              + (size_t)NPT * 64 * 4 + NPT * 4 + (size_t)NPT * 64 * 8 + 256;
  if (ws_size < need) return;

  // geometry + CSR + features
  pg_geom_csr<<<NPT, 256, 0, stream>>>(pos, adj, raw, Hc, sumA, sumAD, nbr, cnt);
  pg_stats<<<1, 256, 0, stream>>>(raw, sumA, sumAD, stats);
  pg_wdeg<<<NPT, 64, 0, stream>>>(pos, nbr, cnt, stats, pack, wdeg, invdeg, Dis, cvec);
  pg_curv_mlp<<<NPT, 64, 0, stream>>>(pos, raw, stats, Wc1, bc1, Wc2, bc2, Win, b_in, h);

  // T = exp(L/32): XCD-striped Taylor-Horner, final pass emits bf16 hi/lo
  pg_tinit<<<512, 256, 0, stream>>>(pack, cnt, wdeg, M0);
  float* cur = M0;
  float* nxt = M1;
  for (int k = TDEG - 1; k >= 2; k--) {
    pg_h2<false><<<512, 256, 0, stream>>>(pack, cnt, wdeg, cur, nxt,
                                          1.0f / (SCL * (float)k), nullptr, nullptr);
    float* tmp = cur; cur = nxt; nxt = tmp;
  }
  pg_h2<true><<<512, 256, 0, stream>>>(pack, cnt, wdeg, cur, nullptr,
                                       1.0f / SCL, SAh, SAl);

  // squaring chain (symmetric): exp(L/32) -> ... -> exp(8L)
  pg_sq<<<256, 256, 0, stream>>>(SAh, SAl, SBh, SBl);     // L/16
  pg_sq<<<256, 256, 0, stream>>>(SBh, SBl, SAh, SAl);     // L/8
  pg_sq<<<256, 256, 0, stream>>>(SAh, SAl, SBh, SBl);     // L/4
  pg_sq<<<256, 256, 0, stream>>>(SBh, SBl, E05h, E05l);   // L/2
  pg_sq<<<256, 256, 0, stream>>>(E05h, E05l, SAh, SAl);   // L
  pg_sq<<<256, 256, 0, stream>>>(SAh, SAl, E2h, E2l);     // 2L
  pg_sq<<<256, 256, 0, stream>>>(E2h, E2l, SBh, SBl);     // 4L
  pg_sq<<<256, 256, 0, stream>>>(SBh, SBl, E8h, E8l);     // 8L

  // NL layers
  for (int i = 0; i < 4; i++) {
    pg_convP<<<NPT, 64, 0, stream>>>(pack, cnt, invdeg, h,
                                     cWs + i * 4096, cbs + i * 64,
                                     cWn + i * 4096, cbn + i * 64, cres + i, tA);
    float* h3 = tA;
    if ((i & 1) == 0) {
      int j = i >> 1;
      pg_splitx<<<32, 256, 0, stream>>>(tA, XTh, XTl);
      pg_emm<<<dim3(32, 3), 256, 0, stream>>>(E05h, E05l, E2h, E2l, E8h, E8l,
                                              XTh, XTl, hd);
      pg_difffuse<<<NPT, 64, 0, stream>>>(tA, hd, dW + j * 3 * 4096, db + j * 64, tB);
      h3 = tB;
    }
    pg_tlr<<<NPT, 64, 0, stream>>>(pack, cnt, Dis, cvec, h3,
                                   rW1 + i * 4096, rb1 + i * 64,
                                   rW2 + i * 4096, rb2 + i * 64,
                                   rdc + i * 64, lng + i * 64, lnb + i * 64, h);
  }

  // attention + output
  pg_qkv<<<NPT, 64, 0, stream>>>(h, Wq, bq, Wk, bk, Wv, bv, q, kbf, vbf);
  pg_attn_out<<<NPT, 256, 0, stream>>>(q, kbf, vbf, nbr, cnt, Hc, abeta,
                                       h, Wo, bo, Wout, bout, (float*)d_out);
}

// Round 4
// 1093.697 us; speedup vs baseline: 3.0755x; 1.3069x over previous
//
#include <hip/hip_runtime.h>
#include <math.h>

#define NPT 2048
#define CH 64
constexpr int TDEG = 12;        // Taylor degree for exp(L/32)
constexpr float SCL = 32.0f;    // scaling denominator

typedef __bf16 bf16_t;
typedef __bf16 bf16x8 __attribute__((ext_vector_type(8)));
typedef __bf16 bf16x4_t __attribute__((ext_vector_type(4)));
typedef float f32x4 __attribute__((ext_vector_type(4)));

__device__ __forceinline__ void gl_lds16(const void* g, void* l) {
  __builtin_amdgcn_global_load_lds(
      (const __attribute__((address_space(1))) void*)g,
      (__attribute__((address_space(3))) void*)l, 16, 0, 0);
}

// ------------------------------------------------- geometry + CSR (one scan) ---
__global__ __launch_bounds__(256) void pg_geom_csr(
    const float* __restrict__ pos, const float* __restrict__ adj,
    float* __restrict__ raw, float* __restrict__ Hc,
    float* __restrict__ sumA, float* __restrict__ sumAD,
    int* __restrict__ nbr, int* __restrict__ cnt)
{
  __shared__ float sp[NPT * 3];
  __shared__ float red[256 * 6];
  __shared__ int wsum[4];
  int i = blockIdx.x, t = threadIdx.x;
  for (int j = t; j < NPT * 3; j += 256) sp[j] = pos[j];
  __syncthreads();
  float px = sp[3 * i], py = sp[3 * i + 1], pz = sp[3 * i + 2];

  size_t base = (size_t)i * NPT + t * 8;
  float av[8];
  int c = 0;
  for (int u = 0; u < 8; u++) { av[u] = adj[base + u]; c += (av[u] != 0.0f); }
  // wave-level inclusive scan
  int sc = c;
  int lane = t & 63;
  for (int off = 1; off < 64; off <<= 1) {
    int v = __shfl_up(sc, off);
    if (lane >= off) sc += v;
  }
  if (lane == 63) wsum[t >> 6] = sc;
  __syncthreads();
  int wprefix = 0;
  for (int w = 0; w < (t >> 6); w++) wprefix += wsum[w];
  int o = wprefix + sc - c;
  int wr = 0;
  for (int u = 0; u < 8; u++)
    if (av[u] != 0.0f) { int p = o + wr; if (p < 64) nbr[i * 64 + p] = t * 8 + u; wr++; }

  // geometry sums from the same entries
  float s0 = 0, s1 = 0, s2 = 0, ax = 0, ay = 0, az = 0;
  for (int u = 0; u < 8; u++) {
    if (av[u] != 0.0f) {
      int j = t * 8 + u;
      float dx = sp[3 * j] - px, dy = sp[3 * j + 1] - py, dz = sp[3 * j + 2] - pz;
      float d2 = dx * dx + dy * dy + dz * dz + 1e-12f;
      float d = sqrtf(d2);
      s0 += 1.0f; s1 += d; s2 += d2;
      ax += sp[3 * j]; ay += sp[3 * j + 1]; az += sp[3 * j + 2];
    }
  }
  red[t * 6 + 0] = s0; red[t * 6 + 1] = s1; red[t * 6 + 2] = s2;
  red[t * 6 + 3] = ax; red[t * 6 + 4] = ay; red[t * 6 + 5] = az;
  __syncthreads();
  for (int s = 128; s > 0; s >>= 1) {
    if (t < s)
      for (int q = 0; q < 6; q++) red[t * 6 + q] += red[(t + s) * 6 + q];
    __syncthreads();
  }
  if (t == 0) {
    s0 = red[0]; s1 = red[1]; s2 = red[2]; ax = red[3]; ay = red[4]; az = red[5];
    float degc = fmaxf(s0, 1.0f);
    float dxm = ax / degc - px, dym = ay / degc - py, dzm = az / degc - pz;
    float H = 0.5f * sqrtf(dxm * dxm + dym * dym + dzm * dzm);
    float r = s1 / degc;
    float var = (s2 - 2.0f * r * s1 + r * r * s0) / degc;
    float sdev = sqrtf(var + 1e-12f);
    float k1 = H + sdev, k2 = H - sdev;
    raw[i * 6 + 0] = H;
    raw[i * 6 + 1] = k1 * k2;
    raw[i * 6 + 2] = k1;
    raw[i * 6 + 3] = k2;
    raw[i * 6 + 4] = 0.6366197723675814f * atanf((k1 + k2) / (k1 - k2 + 1e-6f));
    raw[i * 6 + 5] = sqrtf(0.5f * (k1 * k1 + k2 * k2));
    Hc[i] = H;
    sumA[i] = s0; sumAD[i] = s1;
    int tot = wsum[0] + wsum[1] + wsum[2] + wsum[3];
    cnt[i] = min(tot, 64);
  }
}

__global__ __launch_bounds__(256) void pg_stats(
    const float* __restrict__ raw, const float* __restrict__ sumA,
    const float* __restrict__ sumAD, float* __restrict__ stats)
{
  __shared__ float red[256];
  __shared__ float mean6[6];
  int t = threadIdx.x;
  float sa = 0, sad = 0;
  for (int j = t; j < NPT; j += 256) { sa += sumA[j]; sad += sumAD[j]; }
  red[t] = sa; __syncthreads();
  for (int s = 128; s > 0; s >>= 1) { if (t < s) red[t] += red[t + s]; __syncthreads(); }
  float totA = red[0]; __syncthreads();
  red[t] = sad; __syncthreads();
  for (int s = 128; s > 0; s >>= 1) { if (t < s) red[t] += red[t + s]; __syncthreads(); }
  float totAD = red[0]; __syncthreads();
  if (t == 0) {
    float sigma = fmaxf(totAD / fmaxf(totA, 1.0f), 1e-6f);
    stats[0] = 1.0f / (2.0f * sigma * sigma);
    stats[1] = sigma;
  }
  for (int q = 0; q < 6; q++) {
    float s = 0;
    for (int j = t; j < NPT; j += 256) s += raw[j * 6 + q];
    red[t] = s; __syncthreads();
    for (int k = 128; k > 0; k >>= 1) { if (t < k) red[t] += red[t + k]; __syncthreads(); }
    if (t == 0) mean6[q] = red[0] / (float)NPT;
    __syncthreads();
  }
  for (int q = 0; q < 6; q++) {
    float m = mean6[q], s = 0;
    for (int j = t; j < NPT; j += 256) { float d = raw[j * 6 + q] - m; s += d * d; }
    red[t] = s; __syncthreads();
    for (int k = 128; k > 0; k >>= 1) { if (t < k) red[t] += red[t + k]; __syncthreads(); }
    if (t == 0) {
      float sd = sqrtf(red[0] / (float)(NPT - 1));
      stats[2 + q] = m;
      stats[8 + q] = 1.0f / fmaxf(sd, 1e-6f);
    }
    __syncthreads();
  }
}

__global__ __launch_bounds__(64) void pg_wdeg(
    const float* __restrict__ pos, const int* __restrict__ nbr, const int* __restrict__ cnt,
    const float* __restrict__ stats, int2* __restrict__ pack, float* __restrict__ wdeg,
    float* __restrict__ invdeg, float* __restrict__ Dis, float* __restrict__ cvec)
{
  int i = blockIdx.x, t = threadIdx.x;
  int n = cnt[i];
  float inv2s2 = stats[0];
  float px = pos[3 * i], py = pos[3 * i + 1], pz = pos[3 * i + 2];
  float w = 0.0f;
  int j = 0;
  if (t < n) {
    j = nbr[i * 64 + t];
    float dx = pos[3 * j] - px, dy = pos[3 * j + 1] - py, dz = pos[3 * j + 2] - pz;
    float d2 = dx * dx + dy * dy + dz * dz + 1e-12f;
    w = expf(-d2 * inv2s2);
  }
  pack[i * 64 + t] = make_int2(j, __float_as_int(w));
  float s = w;
  for (int off = 1; off < 64; off <<= 1) s += __shfl_xor(s, off);
  if (t == 0) {
    float md = fmaxf(s, 1e-8f);
    wdeg[i] = s;
    invdeg[i] = 1.0f / md;
    float di = 1.0f / sqrtf(md);
    Dis[i] = di;
    cvec[i] = di * di * s;
  }
}

__global__ __launch_bounds__(64) void pg_curv_mlp(
    const float* __restrict__ pos, const float* __restrict__ raw, const float* __restrict__ stats,
    const float* __restrict__ Wc1, const float* __restrict__ bc1,
    const float* __restrict__ Wc2, const float* __restrict__ bc2,
    const float* __restrict__ Win, const float* __restrict__ b_in, float* __restrict__ h)
{
  __shared__ float feat[19];
  __shared__ float nraw[6];
  __shared__ float hid[32];
  int i = blockIdx.x, t = threadIdx.x;
  if (t < 3) feat[t] = pos[3 * i + t];
  if (t < 6) nraw[t] = (raw[i * 6 + t] - stats[2 + t]) * stats[8 + t];
  __syncthreads();
  if (t < 32) {
    float a = bc1[t];
    for (int k = 0; k < 6; k++) a += nraw[k] * Wc1[k * 32 + t];
    hid[t] = a / (1.0f + expf(-a));
  }
  __syncthreads();
  if (t < 16) {
    float a = bc2[t];
    for (int k = 0; k < 32; k++) a += hid[k] * Wc2[k * 16 + t];
    feat[3 + t] = a;
  }
  __syncthreads();
  float a = b_in[t];
  for (int k = 0; k < 19; k++) a += feat[k] * Win[k * CH + t];
  h[i * CH + t] = a;
}

// ---------------- exp(L/32): fully-fused Taylor-Horner, column stripes in LDS ---
// grid 512, block 256. Block owns 4 columns; [4][2048] f32 stripe ping-pong in
// LDS (pad 2056 so the 4-lane column group hits distinct banks). All TDEG-1
// steps + init + final bf16 hi/lo emission run in one launch. Output written
// transposed (valid: exp(L/32) is symmetric), 32B-contiguous stores.
__global__ __launch_bounds__(256) void pg_hfused(
    const int2* __restrict__ pack, const int* __restrict__ cnt,
    const float* __restrict__ wdeg,
    bf16_t* __restrict__ Th, bf16_t* __restrict__ Tl)
{
  __shared__ float Ys[2 * 4 * 2056];
  const int STRIDE = 2056, HALF = 4 * 2056;
  int t = threadIdx.x;
  int c = t & 3;
  int rg = t >> 2;            // 0..63
  int col = blockIdx.x * 4 + c;
  const float c0 = 1.0f / (SCL * (float)TDEG);
  const int cb0 = c * STRIDE;

  // init: Y = I + L/(SCL*TDEG)
  for (int rr = 0; rr < 32; rr++) {
    int r = rg + rr * 64;
    int n = cnt[r];
    float v = 0.0f;
    const int2* pr = pack + r * 64;
    for (int q = 0; q < n; q++) {
      int2 p = pr[q];
      if (p.x == col) v = __int_as_float(p.y);
    }
    Ys[cb0 + r] = (col == r) ? (1.0f - wdeg[r] * c0) : v * c0;
  }
  __syncthreads();

  int cur = 0;
  for (int k = TDEG - 1; k >= 1; k--) {
    float invc = 1.0f / (SCL * (float)k);
    const float* Yin = Ys + cur + cb0;
    float* Yout = Ys + (cur ^ HALF) + cb0;
    bool last = (k == 1);
    for (int rr = 0; rr < 32; rr++) {
      int r = rg + rr * 64;
      int n = cnt[r];
      int nn = (n + 3) & ~3;     // pack rows are zero-padded to 64 entries
      const int2* pr = pack + r * 64;
      float acc0 = -wdeg[r] * Yin[r];
      float acc1 = 0.0f, acc2 = 0.0f, acc3 = 0.0f;
      for (int q = 0; q < nn; q += 4) {
        int2 p0 = pr[q], p1 = pr[q + 1], p2 = pr[q + 2], p3 = pr[q + 3];
        acc0 += __int_as_float(p0.y) * Yin[p0.x];
        acc1 += __int_as_float(p1.y) * Yin[p1.x];
        acc2 += __int_as_float(p2.y) * Yin[p2.x];
        acc3 += __int_as_float(p3.y) * Yin[p3.x];
      }
      float val = ((r == col) ? 1.0f : 0.0f) + ((acc0 + acc1) + (acc2 + acc3)) * invc;
      if (last) {
        __bf16 hb = (__bf16)val;
        Th[(size_t)col * NPT + r] = hb;               // transposed (symmetric)
        Tl[(size_t)col * NPT + r] = (__bf16)(val - (float)hb);
      } else {
        Yout[r] = val;
      }
    }
    __syncthreads();
    cur ^= HALF;
  }
}

// ------------- symmetric squaring: C = A*A, A symmetric, split-bf16 3-term MFMA
__global__ __launch_bounds__(256) void pg_sq(
    const bf16_t* __restrict__ Ah, const bf16_t* __restrict__ Al,
    bf16_t* __restrict__ Ch, bf16_t* __restrict__ Cl)
{
  __shared__ __align__(16) char smem[131072];  // 2 bufs x 4 tiles x 16 KB
  const int t = threadIdx.x;
  const int w = t >> 6, l = t & 63;
  const int lrow = l & 15, lhi = l >> 4;
  int bid = blockIdx.x;
  int sbid = (bid & 7) * 32 + (bid >> 3);
  const int by = sbid >> 4, bx = sbid & 15;
  const int wr = w >> 1, wc = w & 1;

  int offA[4], offB[4];
#pragma unroll
  for (int it = 0; it < 4; it++) {
    int o = it * 4096 + t * 16;
    int r = o >> 7;
    int cb = (o & 127) ^ ((r & 7) << 4);
    offA[it] = (by * 128 + r) * (NPT * 2) + cb;
    offB[it] = (bx * 128 + r) * (NPT * 2) + cb;
  }
  int aoff[4][2], boff[4][2];
#pragma unroll
  for (int m = 0; m < 4; m++) {
    int arow = wr * 64 + m * 16 + lrow;
    int brow = wc * 64 + m * 16 + lrow;
#pragma unroll
    for (int kk = 0; kk < 2; kk++) {
      int kb = kk * 64 + lhi * 16;
      aoff[m][kk] = arow * 128 + (kb ^ ((arow & 7) << 4));
      boff[m][kk] = brow * 128 + (kb ^ ((brow & 7) << 4));
    }
  }

  f32x4 acc[4][4];
#pragma unroll
  for (int m = 0; m < 4; m++)
#pragma unroll
    for (int n = 0; n < 4; n++) acc[m][n] = (f32x4){0.f, 0.f, 0.f, 0.f};

  const int lofs_w = w << 10;
#pragma unroll
  for (int it = 0; it < 4; it++) {
    int lo = it * 4096 + lofs_w;
    gl_lds16((const char*)Ah + offA[it], smem + lo);
    gl_lds16((const char*)Al + offA[it], smem + 16384 + lo);
    gl_lds16((const char*)Ah + offB[it], smem + 32768 + lo);
    gl_lds16((const char*)Al + offB[it], smem + 49152 + lo);
  }
  __syncthreads();

  for (int ks = 0; ks < NPT / 64; ks++) {
    if (ks + 1 < NPT / 64) {
      char* nbuf = smem + ((ks + 1) & 1) * 65536;
      size_t kadv = (size_t)(ks + 1) * 128;
#pragma unroll
      for (int it = 0; it < 4; it++) {
        int lo = it * 4096 + lofs_w;
        gl_lds16((const char*)Ah + offA[it] + kadv, nbuf + lo);
        gl_lds16((const char*)Al + offA[it] + kadv, nbuf + 16384 + lo);
        gl_lds16((const char*)Ah + offB[it] + kadv, nbuf + 32768 + lo);
        gl_lds16((const char*)Al + offB[it] + kadv, nbuf + 49152 + lo);
      }
    }
    const char* cbuf = smem + (ks & 1) * 65536;
#pragma unroll
    for (int kk = 0; kk < 2; kk++) {
      bf16x8 bhf[4], blf[4];
#pragma unroll
      for (int n = 0; n < 4; n++) {
        bhf[n] = *(const bf16x8*)(cbuf + 32768 + boff[n][kk]);
        blf[n] = *(const bf16x8*)(cbuf + 49152 + boff[n][kk]);
      }
#pragma unroll
      for (int m = 0; m < 4; m++) {
        bf16x8 ah = *(const bf16x8*)(cbuf + aoff[m][kk]);
        bf16x8 al = *(const bf16x8*)(cbuf + 16384 + aoff[m][kk]);
#pragma unroll
        for (int n = 0; n < 4; n++) {
          acc[m][n] = __builtin_amdgcn_mfma_f32_16x16x32_bf16(al, bhf[n], acc[m][n], 0, 0, 0);
          acc[m][n] = __builtin_amdgcn_mfma_f32_16x16x32_bf16(ah, blf[n], acc[m][n], 0, 0, 0);
          acc[m][n] = __builtin_amdgcn_mfma_f32_16x16x32_bf16(ah, bhf[n], acc[m][n], 0, 0, 0);
        }
      }
    }
    __syncthreads();
  }

  const int gr0 = by * 128 + wr * 64 + lhi * 4;
  const int gc0 = bx * 128 + wc * 64 + lrow;
#pragma unroll
  for (int m = 0; m < 4; m++) {
#pragma unroll
    for (int n = 0; n < 4; n++) {
      int gc = gc0 + n * 16;
#pragma unroll
      for (int r = 0; r < 4; r++) {
        float c = acc[m][n][r];
        __bf16 hb = (__bf16)c;
        size_t o = (size_t)(gr0 + m * 16 + r) * NPT + gc;
        Ch[o] = hb;
        Cl[o] = (__bf16)(c - (float)hb);
      }
    }
  }
}

// ------------------- X (2048x64 f32) -> XT hi/lo bf16 (64x2048), LDS transpose ---
__global__ __launch_bounds__(256) void pg_splitx(
    const float* __restrict__ X, bf16_t* __restrict__ XTh, bf16_t* __restrict__ XTl)
{
  __shared__ float sX[64][65];
  int t = threadIdx.x;
  int r0 = blockIdx.x * 64;
  for (int u = 0; u < 16; u++) {
    int idx = u * 256 + t;           // 0..4095
    int r = idx >> 6, c = idx & 63;
    sX[r][c] = X[(size_t)(r0 + r) * CH + c];
  }
  __syncthreads();
  int c = t >> 6;         // 0..3
  int rr = t & 63;        // 0..63
  for (int cc = c; cc < 64; cc += 4) {
    float v = sX[rr][cc];
    __bf16 hb = (__bf16)v;
    XTh[(size_t)cc * NPT + r0 + rr] = hb;
    XTl[(size_t)cc * NPT + r0 + rr] = (__bf16)(v - (float)hb);
  }
}

// ---------- hd[scale] = E_scale @ X  via MFMA; grid (32 row-blocks, 3 scales) ---
__global__ __launch_bounds__(256) void pg_emm(
    const bf16_t* __restrict__ E05h, const bf16_t* __restrict__ E05l,
    const bf16_t* __restrict__ E2h,  const bf16_t* __restrict__ E2l,
    const bf16_t* __restrict__ E8h,  const bf16_t* __restrict__ E8l,
    const bf16_t* __restrict__ XTh,  const bf16_t* __restrict__ XTl,
    float* __restrict__ hd)
{
  __shared__ __align__(16) char smem[65536];  // 2 bufs x 4 tiles x 8 KB
  const int t = threadIdx.x;
  const int w = t >> 6, l = t & 63;
  const int lrow = l & 15, lhi = l >> 4;
  const int scale = blockIdx.y;
  const bf16_t* Eh = (scale == 0) ? E05h : (scale == 1) ? E2h : E8h;
  const bf16_t* El = (scale == 0) ? E05l : (scale == 1) ? E2l : E8l;
  const int rb = blockIdx.x;  // 64-row block

  int offA[2], offB[2];
#pragma unroll
  for (int it = 0; it < 2; it++) {
    int o = it * 4096 + t * 16;
    int r = o >> 7;
    int cb = (o & 127) ^ ((r & 7) << 4);
    offA[it] = (rb * 64 + r) * (NPT * 2) + cb;
    offB[it] = r * (NPT * 2) + cb;
  }
  int aoff[2], boff[4][2];
  {
    int arow = w * 16 + lrow;
#pragma unroll
    for (int kk = 0; kk < 2; kk++) {
      int kb = kk * 64 + lhi * 16;
      aoff[kk] = arow * 128 + (kb ^ ((arow & 7) << 4));
    }
  }
#pragma unroll
  for (int n = 0; n < 4; n++) {
    int brow = n * 16 + lrow;
#pragma unroll
    for (int kk = 0; kk < 2; kk++) {
      int kb = kk * 64 + lhi * 16;
      boff[n][kk] = brow * 128 + (kb ^ ((brow & 7) << 4));
    }
  }

  f32x4 acc[4];
#pragma unroll
  for (int n = 0; n < 4; n++) acc[n] = (f32x4){0.f, 0.f, 0.f, 0.f};

  const int lofs_w = w << 10;
#pragma unroll
  for (int it = 0; it < 2; it++) {
    int lo = it * 4096 + lofs_w;
    gl_lds16((const char*)Eh  + offA[it], smem + lo);
    gl_lds16((const char*)El  + offA[it], smem + 8192 + lo);
    gl_lds16((const char*)XTh + offB[it], smem + 16384 + lo);
    gl_lds16((const char*)XTl + offB[it], smem + 24576 + lo);
  }
  __syncthreads();

  for (int ks = 0; ks < NPT / 64; ks++) {
    if (ks + 1 < NPT / 64) {
      char* nbuf = smem + ((ks + 1) & 1) * 32768;
      size_t kadv = (size_t)(ks + 1) * 128;
#pragma unroll
      for (int it = 0; it < 2; it++) {
        int lo = it * 4096 + lofs_w;
        gl_lds16((const char*)Eh  + offA[it] + kadv, nbuf + lo);
        gl_lds16((const char*)El  + offA[it] + kadv, nbuf + 8192 + lo);
        gl_lds16((const char*)XTh + offB[it] + kadv, nbuf + 16384 + lo);
        gl_lds16((const char*)XTl + offB[it] + kadv, nbuf + 24576 + lo);
      }
    }
    const char* cbuf = smem + (ks & 1) * 32768;
#pragma unroll
    for (int kk = 0; kk < 2; kk++) {
      bf16x8 ah = *(const bf16x8*)(cbuf + aoff[kk]);
      bf16x8 al = *(const bf16x8*)(cbuf + 8192 + aoff[kk]);
#pragma unroll
      for (int n = 0; n < 4; n++) {
        bf16x8 bh = *(const bf16x8*)(cbuf + 16384 + boff[n][kk]);
        bf16x8 bl = *(const bf16x8*)(cbuf + 24576 + boff[n][kk]);
        acc[n] = __builtin_amdgcn_mfma_f32_16x16x32_bf16(al, bh, acc[n], 0, 0, 0);
        acc[n] = __builtin_amdgcn_mfma_f32_16x16x32_bf16(ah, bl, acc[n], 0, 0, 0);
        acc[n] = __builtin_amdgcn_mfma_f32_16x16x32_bf16(ah, bh, acc[n], 0, 0, 0);
      }
    }
    __syncthreads();
  }

  float* Y = hd + (size_t)scale * NPT * CH;
  const int gr0 = rb * 64 + w * 16 + lhi * 4;
#pragma unroll
  for (int n = 0; n < 4; n++) {
    int gc = n * 16 + lrow;
#pragma unroll
    for (int r = 0; r < 4; r++)
      Y[(size_t)(gr0 + r) * CH + gc] = acc[n][r];
  }
}

// ------------------------------------------------------------------- layers ---
__global__ __launch_bounds__(64) void pg_convP(
    const int2* __restrict__ pack, const int* __restrict__ cnt,
    const float* __restrict__ invdeg, const float* __restrict__ h,
    const float* __restrict__ Ws, const float* __restrict__ bs,
    const float* __restrict__ Wn, const float* __restrict__ bn,
    const float* __restrict__ cres, float* __restrict__ out)
{
  __shared__ float sh[64], sp2[64];
  int i = blockIdx.x, t = threadIdx.x;
  sh[t] = h[i * CH + t];
  int n = cnt[i];
  float acc = 0.0f;
  for (int q = 0; q < n; q++) {
    int2 p = pack[i * 64 + q];
    acc += __int_as_float(p.y) * h[(size_t)p.x * CH + t];
  }
  sp2[t] = acc * invdeg[i];
  __syncthreads();
  float a = bs[t] + bn[t] + 0.1f * cres[0] * sh[t];
  for (int k = 0; k < 64; k++) a += sh[k] * Ws[k * CH + t] + sp2[k] * Wn[k * CH + t];
  out[i * CH + t] = a / (1.0f + expf(-a));
}

__global__ __launch_bounds__(64) void pg_difffuse(
    const float* __restrict__ h2, const float* __restrict__ hd,
    const float* __restrict__ dW, const float* __restrict__ db, float* __restrict__ out)
{
  __shared__ float sh[3][64];
  int i = blockIdx.x, t = threadIdx.x;
  for (int s = 0; s < 3; s++) sh[s][t] = hd[(size_t)s * NPT * CH + i * CH + t];
  __syncthreads();
  float a = h2[i * CH + t] + db[t];
  for (int s = 0; s < 3; s++) {
    const float* w = dW + s * CH * CH;
    for (int k = 0; k < 64; k++) a += sh[s][k] * w[k * CH + t];
  }
  out[i * CH + t] = a;
}

// fused tanh-matvec + normalized-Laplacian gather + reaction-diffusion + LN
__global__ __launch_bounds__(64) void pg_tlr(
    const int2* __restrict__ pack, const int* __restrict__ cnt,
    const float* __restrict__ Dis, const float* __restrict__ cvec,
    const float* __restrict__ h3,
    const float* __restrict__ W1, const float* __restrict__ b1,
    const float* __restrict__ W2, const float* __restrict__ b2,
    const float* __restrict__ rdc,
    const float* __restrict__ g, const float* __restrict__ b,
    float* __restrict__ hio)
{
  __shared__ float sh[64], st[64];
  int i = blockIdx.x, t = threadIdx.x;
  sh[t] = h3[i * CH + t];
  __syncthreads();
  float a = b1[t];
  for (int k = 0; k < 64; k++) a += sh[k] * W1[k * CH + t];
  st[t] = tanhf(a);
  int n = cnt[i];
  float accL = 0.0f;
  for (int q = 0; q < n; q++) {
    int2 p = pack[i * 64 + q];
    accL += __int_as_float(p.y) * Dis[p.x] * h3[(size_t)p.x * CH + t];
  }
  float tLv = accL * Dis[i] - cvec[i] * sh[t];
  __syncthreads();
  float react = b2[t];
  for (int k = 0; k < 64; k++) react += st[k] * W2[k * CH + t];
  float x = sh[t] + 0.1f * (rdc[t] * tLv + react) + hio[i * CH + t];
  float s = x;
  for (int off = 1; off < 64; off <<= 1) s += __shfl_xor(s, off);
  float mu = s * (1.0f / 64.0f);
  float d = x - mu;
  float v = d * d;
  for (int off = 1; off < 64; off <<= 1) v += __shfl_xor(v, off);
  v *= (1.0f / 64.0f);
  hio[i * CH + t] = d * (1.0f / sqrtf(v + 1e-5f)) * g[t] + b[t];
}

// ---------------------------------------------------------------- attention ---
__global__ __launch_bounds__(64) void pg_qkv(
    const float* __restrict__ h,
    const float* __restrict__ Wq, const float* __restrict__ bq,
    const float* __restrict__ Wk, const float* __restrict__ bk,
    const float* __restrict__ Wv, const float* __restrict__ bv,
    float* __restrict__ q, float* __restrict__ kb, float* __restrict__ vb)
{
  __shared__ float sh[64];
  int i = blockIdx.x, t = threadIdx.x;
  sh[t] = h[i * CH + t];
  __syncthreads();
  float aq = bq[t], ak = bk[t], avv = bv[t];
  for (int k = 0; k < 64; k++) {
    float x = sh[k];
    aq += x * Wq[k * CH + t];
    ak += x * Wk[k * CH + t];
    avv += x * Wv[k * CH + t];
  }
  q[i * CH + t] = aq;
  kb[i * CH + t] = ak;
  vb[i * CH + t] = avv;
}

// CSR-masked attention + output projection + final linear, fused
__global__ __launch_bounds__(256) void pg_attn_out(
    const float* __restrict__ q, const float* __restrict__ kb, const float* __restrict__ vb,
    const int* __restrict__ nbr, const int* __restrict__ cnt,
    const float* __restrict__ Hc, const float* __restrict__ beta,
    const float* __restrict__ h,
    const float* __restrict__ Wo, const float* __restrict__ bo,
    const float* __restrict__ Wout, const float* __restrict__ bout,
    float* __restrict__ out)
{
  __shared__ float av_s[64];
  int i = blockIdx.x;
  int t = threadIdx.x;
  int head = t >> 6, lane = t & 63;
  float sp_b = logf(1.0f + expf(beta[head]));
  float hci = Hc[i];
  const float* qp = q + i * CH + head * 16;
  float qr[16];
#pragma unroll
  for (int d = 0; d < 16; d++) qr[d] = qp[d];
  int n = cnt[i];
  int K = n + 1;  // neighbors + self
  float mx = -1e30f, den = 0.0f;
  float vac[16];
#pragma unroll
  for (int d = 0; d < 16; d++) vac[d] = 0.0f;
  for (int m = lane; m < K; m += 64) {
    int j = (m == n) ? i : nbr[i * 64 + m];
    const float* kp = kb + (size_t)j * CH + head * 16;
    float sc = 0.0f;
#pragma unroll
    for (int d = 0; d < 16; d++) sc += qr[d] * kp[d];
    sc *= 0.25f;
    sc -= sp_b * fabsf(hci - Hc[j]);
    float nm = fmaxf(mx, sc);
    float corr = expf(mx - nm);
    float p = expf(sc - nm);
    den = den * corr + p;
    const float* vp = vb + (size_t)j * CH + head * 16;
#pragma unroll
    for (int d = 0; d < 16; d++) vac[d] = vac[d] * corr + p * vp[d];
    mx = nm;
  }
  for (int off = 32; off > 0; off >>= 1) {
    float omx = __shfl_down(mx, off);
    float oden = __shfl_down(den, off);
    float ov[16];
#pragma unroll
    for (int d = 0; d < 16; d++) ov[d] = __shfl_down(vac[d], off);
    float nm = fmaxf(mx, omx);
    float c1 = expf(mx - nm), c2 = expf(omx - nm);
    den = den * c1 + oden * c2;
#pragma unroll
    for (int d = 0; d < 16; d++) vac[d] = vac[d] * c1 + ov[d] * c2;
    mx = nm;
  }
  if (lane == 0) {
    float inv = 1.0f / den;
    for (int d = 0; d < 16; d++) av_s[head * 16 + d] = vac[d] * inv;
  }
  __syncthreads();
  if (t < 64) {
    float a = h[i * CH + t] + bo[t];
    for (int k = 0; k < 64; k++) a += av_s[k] * Wo[k * CH + t];
    float s = a * Wout[t];
    for (int off = 1; off < 64; off <<= 1) s += __shfl_xor(s, off);
    if (t == 0) out[i] = s + bout[0];
  }
}

// ------------------------------------------------------------------- launch ---
extern "C" void kernel_launch(void* const* d_in, const int* in_sizes, int n_in,
                              void* d_out, int out_size, void* d_ws, size_t ws_size,
                              hipStream_t stream)
{
  const float* pos   = (const float*)d_in[0];
  const float* adj   = (const float*)d_in[1];
  const float* Wc1   = (const float*)d_in[2];
  const float* bc1   = (const float*)d_in[3];
  const float* Wc2   = (const float*)d_in[4];
  const float* bc2   = (const float*)d_in[5];
  const float* Win   = (const float*)d_in[6];
  const float* b_in  = (const float*)d_in[7];
  const float* cWs   = (const float*)d_in[8];
  const float* cbs   = (const float*)d_in[9];
  const float* cWn   = (const float*)d_in[10];
  const float* cbn   = (const float*)d_in[11];
  const float* cres  = (const float*)d_in[12];
  const float* dW    = (const float*)d_in[13];
  const float* db    = (const float*)d_in[14];
  const float* rW1   = (const float*)d_in[15];
  const float* rb1   = (const float*)d_in[16];
  const float* rW2   = (const float*)d_in[17];
  const float* rb2   = (const float*)d_in[18];
  const float* rdc   = (const float*)d_in[19];
  const float* lng   = (const float*)d_in[20];
  const float* lnb   = (const float*)d_in[21];
  const float* Wq    = (const float*)d_in[22];
  const float* bq    = (const float*)d_in[23];
  const float* Wk    = (const float*)d_in[24];
  const float* bk    = (const float*)d_in[25];
  const float* Wv    = (const float*)d_in[26];
  const float* bv    = (const float*)d_in[27];
  const float* Wo    = (const float*)d_in[28];
  const float* bo    = (const float*)d_in[29];
  const float* abeta = (const float*)d_in[30];
  const float* Wout  = (const float*)d_in[31];
  const float* bout  = (const float*)d_in[32];

  const size_t NNe = (size_t)NPT * NPT;
  const size_t NC  = (size_t)NPT * CH;
  const size_t P   = NNe * 2;   // bytes per bf16 plane (8 MB)

  char* base = (char*)d_ws;
  bf16_t* E05h = (bf16_t*)(base + 0 * P);
  bf16_t* E05l = (bf16_t*)(base + 1 * P);
  bf16_t* E2h  = (bf16_t*)(base + 2 * P);
  bf16_t* E2l  = (bf16_t*)(base + 3 * P);
  bf16_t* E8h  = (bf16_t*)(base + 4 * P);
  bf16_t* E8l  = (bf16_t*)(base + 5 * P);
  bf16_t* SAh  = (bf16_t*)(base + 6 * P);
  bf16_t* SAl  = (bf16_t*)(base + 7 * P);
  bf16_t* SBh  = (bf16_t*)(base + 8 * P);
  bf16_t* SBl  = (bf16_t*)(base + 9 * P);
  bf16_t* XTh  = (bf16_t*)(base + 12 * P);
  bf16_t* XTl  = (bf16_t*)(base + 12 * P + NPT * CH * 2);
  float*  smb  = (float*)(base + 12 * P + 1024 * 1024);

  float* h   = smb;
  float* tA  = h + NC;
  float* tB  = tA + NC;
  float* hd  = tB + NC;        // 3*NC
  float* q   = hd + 3 * NC;
  float* kbf = q + NC;
  float* vbf = kbf + NC;
  float* raw = vbf + NC;       // NPT*6 padded; small region follows
  float* sm  = raw + 8 * NPT;
  float* sumA   = sm;
  float* sumAD  = sm + NPT;
  float* wdeg   = sm + 2 * NPT;
  float* invdeg = sm + 3 * NPT;
  float* Dis    = sm + 4 * NPT;
  float* cvec   = sm + 5 * NPT;
  float* Hc     = sm + 6 * NPT;
  float* stats  = sm + 7 * NPT;
  int*   nbr    = (int*)(sm + 8 * NPT);        // NPT*64
  int*   cnt    = nbr + (size_t)NPT * 64;
  int2*  pack   = (int2*)(cnt + NPT);          // NPT*64 int2

  size_t need = 12 * P + 1024 * 1024
              + (9 * NC + 16 * (size_t)NPT) * 4
              + (size_t)NPT * 64 * 4 + NPT * 4 + (size_t)NPT * 64 * 8 + 256;
  if (ws_size < need) return;

  // geometry + CSR + features
  pg_geom_csr<<<NPT, 256, 0, stream>>>(pos, adj, raw, Hc, sumA, sumAD, nbr, cnt);
  pg_stats<<<1, 256, 0, stream>>>(raw, sumA, sumAD, stats);
  pg_wdeg<<<NPT, 64, 0, stream>>>(pos, nbr, cnt, stats, pack, wdeg, invdeg, Dis, cvec);
  pg_curv_mlp<<<NPT, 64, 0, stream>>>(pos, raw, stats, Wc1, bc1, Wc2, bc2, Win, b_in, h);

  // T = exp(L/32): fully fused LDS-resident Taylor-Horner, emits bf16 hi/lo
  pg_hfused<<<512, 256, 0, stream>>>(pack, cnt, wdeg, SAh, SAl);

  // squaring chain (symmetric): exp(L/32) -> ... -> exp(8L)
  pg_sq<<<256, 256, 0, stream>>>(SAh, SAl, SBh, SBl);     // L/16
  pg_sq<<<256, 256, 0, stream>>>(SBh, SBl, SAh, SAl);     // L/8
  pg_sq<<<256, 256, 0, stream>>>(SAh, SAl, SBh, SBl);     // L/4
  pg_sq<<<256, 256, 0, stream>>>(SBh, SBl, E05h, E05l);   // L/2
  pg_sq<<<256, 256, 0, stream>>>(E05h, E05l, SAh, SAl);   // L
  pg_sq<<<256, 256, 0, stream>>>(SAh, SAl, E2h, E2l);     // 2L
  pg_sq<<<256, 256, 0, stream>>>(E2h, E2l, SBh, SBl);     // 4L
  pg_sq<<<256, 256, 0, stream>>>(SBh, SBl, E8h, E8l);     // 8L

  // NL layers
  for (int i = 0; i < 4; i++) {
    pg_convP<<<NPT, 64, 0, stream>>>(pack, cnt, invdeg, h,
                                     cWs + i * 4096, cbs + i * 64,
                                     cWn + i * 4096, cbn + i * 64, cres + i, tA);
    float* h3 = tA;
    if ((i & 1) == 0) {
      int j = i >> 1;
      pg_splitx<<<32, 256, 0, stream>>>(tA, XTh, XTl);
      pg_emm<<<dim3(32, 3), 256, 0, stream>>>(E05h, E05l, E2h, E2l, E8h, E8l,
                                              XTh, XTl, hd);
      pg_difffuse<<<NPT, 64, 0, stream>>>(tA, hd, dW + j * 3 * 4096, db + j * 64, tB);
      h3 = tB;
    }
    pg_tlr<<<NPT, 64, 0, stream>>>(pack, cnt, Dis, cvec, h3,
                                   rW1 + i * 4096, rb1 + i * 64,
                                   rW2 + i * 4096, rb2 + i * 64,
                                   rdc + i * 64, lng + i * 64, lnb + i * 64, h);
  }

  // attention + output
  pg_qkv<<<NPT, 64, 0, stream>>>(h, Wq, bq, Wk, bk, Wv, bv, q, kbf, vbf);
  pg_attn_out<<<NPT, 256, 0, stream>>>(q, kbf, vbf, nbr, cnt, Hc, abeta,
                                       h, Wo, bo, Wout, bout, (float*)d_out);
}

// Round 5
// 791.858 us; speedup vs baseline: 4.2478x; 1.3812x over previous
//
#include <hip/hip_runtime.h>
#include <math.h>

#define NPT 2048
#define CH 64
constexpr int TDEG = 12;        // Taylor degree for exp(L/32)
constexpr float SCL = 32.0f;    // scaling denominator

typedef __bf16 bf16_t;
typedef __bf16 bf16x8 __attribute__((ext_vector_type(8)));
typedef __bf16 bf16x4_t __attribute__((ext_vector_type(4)));
typedef float f32x4 __attribute__((ext_vector_type(4)));

__device__ __forceinline__ void gl_lds16(const void* g, void* l) {
  __builtin_amdgcn_global_load_lds(
      (const __attribute__((address_space(1))) void*)g,
      (__attribute__((address_space(3))) void*)l, 16, 0, 0);
}

// ------------------------------------------------- geometry + CSR (one scan) ---
__global__ __launch_bounds__(256) void pg_geom_csr(
    const float* __restrict__ pos, const float* __restrict__ adj,
    float* __restrict__ raw, float* __restrict__ Hc,
    float* __restrict__ sumA, float* __restrict__ sumAD,
    int* __restrict__ nbr, int* __restrict__ cnt)
{
  __shared__ float sp[NPT * 3];
  __shared__ float red[256 * 6];
  __shared__ int wsum[4];
  int i = blockIdx.x, t = threadIdx.x;
  for (int j = t; j < NPT * 3; j += 256) sp[j] = pos[j];
  __syncthreads();
  float px = sp[3 * i], py = sp[3 * i + 1], pz = sp[3 * i + 2];

  size_t base = (size_t)i * NPT + t * 8;
  float av[8];
  int c = 0;
  for (int u = 0; u < 8; u++) { av[u] = adj[base + u]; c += (av[u] != 0.0f); }
  int sc = c;
  int lane = t & 63;
  for (int off = 1; off < 64; off <<= 1) {
    int v = __shfl_up(sc, off);
    if (lane >= off) sc += v;
  }
  if (lane == 63) wsum[t >> 6] = sc;
  __syncthreads();
  int wprefix = 0;
  for (int w = 0; w < (t >> 6); w++) wprefix += wsum[w];
  int o = wprefix + sc - c;
  int wr = 0;
  for (int u = 0; u < 8; u++)
    if (av[u] != 0.0f) { int p = o + wr; if (p < 64) nbr[i * 64 + p] = t * 8 + u; wr++; }

  float s0 = 0, s1 = 0, s2 = 0, ax = 0, ay = 0, az = 0;
  for (int u = 0; u < 8; u++) {
    if (av[u] != 0.0f) {
      int j = t * 8 + u;
      float dx = sp[3 * j] - px, dy = sp[3 * j + 1] - py, dz = sp[3 * j + 2] - pz;
      float d2 = dx * dx + dy * dy + dz * dz + 1e-12f;
      float d = sqrtf(d2);
      s0 += 1.0f; s1 += d; s2 += d2;
      ax += sp[3 * j]; ay += sp[3 * j + 1]; az += sp[3 * j + 2];
    }
  }
  red[t * 6 + 0] = s0; red[t * 6 + 1] = s1; red[t * 6 + 2] = s2;
  red[t * 6 + 3] = ax; red[t * 6 + 4] = ay; red[t * 6 + 5] = az;
  __syncthreads();
  for (int s = 128; s > 0; s >>= 1) {
    if (t < s)
      for (int q = 0; q < 6; q++) red[t * 6 + q] += red[(t + s) * 6 + q];
    __syncthreads();
  }
  if (t == 0) {
    s0 = red[0]; s1 = red[1]; s2 = red[2]; ax = red[3]; ay = red[4]; az = red[5];
    float degc = fmaxf(s0, 1.0f);
    float dxm = ax / degc - px, dym = ay / degc - py, dzm = az / degc - pz;
    float H = 0.5f * sqrtf(dxm * dxm + dym * dym + dzm * dzm);
    float r = s1 / degc;
    float var = (s2 - 2.0f * r * s1 + r * r * s0) / degc;
    float sdev = sqrtf(var + 1e-12f);
    float k1 = H + sdev, k2 = H - sdev;
    raw[i * 6 + 0] = H;
    raw[i * 6 + 1] = k1 * k2;
    raw[i * 6 + 2] = k1;
    raw[i * 6 + 3] = k2;
    raw[i * 6 + 4] = 0.6366197723675814f * atanf((k1 + k2) / (k1 - k2 + 1e-6f));
    raw[i * 6 + 5] = sqrtf(0.5f * (k1 * k1 + k2 * k2));
    Hc[i] = H;
    sumA[i] = s0; sumAD[i] = s1;
    int tot = wsum[0] + wsum[1] + wsum[2] + wsum[3];
    cnt[i] = min(tot, 64);
  }
}

__global__ __launch_bounds__(256) void pg_stats(
    const float* __restrict__ raw, const float* __restrict__ sumA,
    const float* __restrict__ sumAD, float* __restrict__ stats)
{
  __shared__ float red[256];
  __shared__ float mean6[6];
  int t = threadIdx.x;
  float sa = 0, sad = 0;
  for (int j = t; j < NPT; j += 256) { sa += sumA[j]; sad += sumAD[j]; }
  red[t] = sa; __syncthreads();
  for (int s = 128; s > 0; s >>= 1) { if (t < s) red[t] += red[t + s]; __syncthreads(); }
  float totA = red[0]; __syncthreads();
  red[t] = sad; __syncthreads();
  for (int s = 128; s > 0; s >>= 1) { if (t < s) red[t] += red[t + s]; __syncthreads(); }
  float totAD = red[0]; __syncthreads();
  if (t == 0) {
    float sigma = fmaxf(totAD / fmaxf(totA, 1.0f), 1e-6f);
    stats[0] = 1.0f / (2.0f * sigma * sigma);
    stats[1] = sigma;
  }
  for (int q = 0; q < 6; q++) {
    float s = 0;
    for (int j = t; j < NPT; j += 256) s += raw[j * 6 + q];
    red[t] = s; __syncthreads();
    for (int k = 128; k > 0; k >>= 1) { if (t < k) red[t] += red[t + k]; __syncthreads(); }
    if (t == 0) mean6[q] = red[0] / (float)NPT;
    __syncthreads();
  }
  for (int q = 0; q < 6; q++) {
    float m = mean6[q], s = 0;
    for (int j = t; j < NPT; j += 256) { float d = raw[j * 6 + q] - m; s += d * d; }
    red[t] = s; __syncthreads();
    for (int k = 128; k > 0; k >>= 1) { if (t < k) red[t] += red[t + k]; __syncthreads(); }
    if (t == 0) {
      float sd = sqrtf(red[0] / (float)(NPT - 1));
      stats[2 + q] = m;
      stats[8 + q] = 1.0f / fmaxf(sd, 1e-6f);
    }
    __syncthreads();
  }
}

__global__ __launch_bounds__(64) void pg_wdeg(
    const float* __restrict__ pos, const int* __restrict__ nbr, const int* __restrict__ cnt,
    const float* __restrict__ stats, int2* __restrict__ pack, float* __restrict__ wdeg,
    float* __restrict__ invdeg, float* __restrict__ Dis, float* __restrict__ cvec)
{
  int i = blockIdx.x, t = threadIdx.x;
  int n = cnt[i];
  float inv2s2 = stats[0];
  float px = pos[3 * i], py = pos[3 * i + 1], pz = pos[3 * i + 2];
  float w = 0.0f;
  int j = 0;
  if (t < n) {
    j = nbr[i * 64 + t];
    float dx = pos[3 * j] - px, dy = pos[3 * j + 1] - py, dz = pos[3 * j + 2] - pz;
    float d2 = dx * dx + dy * dy + dz * dz + 1e-12f;
    w = expf(-d2 * inv2s2);
  }
  pack[i * 64 + t] = make_int2(j, __float_as_int(w));
  float s = w;
  for (int off = 1; off < 64; off <<= 1) s += __shfl_xor(s, off);
  if (t == 0) {
    float md = fmaxf(s, 1e-8f);
    wdeg[i] = s;
    invdeg[i] = 1.0f / md;
    float di = 1.0f / sqrtf(md);
    Dis[i] = di;
    cvec[i] = di * di * s;
  }
}

__global__ __launch_bounds__(64) void pg_curv_mlp(
    const float* __restrict__ pos, const float* __restrict__ raw, const float* __restrict__ stats,
    const float* __restrict__ Wc1, const float* __restrict__ bc1,
    const float* __restrict__ Wc2, const float* __restrict__ bc2,
    const float* __restrict__ Win, const float* __restrict__ b_in, float* __restrict__ h)
{
  __shared__ float feat[19];
  __shared__ float nraw[6];
  __shared__ float hid[32];
  int i = blockIdx.x, t = threadIdx.x;
  if (t < 3) feat[t] = pos[3 * i + t];
  if (t < 6) nraw[t] = (raw[i * 6 + t] - stats[2 + t]) * stats[8 + t];
  __syncthreads();
  if (t < 32) {
    float a = bc1[t];
    for (int k = 0; k < 6; k++) a += nraw[k] * Wc1[k * 32 + t];
    hid[t] = a / (1.0f + expf(-a));
  }
  __syncthreads();
  if (t < 16) {
    float a = bc2[t];
    for (int k = 0; k < 32; k++) a += hid[k] * Wc2[k * 16 + t];
    feat[3 + t] = a;
  }
  __syncthreads();
  float a = b_in[t];
  for (int k = 0; k < 19; k++) a += feat[k] * Win[k * CH + t];
  h[i * CH + t] = a;
}

// --------------- exp(L/32) Taylor-Horner: global ping-pong, XCD column stripes
// init: Y = I + L/(SCL*TDEG). One block per row.
__global__ __launch_bounds__(256) void pg_hinit(
    const int2* __restrict__ pack, const int* __restrict__ cnt,
    const float* __restrict__ wdeg, float* __restrict__ Y)
{
  int r = blockIdx.x, t = threadIdx.x;
  const float c0 = 1.0f / (SCL * (float)TDEG);
  float* row = Y + (size_t)r * NPT;
  for (int j = t * 4; j < NPT; j += 1024)
    *(f32x4*)(row + j) = (f32x4){0.f, 0.f, 0.f, 0.f};
  __syncthreads();
  int n = cnt[r];
  if (t < n) {
    int2 p = pack[r * 64 + t];
    row[p.x] = __int_as_float(p.y) * c0;
  }
  if (t == 0) row[r] = 1.0f - wdeg[r] * c0;
}

// one Horner step: Yout = I + Lhat*Yin*invc.
// grid 2048 = 8 stripes (256 cols, XCD-pinned via bid&7) x 256 row-groups.
// thread: 2 rows x 4 cols; row is wave-uniform -> pack/cnt/wdeg scalar loads.
template <bool LAST>
__global__ __launch_bounds__(256) void pg_hstep(
    const int2* __restrict__ pack, const int* __restrict__ cnt,
    const float* __restrict__ wdeg, const float* __restrict__ Yin,
    float* __restrict__ Yout, float invc,
    bf16_t* __restrict__ Th, bf16_t* __restrict__ Tl)
{
  int b = blockIdx.x;
  int s = b & 7, w = b >> 3;
  int t = threadIdx.x;
  int lane = t & 63, v = t >> 6;
  int c0 = s * 256 + lane * 4;
#pragma unroll
  for (int ri = 0; ri < 2; ri++) {
    int r = __builtin_amdgcn_readfirstlane(w * 8 + v * 2 + ri);
    int n = cnt[r];
    float wd = wdeg[r];
    const int2* pr = pack + r * 64;
    f32x4 y0 = *(const f32x4*)(Yin + (size_t)r * NPT + c0);
    f32x4 acc0 = {-wd * y0[0], -wd * y0[1], -wd * y0[2], -wd * y0[3]};
    f32x4 acc1 = {0.f, 0.f, 0.f, 0.f};
    int nn = (n + 1) & ~1;   // pack rows zero-padded to 64 entries
    for (int q = 0; q < nn; q += 2) {
      int2 p0 = pr[q], p1 = pr[q + 1];
      float w0 = __int_as_float(p0.y), w1 = __int_as_float(p1.y);
      f32x4 g0 = *(const f32x4*)(Yin + (size_t)p0.x * NPT + c0);
      f32x4 g1 = *(const f32x4*)(Yin + (size_t)p1.x * NPT + c0);
#pragma unroll
      for (int e = 0; e < 4; e++) {
        acc0[e] += w0 * g0[e];
        acc1[e] += w1 * g1[e];
      }
    }
    f32x4 val;
#pragma unroll
    for (int e = 0; e < 4; e++) {
      float id = (c0 + e == r) ? 1.0f : 0.0f;
      val[e] = id + (acc0[e] + acc1[e]) * invc;
    }
    if (LAST) {
      bf16x4_t hv, lv;
#pragma unroll
      for (int e = 0; e < 4; e++) {
        __bf16 hb = (__bf16)val[e];
        hv[e] = hb;
        lv[e] = (__bf16)(val[e] - (float)hb);
      }
      *(bf16x4_t*)(Th + (size_t)r * NPT + c0) = hv;
      *(bf16x4_t*)(Tl + (size_t)r * NPT + c0) = lv;
    } else {
      *(f32x4*)(Yout + (size_t)r * NPT + c0) = val;
    }
  }
}

// ------------- symmetric squaring: C = A*A, A symmetric, split-bf16 3-term MFMA
__global__ __launch_bounds__(256) void pg_sq(
    const bf16_t* __restrict__ Ah, const bf16_t* __restrict__ Al,
    bf16_t* __restrict__ Ch, bf16_t* __restrict__ Cl)
{
  __shared__ __align__(16) char smem[131072];  // 2 bufs x 4 tiles x 16 KB
  const int t = threadIdx.x;
  const int w = t >> 6, l = t & 63;
  const int lrow = l & 15, lhi = l >> 4;
  int bid = blockIdx.x;
  int sbid = (bid & 7) * 32 + (bid >> 3);
  const int by = sbid >> 4, bx = sbid & 15;
  const int wr = w >> 1, wc = w & 1;

  int offA[4], offB[4];
#pragma unroll
  for (int it = 0; it < 4; it++) {
    int o = it * 4096 + t * 16;
    int r = o >> 7;
    int cb = (o & 127) ^ ((r & 7) << 4);
    offA[it] = (by * 128 + r) * (NPT * 2) + cb;
    offB[it] = (bx * 128 + r) * (NPT * 2) + cb;
  }
  int aoff[4][2], boff[4][2];
#pragma unroll
  for (int m = 0; m < 4; m++) {
    int arow = wr * 64 + m * 16 + lrow;
    int brow = wc * 64 + m * 16 + lrow;
#pragma unroll
    for (int kk = 0; kk < 2; kk++) {
      int kb = kk * 64 + lhi * 16;
      aoff[m][kk] = arow * 128 + (kb ^ ((arow & 7) << 4));
      boff[m][kk] = brow * 128 + (kb ^ ((brow & 7) << 4));
    }
  }

  f32x4 acc[4][4];
#pragma unroll
  for (int m = 0; m < 4; m++)
#pragma unroll
    for (int n = 0; n < 4; n++) acc[m][n] = (f32x4){0.f, 0.f, 0.f, 0.f};

  const int lofs_w = w << 10;
#pragma unroll
  for (int it = 0; it < 4; it++) {
    int lo = it * 4096 + lofs_w;
    gl_lds16((const char*)Ah + offA[it], smem + lo);
    gl_lds16((const char*)Al + offA[it], smem + 16384 + lo);
    gl_lds16((const char*)Ah + offB[it], smem + 32768 + lo);
    gl_lds16((const char*)Al + offB[it], smem + 49152 + lo);
  }
  __syncthreads();

  for (int ks = 0; ks < NPT / 64; ks++) {
    if (ks + 1 < NPT / 64) {
      char* nbuf = smem + ((ks + 1) & 1) * 65536;
      size_t kadv = (size_t)(ks + 1) * 128;
#pragma unroll
      for (int it = 0; it < 4; it++) {
        int lo = it * 4096 + lofs_w;
        gl_lds16((const char*)Ah + offA[it] + kadv, nbuf + lo);
        gl_lds16((const char*)Al + offA[it] + kadv, nbuf + 16384 + lo);
        gl_lds16((const char*)Ah + offB[it] + kadv, nbuf + 32768 + lo);
        gl_lds16((const char*)Al + offB[it] + kadv, nbuf + 49152 + lo);
      }
    }
    const char* cbuf = smem + (ks & 1) * 65536;
#pragma unroll
    for (int kk = 0; kk < 2; kk++) {
      bf16x8 bhf[4], blf[4];
#pragma unroll
      for (int n = 0; n < 4; n++) {
        bhf[n] = *(const bf16x8*)(cbuf + 32768 + boff[n][kk]);
        blf[n] = *(const bf16x8*)(cbuf + 49152 + boff[n][kk]);
      }
#pragma unroll
      for (int m = 0; m < 4; m++) {
        bf16x8 ah = *(const bf16x8*)(cbuf + aoff[m][kk]);
        bf16x8 al = *(const bf16x8*)(cbuf + 16384 + aoff[m][kk]);
#pragma unroll
        for (int n = 0; n < 4; n++) {
          acc[m][n] = __builtin_amdgcn_mfma_f32_16x16x32_bf16(al, bhf[n], acc[m][n], 0, 0, 0);
          acc[m][n] = __builtin_amdgcn_mfma_f32_16x16x32_bf16(ah, blf[n], acc[m][n], 0, 0, 0);
          acc[m][n] = __builtin_amdgcn_mfma_f32_16x16x32_bf16(ah, bhf[n], acc[m][n], 0, 0, 0);
        }
      }
    }
    __syncthreads();
  }

  const int gr0 = by * 128 + wr * 64 + lhi * 4;
  const int gc0 = bx * 128 + wc * 64 + lrow;
#pragma unroll
  for (int m = 0; m < 4; m++) {
#pragma unroll
    for (int n = 0; n < 4; n++) {
      int gc = gc0 + n * 16;
#pragma unroll
      for (int r = 0; r < 4; r++) {
        float c = acc[m][n][r];
        __bf16 hb = (__bf16)c;
        size_t o = (size_t)(gr0 + m * 16 + r) * NPT + gc;
        Ch[o] = hb;
        Cl[o] = (__bf16)(c - (float)hb);
      }
    }
  }
}

// ------------------- X (2048x64 f32) -> XT hi/lo bf16 (64x2048), LDS transpose ---
__global__ __launch_bounds__(256) void pg_splitx(
    const float* __restrict__ X, bf16_t* __restrict__ XTh, bf16_t* __restrict__ XTl)
{
  __shared__ float sX[64][65];
  int t = threadIdx.x;
  int r0 = blockIdx.x * 64;
  for (int u = 0; u < 16; u++) {
    int idx = u * 256 + t;
    int r = idx >> 6, c = idx & 63;
    sX[r][c] = X[(size_t)(r0 + r) * CH + c];
  }
  __syncthreads();
  int c = t >> 6;
  int rr = t & 63;
  for (int cc = c; cc < 64; cc += 4) {
    float v = sX[rr][cc];
    __bf16 hb = (__bf16)v;
    XTh[(size_t)cc * NPT + r0 + rr] = hb;
    XTl[(size_t)cc * NPT + r0 + rr] = (__bf16)(v - (float)hb);
  }
}

// ---------- hd[scale] = E_scale @ X  via MFMA; grid (32 row-blocks, 3 scales) ---
__global__ __launch_bounds__(256) void pg_emm(
    const bf16_t* __restrict__ E05h, const bf16_t* __restrict__ E05l,
    const bf16_t* __restrict__ E2h,  const bf16_t* __restrict__ E2l,
    const bf16_t* __restrict__ E8h,  const bf16_t* __restrict__ E8l,
    const bf16_t* __restrict__ XTh,  const bf16_t* __restrict__ XTl,
    float* __restrict__ hd)
{
  __shared__ __align__(16) char smem[65536];
  const int t = threadIdx.x;
  const int w = t >> 6, l = t & 63;
  const int lrow = l & 15, lhi = l >> 4;
  const int scale = blockIdx.y;
  const bf16_t* Eh = (scale == 0) ? E05h : (scale == 1) ? E2h : E8h;
  const bf16_t* El = (scale == 0) ? E05l : (scale == 1) ? E2l : E8l;
  const int rb = blockIdx.x;

  int offA[2], offB[2];
#pragma unroll
  for (int it = 0; it < 2; it++) {
    int o = it * 4096 + t * 16;
    int r = o >> 7;
    int cb = (o & 127) ^ ((r & 7) << 4);
    offA[it] = (rb * 64 + r) * (NPT * 2) + cb;
    offB[it] = r * (NPT * 2) + cb;
  }
  int aoff[2], boff[4][2];
  {
    int arow = w * 16 + lrow;
#pragma unroll
    for (int kk = 0; kk < 2; kk++) {
      int kb = kk * 64 + lhi * 16;
      aoff[kk] = arow * 128 + (kb ^ ((arow & 7) << 4));
    }
  }
#pragma unroll
  for (int n = 0; n < 4; n++) {
    int brow = n * 16 + lrow;
#pragma unroll
    for (int kk = 0; kk < 2; kk++) {
      int kb = kk * 64 + lhi * 16;
      boff[n][kk] = brow * 128 + (kb ^ ((brow & 7) << 4));
    }
  }

  f32x4 acc[4];
#pragma unroll
  for (int n = 0; n < 4; n++) acc[n] = (f32x4){0.f, 0.f, 0.f, 0.f};

  const int lofs_w = w << 10;
#pragma unroll
  for (int it = 0; it < 2; it++) {
    int lo = it * 4096 + lofs_w;
    gl_lds16((const char*)Eh  + offA[it], smem + lo);
    gl_lds16((const char*)El  + offA[it], smem + 8192 + lo);
    gl_lds16((const char*)XTh + offB[it], smem + 16384 + lo);
    gl_lds16((const char*)XTl + offB[it], smem + 24576 + lo);
  }
  __syncthreads();

  for (int ks = 0; ks < NPT / 64; ks++) {
    if (ks + 1 < NPT / 64) {
      char* nbuf = smem + ((ks + 1) & 1) * 32768;
      size_t kadv = (size_t)(ks + 1) * 128;
#pragma unroll
      for (int it = 0; it < 2; it++) {
        int lo = it * 4096 + lofs_w;
        gl_lds16((const char*)Eh  + offA[it] + kadv, nbuf + lo);
        gl_lds16((const char*)El  + offA[it] + kadv, nbuf + 8192 + lo);
        gl_lds16((const char*)XTh + offB[it] + kadv, nbuf + 16384 + lo);
        gl_lds16((const char*)XTl + offB[it] + kadv, nbuf + 24576 + lo);
      }
    }
    const char* cbuf = smem + (ks & 1) * 32768;
#pragma unroll
    for (int kk = 0; kk < 2; kk++) {
      bf16x8 ah = *(const bf16x8*)(cbuf + aoff[kk]);
      bf16x8 al = *(const bf16x8*)(cbuf + 8192 + aoff[kk]);
#pragma unroll
      for (int n = 0; n < 4; n++) {
        bf16x8 bh = *(const bf16x8*)(cbuf + 16384 + boff[n][kk]);
        bf16x8 bl = *(const bf16x8*)(cbuf + 24576 + boff[n][kk]);
        acc[n] = __builtin_amdgcn_mfma_f32_16x16x32_bf16(al, bh, acc[n], 0, 0, 0);
        acc[n] = __builtin_amdgcn_mfma_f32_16x16x32_bf16(ah, bl, acc[n], 0, 0, 0);
        acc[n] = __builtin_amdgcn_mfma_f32_16x16x32_bf16(ah, bh, acc[n], 0, 0, 0);
      }
    }
    __syncthreads();
  }

  float* Y = hd + (size_t)scale * NPT * CH;
  const int gr0 = rb * 64 + w * 16 + lhi * 4;
#pragma unroll
  for (int n = 0; n < 4; n++) {
    int gc = n * 16 + lrow;
#pragma unroll
    for (int r = 0; r < 4; r++)
      Y[(size_t)(gr0 + r) * CH + gc] = acc[n][r];
  }
}

// ------------------------------------------------------------------- layers ---
__global__ __launch_bounds__(64) void pg_convP(
    const int2* __restrict__ pack, const int* __restrict__ cnt,
    const float* __restrict__ invdeg, const float* __restrict__ h,
    const float* __restrict__ Ws, const float* __restrict__ bs,
    const float* __restrict__ Wn, const float* __restrict__ bn,
    const float* __restrict__ cres, float* __restrict__ out)
{
  __shared__ float sh[64], sp2[64];
  int i = blockIdx.x, t = threadIdx.x;
  sh[t] = h[i * CH + t];
  int n = cnt[i];
  float acc = 0.0f;
  for (int q = 0; q < n; q++) {
    int2 p = pack[i * 64 + q];
    acc += __int_as_float(p.y) * h[(size_t)p.x * CH + t];
  }
  sp2[t] = acc * invdeg[i];
  __syncthreads();
  float a = bs[t] + bn[t] + 0.1f * cres[0] * sh[t];
  for (int k = 0; k < 64; k++) a += sh[k] * Ws[k * CH + t] + sp2[k] * Wn[k * CH + t];
  out[i * CH + t] = a / (1.0f + expf(-a));
}

__global__ __launch_bounds__(64) void pg_difffuse(
    const float* __restrict__ h2, const float* __restrict__ hd,
    const float* __restrict__ dW, const float* __restrict__ db, float* __restrict__ out)
{
  __shared__ float sh[3][64];
  int i = blockIdx.x, t = threadIdx.x;
  for (int s = 0; s < 3; s++) sh[s][t] = hd[(size_t)s * NPT * CH + i * CH + t];
  __syncthreads();
  float a = h2[i * CH + t] + db[t];
  for (int s = 0; s < 3; s++) {
    const float* w = dW + s * CH * CH;
    for (int k = 0; k < 64; k++) a += sh[s][k] * w[k * CH + t];
  }
  out[i * CH + t] = a;
}

// fused tanh-matvec + normalized-Laplacian gather + reaction-diffusion + LN
__global__ __launch_bounds__(64) void pg_tlr(
    const int2* __restrict__ pack, const int* __restrict__ cnt,
    const float* __restrict__ Dis, const float* __restrict__ cvec,
    const float* __restrict__ h3,
    const float* __restrict__ W1, const float* __restrict__ b1,
    const float* __restrict__ W2, const float* __restrict__ b2,
    const float* __restrict__ rdc,
    const float* __restrict__ g, const float* __restrict__ b,
    float* __restrict__ hio)
{
  __shared__ float sh[64], st[64];
  int i = blockIdx.x, t = threadIdx.x;
  sh[t] = h3[i * CH + t];
  __syncthreads();
  float a = b1[t];
  for (int k = 0; k < 64; k++) a += sh[k] * W1[k * CH + t];
  st[t] = tanhf(a);
  int n = cnt[i];
  float accL = 0.0f;
  for (int q = 0; q < n; q++) {
    int2 p = pack[i * 64 + q];
    accL += __int_as_float(p.y) * Dis[p.x] * h3[(size_t)p.x * CH + t];
  }
  float tLv = accL * Dis[i] - cvec[i] * sh[t];
  __syncthreads();
  float react = b2[t];
  for (int k = 0; k < 64; k++) react += st[k] * W2[k * CH + t];
  float x = sh[t] + 0.1f * (rdc[t] * tLv + react) + hio[i * CH + t];
  float s = x;
  for (int off = 1; off < 64; off <<= 1) s += __shfl_xor(s, off);
  float mu = s * (1.0f / 64.0f);
  float d = x - mu;
  float v = d * d;
  for (int off = 1; off < 64; off <<= 1) v += __shfl_xor(v, off);
  v *= (1.0f / 64.0f);
  hio[i * CH + t] = d * (1.0f / sqrtf(v + 1e-5f)) * g[t] + b[t];
}

// ---------------------------------------------------------------- attention ---
__global__ __launch_bounds__(64) void pg_qkv(
    const float* __restrict__ h,
    const float* __restrict__ Wq, const float* __restrict__ bq,
    const float* __restrict__ Wk, const float* __restrict__ bk,
    const float* __restrict__ Wv, const float* __restrict__ bv,
    float* __restrict__ q, float* __restrict__ kb, float* __restrict__ vb)
{
  __shared__ float sh[64];
  int i = blockIdx.x, t = threadIdx.x;
  sh[t] = h[i * CH + t];
  __syncthreads();
  float aq = bq[t], ak = bk[t], avv = bv[t];
  for (int k = 0; k < 64; k++) {
    float x = sh[k];
    aq += x * Wq[k * CH + t];
    ak += x * Wk[k * CH + t];
    avv += x * Wv[k * CH + t];
  }
  q[i * CH + t] = aq;
  kb[i * CH + t] = ak;
  vb[i * CH + t] = avv;
}

// CSR-masked attention + output projection + final linear, fused
__global__ __launch_bounds__(256) void pg_attn_out(
    const float* __restrict__ q, const float* __restrict__ kb, const float* __restrict__ vb,
    const int* __restrict__ nbr, const int* __restrict__ cnt,
    const float* __restrict__ Hc, const float* __restrict__ beta,
    const float* __restrict__ h,
    const float* __restrict__ Wo, const float* __restrict__ bo,
    const float* __restrict__ Wout, const float* __restrict__ bout,
    float* __restrict__ out)
{
  __shared__ float av_s[64];
  int i = blockIdx.x;
  int t = threadIdx.x;
  int head = t >> 6, lane = t & 63;
  float sp_b = logf(1.0f + expf(beta[head]));
  float hci = Hc[i];
  const float* qp = q + i * CH + head * 16;
  float qr[16];
#pragma unroll
  for (int d = 0; d < 16; d++) qr[d] = qp[d];
  int n = cnt[i];
  int K = n + 1;
  float mx = -1e30f, den = 0.0f;
  float vac[16];
#pragma unroll
  for (int d = 0; d < 16; d++) vac[d] = 0.0f;
  for (int m = lane; m < K; m += 64) {
    int j = (m == n) ? i : nbr[i * 64 + m];
    const float* kp = kb + (size_t)j * CH + head * 16;
    float sc = 0.0f;
#pragma unroll
    for (int d = 0; d < 16; d++) sc += qr[d] * kp[d];
    sc *= 0.25f;
    sc -= sp_b * fabsf(hci - Hc[j]);
    float nm = fmaxf(mx, sc);
    float corr = expf(mx - nm);
    float p = expf(sc - nm);
    den = den * corr + p;
    const float* vp = vb + (size_t)j * CH + head * 16;
#pragma unroll
    for (int d = 0; d < 16; d++) vac[d] = vac[d] * corr + p * vp[d];
    mx = nm;
  }
  for (int off = 32; off > 0; off >>= 1) {
    float omx = __shfl_down(mx, off);
    float oden = __shfl_down(den, off);
    float ov[16];
#pragma unroll
    for (int d = 0; d < 16; d++) ov[d] = __shfl_down(vac[d], off);
    float nm = fmaxf(mx, omx);
    float c1 = expf(mx - nm), c2 = expf(omx - nm);
    den = den * c1 + oden * c2;
#pragma unroll
    for (int d = 0; d < 16; d++) vac[d] = vac[d] * c1 + ov[d] * c2;
    mx = nm;
  }
  if (lane == 0) {
    float inv = 1.0f / den;
    for (int d = 0; d < 16; d++) av_s[head * 16 + d] = vac[d] * inv;
  }
  __syncthreads();
  if (t < 64) {
    float a = h[i * CH + t] + bo[t];
    for (int k = 0; k < 64; k++) a += av_s[k] * Wo[k * CH + t];
    float s = a * Wout[t];
    for (int off = 1; off < 64; off <<= 1) s += __shfl_xor(s, off);
    if (t == 0) out[i] = s + bout[0];
  }
}

// ------------------------------------------------------------------- launch ---
extern "C" void kernel_launch(void* const* d_in, const int* in_sizes, int n_in,
                              void* d_out, int out_size, void* d_ws, size_t ws_size,
                              hipStream_t stream)
{
  const float* pos   = (const float*)d_in[0];
  const float* adj   = (const float*)d_in[1];
  const float* Wc1   = (const float*)d_in[2];
  const float* bc1   = (const float*)d_in[3];
  const float* Wc2   = (const float*)d_in[4];
  const float* bc2   = (const float*)d_in[5];
  const float* Win   = (const float*)d_in[6];
  const float* b_in  = (const float*)d_in[7];
  const float* cWs   = (const float*)d_in[8];
  const float* cbs   = (const float*)d_in[9];
  const float* cWn   = (const float*)d_in[10];
  const float* cbn   = (const float*)d_in[11];
  const float* cres  = (const float*)d_in[12];
  const float* dW    = (const float*)d_in[13];
  const float* db    = (const float*)d_in[14];
  const float* rW1   = (const float*)d_in[15];
  const float* rb1   = (const float*)d_in[16];
  const float* rW2   = (const float*)d_in[17];
  const float* rb2   = (const float*)d_in[18];
  const float* rdc   = (const float*)d_in[19];
  const float* lng   = (const float*)d_in[20];
  const float* lnb   = (const float*)d_in[21];
  const float* Wq    = (const float*)d_in[22];
  const float* bq    = (const float*)d_in[23];
  const float* Wk    = (const float*)d_in[24];
  const float* bk    = (const float*)d_in[25];
  const float* Wv    = (const float*)d_in[26];
  const float* bv    = (const float*)d_in[27];
  const float* Wo    = (const float*)d_in[28];
  const float* bo    = (const float*)d_in[29];
  const float* abeta = (const float*)d_in[30];
  const float* Wout  = (const float*)d_in[31];
  const float* bout  = (const float*)d_in[32];

  const size_t NNe = (size_t)NPT * NPT;
  const size_t NC  = (size_t)NPT * CH;
  const size_t P   = NNe * 2;   // bytes per bf16 plane (8 MB)

  char* base = (char*)d_ws;
  bf16_t* E05h = (bf16_t*)(base + 0 * P);
  bf16_t* E05l = (bf16_t*)(base + 1 * P);
  bf16_t* E2h  = (bf16_t*)(base + 2 * P);
  bf16_t* E2l  = (bf16_t*)(base + 3 * P);
  bf16_t* E8h  = (bf16_t*)(base + 4 * P);
  bf16_t* E8l  = (bf16_t*)(base + 5 * P);
  bf16_t* SAh  = (bf16_t*)(base + 6 * P);
  bf16_t* SAl  = (bf16_t*)(base + 7 * P);
  bf16_t* SBh  = (bf16_t*)(base + 8 * P);
  bf16_t* SBl  = (bf16_t*)(base + 9 * P);
  // Horner ping-pong aliases E05/E2 planes (dead until squarings write them)
  float*  M0   = (float*)(base + 0 * P);    // 16 MB = planes 0,1
  float*  M1   = (float*)(base + 2 * P);    // 16 MB = planes 2,3
  bf16_t* XTh  = (bf16_t*)(base + 12 * P);
  bf16_t* XTl  = (bf16_t*)(base + 12 * P + NPT * CH * 2);
  float*  smb  = (float*)(base + 12 * P + 1024 * 1024);

  float* h   = smb;
  float* tA  = h + NC;
  float* tB  = tA + NC;
  float* hd  = tB + NC;        // 3*NC
  float* q   = hd + 3 * NC;
  float* kbf = q + NC;
  float* vbf = kbf + NC;
  float* raw = vbf + NC;
  float* sm  = raw + 8 * NPT;
  float* sumA   = sm;
  float* sumAD  = sm + NPT;
  float* wdeg   = sm + 2 * NPT;
  float* invdeg = sm + 3 * NPT;
  float* Dis    = sm + 4 * NPT;
  float* cvec   = sm + 5 * NPT;
  float* Hc     = sm + 6 * NPT;
  float* stats  = sm + 7 * NPT;
  int*   nbr    = (int*)(sm + 8 * NPT);
  int*   cnt    = nbr + (size_t)NPT * 64;
  int2*  pack   = (int2*)(cnt + NPT);

  size_t need = 12 * P + 1024 * 1024
              + (9 * NC + 16 * (size_t)NPT) * 4
              + (size_t)NPT * 64 * 4 + NPT * 4 + (size_t)NPT * 64 * 8 + 256;
  if (ws_size < need) return;

  // geometry + CSR + features
  pg_geom_csr<<<NPT, 256, 0, stream>>>(pos, adj, raw, Hc, sumA, sumAD, nbr, cnt);
  pg_stats<<<1, 256, 0, stream>>>(raw, sumA, sumAD, stats);
  pg_wdeg<<<NPT, 64, 0, stream>>>(pos, nbr, cnt, stats, pack, wdeg, invdeg, Dis, cvec);
  pg_curv_mlp<<<NPT, 64, 0, stream>>>(pos, raw, stats, Wc1, bc1, Wc2, bc2, Win, b_in, h);

  // T = exp(L/32): global ping-pong Taylor-Horner, XCD column stripes
  pg_hinit<<<NPT, 256, 0, stream>>>(pack, cnt, wdeg, M0);
  float* cur = M0;
  float* nxt = M1;
  for (int k = TDEG - 1; k >= 2; k--) {
    pg_hstep<false><<<NPT, 256, 0, stream>>>(pack, cnt, wdeg, cur, nxt,
                                             1.0f / (SCL * (float)k), nullptr, nullptr);
    float* tmp = cur; cur = nxt; nxt = tmp;
  }
  pg_hstep<true><<<NPT, 256, 0, stream>>>(pack, cnt, wdeg, cur, nullptr,
                                          1.0f / SCL, SAh, SAl);

  // squaring chain (symmetric): exp(L/32) -> ... -> exp(8L)
  pg_sq<<<256, 256, 0, stream>>>(SAh, SAl, SBh, SBl);     // L/16
  pg_sq<<<256, 256, 0, stream>>>(SBh, SBl, SAh, SAl);     // L/8
  pg_sq<<<256, 256, 0, stream>>>(SAh, SAl, SBh, SBl);     // L/4
  pg_sq<<<256, 256, 0, stream>>>(SBh, SBl, E05h, E05l);   // L/2
  pg_sq<<<256, 256, 0, stream>>>(E05h, E05l, SAh, SAl);   // L
  pg_sq<<<256, 256, 0, stream>>>(SAh, SAl, E2h, E2l);     // 2L
  pg_sq<<<256, 256, 0, stream>>>(E2h, E2l, SBh, SBl);     // 4L
  pg_sq<<<256, 256, 0, stream>>>(SBh, SBl, E8h, E8l);     // 8L

  // NL layers
  for (int i = 0; i < 4; i++) {
    pg_convP<<<NPT, 64, 0, stream>>>(pack, cnt, invdeg, h,
                                     cWs + i * 4096, cbs + i * 64,
                                     cWn + i * 4096, cbn + i * 64, cres + i, tA);
    float* h3 = tA;
    if ((i & 1) == 0) {
      int j = i >> 1;
      pg_splitx<<<32, 256, 0, stream>>>(tA, XTh, XTl);
      pg_emm<<<dim3(32, 3), 256, 0, stream>>>(E05h, E05l, E2h, E2l, E8h, E8l,
                                              XTh, XTl, hd);
      pg_difffuse<<<NPT, 64, 0, stream>>>(tA, hd, dW + j * 3 * 4096, db + j * 64, tB);
      h3 = tB;
    }
    pg_tlr<<<NPT, 64, 0, stream>>>(pack, cnt, Dis, cvec, h3,
                                   rW1 + i * 4096, rb1 + i * 64,
                                   rW2 + i * 4096, rb2 + i * 64,
                                   rdc + i * 64, lng + i * 64, lnb + i * 64, h);
  }

  // attention + output
  pg_qkv<<<NPT, 64, 0, stream>>>(h, Wq, bq, Wk, bk, Wv, bv, q, kbf, vbf);
  pg_attn_out<<<NPT, 256, 0, stream>>>(q, kbf, vbf, nbr, cnt, Hc, abeta,
                                       h, Wo, bo, Wout, bout, (float*)d_out);
}

// Round 6
// 786.128 us; speedup vs baseline: 4.2788x; 1.0073x over previous
//
#include <hip/hip_runtime.h>
#include <math.h>

#define NPT 2048
#define CH 64
constexpr int TDEG = 14;        // Taylor degree for exp(L/16)
constexpr float SCL = 16.0f;    // scaling denominator

typedef __bf16 bf16_t;
typedef __bf16 bf16x8 __attribute__((ext_vector_type(8)));
typedef __bf16 bf16x4_t __attribute__((ext_vector_type(4)));
typedef float f32x4 __attribute__((ext_vector_type(4)));

__device__ __forceinline__ void gl_lds16(const void* g, void* l) {
  __builtin_amdgcn_global_load_lds(
      (const __attribute__((address_space(1))) void*)g,
      (__attribute__((address_space(3))) void*)l, 16, 0, 0);
}

// ------------------------------------------------- geometry + CSR (one scan) ---
__global__ __launch_bounds__(256) void pg_geom_csr(
    const float* __restrict__ pos, const float* __restrict__ adj,
    float* __restrict__ raw, float* __restrict__ Hc,
    float* __restrict__ sumA, float* __restrict__ sumAD,
    int* __restrict__ nbr, int* __restrict__ cnt)
{
  __shared__ float sp[NPT * 3];
  __shared__ float red[256 * 6];
  __shared__ int wsum[4];
  int i = blockIdx.x, t = threadIdx.x;
  for (int j = t; j < NPT * 3; j += 256) sp[j] = pos[j];
  __syncthreads();
  float px = sp[3 * i], py = sp[3 * i + 1], pz = sp[3 * i + 2];

  size_t base = (size_t)i * NPT + t * 8;
  float av[8];
  int c = 0;
  for (int u = 0; u < 8; u++) { av[u] = adj[base + u]; c += (av[u] != 0.0f); }
  int sc = c;
  int lane = t & 63;
  for (int off = 1; off < 64; off <<= 1) {
    int v = __shfl_up(sc, off);
    if (lane >= off) sc += v;
  }
  if (lane == 63) wsum[t >> 6] = sc;
  __syncthreads();
  int wprefix = 0;
  for (int w = 0; w < (t >> 6); w++) wprefix += wsum[w];
  int o = wprefix + sc - c;
  int wr = 0;
  for (int u = 0; u < 8; u++)
    if (av[u] != 0.0f) { int p = o + wr; if (p < 64) nbr[i * 64 + p] = t * 8 + u; wr++; }

  float s0 = 0, s1 = 0, s2 = 0, ax = 0, ay = 0, az = 0;
  for (int u = 0; u < 8; u++) {
    if (av[u] != 0.0f) {
      int j = t * 8 + u;
      float dx = sp[3 * j] - px, dy = sp[3 * j + 1] - py, dz = sp[3 * j + 2] - pz;
      float d2 = dx * dx + dy * dy + dz * dz + 1e-12f;
      float d = sqrtf(d2);
      s0 += 1.0f; s1 += d; s2 += d2;
      ax += sp[3 * j]; ay += sp[3 * j + 1]; az += sp[3 * j + 2];
    }
  }
  red[t * 6 + 0] = s0; red[t * 6 + 1] = s1; red[t * 6 + 2] = s2;
  red[t * 6 + 3] = ax; red[t * 6 + 4] = ay; red[t * 6 + 5] = az;
  __syncthreads();
  for (int s = 128; s > 0; s >>= 1) {
    if (t < s)
      for (int q = 0; q < 6; q++) red[t * 6 + q] += red[(t + s) * 6 + q];
    __syncthreads();
  }
  if (t == 0) {
    s0 = red[0]; s1 = red[1]; s2 = red[2]; ax = red[3]; ay = red[4]; az = red[5];
    float degc = fmaxf(s0, 1.0f);
    float dxm = ax / degc - px, dym = ay / degc - py, dzm = az / degc - pz;
    float H = 0.5f * sqrtf(dxm * dxm + dym * dym + dzm * dzm);
    float r = s1 / degc;
    float var = (s2 - 2.0f * r * s1 + r * r * s0) / degc;
    float sdev = sqrtf(var + 1e-12f);
    float k1 = H + sdev, k2 = H - sdev;
    raw[i * 6 + 0] = H;
    raw[i * 6 + 1] = k1 * k2;
    raw[i * 6 + 2] = k1;
    raw[i * 6 + 3] = k2;
    raw[i * 6 + 4] = 0.6366197723675814f * atanf((k1 + k2) / (k1 - k2 + 1e-6f));
    raw[i * 6 + 5] = sqrtf(0.5f * (k1 * k1 + k2 * k2));
    Hc[i] = H;
    sumA[i] = s0; sumAD[i] = s1;
    int tot = wsum[0] + wsum[1] + wsum[2] + wsum[3];
    cnt[i] = min(tot, 64);
  }
}

__global__ __launch_bounds__(256) void pg_stats(
    const float* __restrict__ raw, const float* __restrict__ sumA,
    const float* __restrict__ sumAD, float* __restrict__ stats)
{
  __shared__ float red[256];
  __shared__ float mean6[6];
  int t = threadIdx.x;
  float sa = 0, sad = 0;
  for (int j = t; j < NPT; j += 256) { sa += sumA[j]; sad += sumAD[j]; }
  red[t] = sa; __syncthreads();
  for (int s = 128; s > 0; s >>= 1) { if (t < s) red[t] += red[t + s]; __syncthreads(); }
  float totA = red[0]; __syncthreads();
  red[t] = sad; __syncthreads();
  for (int s = 128; s > 0; s >>= 1) { if (t < s) red[t] += red[t + s]; __syncthreads(); }
  float totAD = red[0]; __syncthreads();
  if (t == 0) {
    float sigma = fmaxf(totAD / fmaxf(totA, 1.0f), 1e-6f);
    stats[0] = 1.0f / (2.0f * sigma * sigma);
    stats[1] = sigma;
  }
  for (int q = 0; q < 6; q++) {
    float s = 0;
    for (int j = t; j < NPT; j += 256) s += raw[j * 6 + q];
    red[t] = s; __syncthreads();
    for (int k = 128; k > 0; k >>= 1) { if (t < k) red[t] += red[t + k]; __syncthreads(); }
    if (t == 0) mean6[q] = red[0] / (float)NPT;
    __syncthreads();
  }
  for (int q = 0; q < 6; q++) {
    float m = mean6[q], s = 0;
    for (int j = t; j < NPT; j += 256) { float d = raw[j * 6 + q] - m; s += d * d; }
    red[t] = s; __syncthreads();
    for (int k = 128; k > 0; k >>= 1) { if (t < k) red[t] += red[t + k]; __syncthreads(); }
    if (t == 0) {
      float sd = sqrtf(red[0] / (float)(NPT - 1));
      stats[2 + q] = m;
      stats[8 + q] = 1.0f / fmaxf(sd, 1e-6f);
    }
    __syncthreads();
  }
}

__global__ __launch_bounds__(64) void pg_wdeg(
    const float* __restrict__ pos, const int* __restrict__ nbr, const int* __restrict__ cnt,
    const float* __restrict__ stats, int2* __restrict__ pack, float* __restrict__ wdeg,
    float* __restrict__ invdeg, float* __restrict__ Dis, float* __restrict__ cvec)
{
  int i = blockIdx.x, t = threadIdx.x;
  int n = cnt[i];
  float inv2s2 = stats[0];
  float px = pos[3 * i], py = pos[3 * i + 1], pz = pos[3 * i + 2];
  float w = 0.0f;
  int j = 0;
  if (t < n) {
    j = nbr[i * 64 + t];
    float dx = pos[3 * j] - px, dy = pos[3 * j + 1] - py, dz = pos[3 * j + 2] - pz;
    float d2 = dx * dx + dy * dy + dz * dz + 1e-12f;
    w = expf(-d2 * inv2s2);
  }
  pack[i * 64 + t] = make_int2(j, __float_as_int(w));
  float s = w;
  for (int off = 1; off < 64; off <<= 1) s += __shfl_xor(s, off);
  if (t == 0) {
    float md = fmaxf(s, 1e-8f);
    wdeg[i] = s;
    invdeg[i] = 1.0f / md;
    float di = 1.0f / sqrtf(md);
    Dis[i] = di;
    cvec[i] = di * di * s;
  }
}

__global__ __launch_bounds__(64) void pg_curv_mlp(
    const float* __restrict__ pos, const float* __restrict__ raw, const float* __restrict__ stats,
    const float* __restrict__ Wc1, const float* __restrict__ bc1,
    const float* __restrict__ Wc2, const float* __restrict__ bc2,
    const float* __restrict__ Win, const float* __restrict__ b_in, float* __restrict__ h)
{
  __shared__ float feat[19];
  __shared__ float nraw[6];
  __shared__ float hid[32];
  int i = blockIdx.x, t = threadIdx.x;
  if (t < 3) feat[t] = pos[3 * i + t];
  if (t < 6) nraw[t] = (raw[i * 6 + t] - stats[2 + t]) * stats[8 + t];
  __syncthreads();
  if (t < 32) {
    float a = bc1[t];
    for (int k = 0; k < 6; k++) a += nraw[k] * Wc1[k * 32 + t];
    hid[t] = a / (1.0f + expf(-a));
  }
  __syncthreads();
  if (t < 16) {
    float a = bc2[t];
    for (int k = 0; k < 32; k++) a += hid[k] * Wc2[k * 16 + t];
    feat[3 + t] = a;
  }
  __syncthreads();
  float a = b_in[t];
  for (int k = 0; k < 19; k++) a += feat[k] * Win[k * CH + t];
  h[i * CH + t] = a;
}

// --------------- exp(L/16) Taylor-Horner: global ping-pong, XCD column stripes
__global__ __launch_bounds__(256) void pg_hinit(
    const int2* __restrict__ pack, const int* __restrict__ cnt,
    const float* __restrict__ wdeg, float* __restrict__ Y)
{
  int r = blockIdx.x, t = threadIdx.x;
  const float c0 = 1.0f / (SCL * (float)TDEG);
  float* row = Y + (size_t)r * NPT;
  for (int j = t * 4; j < NPT; j += 1024)
    *(f32x4*)(row + j) = (f32x4){0.f, 0.f, 0.f, 0.f};
  __syncthreads();
  int n = cnt[r];
  if (t < n) {
    int2 p = pack[r * 64 + t];
    row[p.x] = __int_as_float(p.y) * c0;
  }
  if (t == 0) row[r] = 1.0f - wdeg[r] * c0;
}

// one Horner step: Yout = I + Lhat*Yin*invc.
// grid 2048 = 8 stripes (256 cols, XCD-pinned via bid&7) x 256 row-groups.
// thread: 2 rows x 4 cols; row is wave-uniform -> pack/cnt/wdeg scalar loads.
// gather loop unrolled x4 (4 accumulators, 4 f32x4 loads in flight).
template <bool LAST>
__global__ __launch_bounds__(256) void pg_hstep(
    const int2* __restrict__ pack, const int* __restrict__ cnt,
    const float* __restrict__ wdeg, const float* __restrict__ Yin,
    float* __restrict__ Yout, float invc,
    bf16_t* __restrict__ Th, bf16_t* __restrict__ Tl)
{
  int b = blockIdx.x;
  int s = b & 7, w = b >> 3;
  int t = threadIdx.x;
  int lane = t & 63, v = t >> 6;
  int c0 = s * 256 + lane * 4;
#pragma unroll
  for (int ri = 0; ri < 2; ri++) {
    int r = __builtin_amdgcn_readfirstlane(w * 8 + v * 2 + ri);
    int n = cnt[r];
    float wd = wdeg[r];
    const int2* pr = pack + r * 64;
    f32x4 y0 = *(const f32x4*)(Yin + (size_t)r * NPT + c0);
    f32x4 acc0 = {-wd * y0[0], -wd * y0[1], -wd * y0[2], -wd * y0[3]};
    f32x4 acc1 = {0.f, 0.f, 0.f, 0.f};
    f32x4 acc2 = {0.f, 0.f, 0.f, 0.f};
    f32x4 acc3 = {0.f, 0.f, 0.f, 0.f};
    int nn = (n + 3) & ~3;   // pack rows zero-padded to 64 entries
    for (int q = 0; q < nn; q += 4) {
      int2 p0 = pr[q], p1 = pr[q + 1], p2 = pr[q + 2], p3 = pr[q + 3];
      float w0 = __int_as_float(p0.y), w1 = __int_as_float(p1.y);
      float w2 = __int_as_float(p2.y), w3 = __int_as_float(p3.y);
      f32x4 g0 = *(const f32x4*)(Yin + (size_t)p0.x * NPT + c0);
      f32x4 g1 = *(const f32x4*)(Yin + (size_t)p1.x * NPT + c0);
      f32x4 g2 = *(const f32x4*)(Yin + (size_t)p2.x * NPT + c0);
      f32x4 g3 = *(const f32x4*)(Yin + (size_t)p3.x * NPT + c0);
#pragma unroll
      for (int e = 0; e < 4; e++) {
        acc0[e] += w0 * g0[e];
        acc1[e] += w1 * g1[e];
        acc2[e] += w2 * g2[e];
        acc3[e] += w3 * g3[e];
      }
    }
    f32x4 val;
#pragma unroll
    for (int e = 0; e < 4; e++) {
      float id = (c0 + e == r) ? 1.0f : 0.0f;
      val[e] = id + ((acc0[e] + acc1[e]) + (acc2[e] + acc3[e])) * invc;
    }
    if (LAST) {
      bf16x4_t hv, lv;
#pragma unroll
      for (int e = 0; e < 4; e++) {
        __bf16 hb = (__bf16)val[e];
        hv[e] = hb;
        lv[e] = (__bf16)(val[e] - (float)hb);
      }
      *(bf16x4_t*)(Th + (size_t)r * NPT + c0) = hv;
      *(bf16x4_t*)(Tl + (size_t)r * NPT + c0) = lv;
    } else {
      *(f32x4*)(Yout + (size_t)r * NPT + c0) = val;
    }
  }
}

// ------------- symmetric squaring: C = A*A, A symmetric, split-bf16 3-term MFMA
__global__ __launch_bounds__(256) void pg_sq(
    const bf16_t* __restrict__ Ah, const bf16_t* __restrict__ Al,
    bf16_t* __restrict__ Ch, bf16_t* __restrict__ Cl)
{
  __shared__ __align__(16) char smem[131072];  // 2 bufs x 4 tiles x 16 KB
  const int t = threadIdx.x;
  const int w = t >> 6, l = t & 63;
  const int lrow = l & 15, lhi = l >> 4;
  int bid = blockIdx.x;
  int sbid = (bid & 7) * 32 + (bid >> 3);
  const int by = sbid >> 4, bx = sbid & 15;
  const int wr = w >> 1, wc = w & 1;

  int offA[4], offB[4];
#pragma unroll
  for (int it = 0; it < 4; it++) {
    int o = it * 4096 + t * 16;
    int r = o >> 7;
    int cb = (o & 127) ^ ((r & 7) << 4);
    offA[it] = (by * 128 + r) * (NPT * 2) + cb;
    offB[it] = (bx * 128 + r) * (NPT * 2) + cb;
  }
  int aoff[4][2], boff[4][2];
#pragma unroll
  for (int m = 0; m < 4; m++) {
    int arow = wr * 64 + m * 16 + lrow;
    int brow = wc * 64 + m * 16 + lrow;
#pragma unroll
    for (int kk = 0; kk < 2; kk++) {
      int kb = kk * 64 + lhi * 16;
      aoff[m][kk] = arow * 128 + (kb ^ ((arow & 7) << 4));
      boff[m][kk] = brow * 128 + (kb ^ ((brow & 7) << 4));
    }
  }

  f32x4 acc[4][4];
#pragma unroll
  for (int m = 0; m < 4; m++)
#pragma unroll
    for (int n = 0; n < 4; n++) acc[m][n] = (f32x4){0.f, 0.f, 0.f, 0.f};

  const int lofs_w = w << 10;
#pragma unroll
  for (int it = 0; it < 4; it++) {
    int lo = it * 4096 + lofs_w;
    gl_lds16((const char*)Ah + offA[it], smem + lo);
    gl_lds16((const char*)Al + offA[it], smem + 16384 + lo);
    gl_lds16((const char*)Ah + offB[it], smem + 32768 + lo);
    gl_lds16((const char*)Al + offB[it], smem + 49152 + lo);
  }
  __syncthreads();

  for (int ks = 0; ks < NPT / 64; ks++) {
    if (ks + 1 < NPT / 64) {
      char* nbuf = smem + ((ks + 1) & 1) * 65536;
      size_t kadv = (size_t)(ks + 1) * 128;
#pragma unroll
      for (int it = 0; it < 4; it++) {
        int lo = it * 4096 + lofs_w;
        gl_lds16((const char*)Ah + offA[it] + kadv, nbuf + lo);
        gl_lds16((const char*)Al + offA[it] + kadv, nbuf + 16384 + lo);
        gl_lds16((const char*)Ah + offB[it] + kadv, nbuf + 32768 + lo);
        gl_lds16((const char*)Al + offB[it] + kadv, nbuf + 49152 + lo);
      }
    }
    const char* cbuf = smem + (ks & 1) * 65536;
#pragma unroll
    for (int kk = 0; kk < 2; kk++) {
      bf16x8 bhf[4], blf[4];
#pragma unroll
      for (int n = 0; n < 4; n++) {
        bhf[n] = *(const bf16x8*)(cbuf + 32768 + boff[n][kk]);
        blf[n] = *(const bf16x8*)(cbuf + 49152 + boff[n][kk]);
      }
#pragma unroll
      for (int m = 0; m < 4; m++) {
        bf16x8 ah = *(const bf16x8*)(cbuf + aoff[m][kk]);
        bf16x8 al = *(const bf16x8*)(cbuf + 16384 + aoff[m][kk]);
#pragma unroll
        for (int n = 0; n < 4; n++) {
          acc[m][n] = __builtin_amdgcn_mfma_f32_16x16x32_bf16(al, bhf[n], acc[m][n], 0, 0, 0);
          acc[m][n] = __builtin_amdgcn_mfma_f32_16x16x32_bf16(ah, blf[n], acc[m][n], 0, 0, 0);
          acc[m][n] = __builtin_amdgcn_mfma_f32_16x16x32_bf16(ah, bhf[n], acc[m][n], 0, 0, 0);
        }
      }
    }
    __syncthreads();
  }

  // epilogue: C is symmetric (C = A^2, A sym) -> write transposed with
  // contiguous bf16x4 stores (4 consecutive elements along original rows).
  const int gr0 = by * 128 + wr * 64 + lhi * 4;
  const int gc0 = bx * 128 + wc * 64 + lrow;
#pragma unroll
  for (int m = 0; m < 4; m++) {
    int cb = gr0 + m * 16;
#pragma unroll
    for (int n = 0; n < 4; n++) {
      int gc = gc0 + n * 16;
      bf16x4_t hv, lv;
#pragma unroll
      for (int r = 0; r < 4; r++) {
        float c = acc[m][n][r];
        __bf16 hb = (__bf16)c;
        hv[r] = hb;
        lv[r] = (__bf16)(c - (float)hb);
      }
      *(bf16x4_t*)(Ch + (size_t)gc * NPT + cb) = hv;
      *(bf16x4_t*)(Cl + (size_t)gc * NPT + cb) = lv;
    }
  }
}

// ------------------- X (2048x64 f32) -> XT hi/lo bf16 (64x2048), LDS transpose ---
__global__ __launch_bounds__(256) void pg_splitx(
    const float* __restrict__ X, bf16_t* __restrict__ XTh, bf16_t* __restrict__ XTl)
{
  __shared__ float sX[64][65];
  int t = threadIdx.x;
  int r0 = blockIdx.x * 64;
  for (int u = 0; u < 16; u++) {
    int idx = u * 256 + t;
    int r = idx >> 6, c = idx & 63;
    sX[r][c] = X[(size_t)(r0 + r) * CH + c];
  }
  __syncthreads();
  int c = t >> 6;
  int rr = t & 63;
  for (int cc = c; cc < 64; cc += 4) {
    float v = sX[rr][cc];
    __bf16 hb = (__bf16)v;
    XTh[(size_t)cc * NPT + r0 + rr] = hb;
    XTl[(size_t)cc * NPT + r0 + rr] = (__bf16)(v - (float)hb);
  }
}

// ---------- hd[scale] = E_scale @ X  via MFMA; grid (32 row-blocks, 3 scales) ---
__global__ __launch_bounds__(256) void pg_emm(
    const bf16_t* __restrict__ E05h, const bf16_t* __restrict__ E05l,
    const bf16_t* __restrict__ E2h,  const bf16_t* __restrict__ E2l,
    const bf16_t* __restrict__ E8h,  const bf16_t* __restrict__ E8l,
    const bf16_t* __restrict__ XTh,  const bf16_t* __restrict__ XTl,
    float* __restrict__ hd)
{
  __shared__ __align__(16) char smem[65536];
  const int t = threadIdx.x;
  const int w = t >> 6, l = t & 63;
  const int lrow = l & 15, lhi = l >> 4;
  const int scale = blockIdx.y;
  const bf16_t* Eh = (scale == 0) ? E05h : (scale == 1) ? E2h : E8h;
  const bf16_t* El = (scale == 0) ? E05l : (scale == 1) ? E2l : E8l;
  const int rb = blockIdx.x;

  int offA[2], offB[2];
#pragma unroll
  for (int it = 0; it < 2; it++) {
    int o = it * 4096 + t * 16;
    int r = o >> 7;
    int cb = (o & 127) ^ ((r & 7) << 4);
    offA[it] = (rb * 64 + r) * (NPT * 2) + cb;
    offB[it] = r * (NPT * 2) + cb;
  }
  int aoff[2], boff[4][2];
  {
    int arow = w * 16 + lrow;
#pragma unroll
    for (int kk = 0; kk < 2; kk++) {
      int kb = kk * 64 + lhi * 16;
      aoff[kk] = arow * 128 + (kb ^ ((arow & 7) << 4));
    }
  }
#pragma unroll
  for (int n = 0; n < 4; n++) {
    int brow = n * 16 + lrow;
#pragma unroll
    for (int kk = 0; kk < 2; kk++) {
      int kb = kk * 64 + lhi * 16;
      boff[n][kk] = brow * 128 + (kb ^ ((brow & 7) << 4));
    }
  }

  f32x4 acc[4];
#pragma unroll
  for (int n = 0; n < 4; n++) acc[n] = (f32x4){0.f, 0.f, 0.f, 0.f};

  const int lofs_w = w << 10;
#pragma unroll
  for (int it = 0; it < 2; it++) {
    int lo = it * 4096 + lofs_w;
    gl_lds16((const char*)Eh  + offA[it], smem + lo);
    gl_lds16((const char*)El  + offA[it], smem + 8192 + lo);
    gl_lds16((const char*)XTh + offB[it], smem + 16384 + lo);
    gl_lds16((const char*)XTl + offB[it], smem + 24576 + lo);
  }
  __syncthreads();

  for (int ks = 0; ks < NPT / 64; ks++) {
    if (ks + 1 < NPT / 64) {
      char* nbuf = smem + ((ks + 1) & 1) * 32768;
      size_t kadv = (size_t)(ks + 1) * 128;
#pragma unroll
      for (int it = 0; it < 2; it++) {
        int lo = it * 4096 + lofs_w;
        gl_lds16((const char*)Eh  + offA[it] + kadv, nbuf + lo);
        gl_lds16((const char*)El  + offA[it] + kadv, nbuf + 8192 + lo);
        gl_lds16((const char*)XTh + offB[it] + kadv, nbuf + 16384 + lo);
        gl_lds16((const char*)XTl + offB[it] + kadv, nbuf + 24576 + lo);
      }
    }
    const char* cbuf = smem + (ks & 1) * 32768;
#pragma unroll
    for (int kk = 0; kk < 2; kk++) {
      bf16x8 ah = *(const bf16x8*)(cbuf + aoff[kk]);
      bf16x8 al = *(const bf16x8*)(cbuf + 8192 + aoff[kk]);
#pragma unroll
      for (int n = 0; n < 4; n++) {
        bf16x8 bh = *(const bf16x8*)(cbuf + 16384 + boff[n][kk]);
        bf16x8 bl = *(const bf16x8*)(cbuf + 24576 + boff[n][kk]);
        acc[n] = __builtin_amdgcn_mfma_f32_16x16x32_bf16(al, bh, acc[n], 0, 0, 0);
        acc[n] = __builtin_amdgcn_mfma_f32_16x16x32_bf16(ah, bl, acc[n], 0, 0, 0);
        acc[n] = __builtin_amdgcn_mfma_f32_16x16x32_bf16(ah, bh, acc[n], 0, 0, 0);
      }
    }
    __syncthreads();
  }

  float* Y = hd + (size_t)scale * NPT * CH;
  const int gr0 = rb * 64 + w * 16 + lhi * 4;
#pragma unroll
  for (int n = 0; n < 4; n++) {
    int gc = n * 16 + lrow;
#pragma unroll
    for (int r = 0; r < 4; r++)
      Y[(size_t)(gr0 + r) * CH + gc] = acc[n][r];
  }
}

// ------------------------------------------------------------------- layers ---
__global__ __launch_bounds__(64) void pg_convP(
    const int2* __restrict__ pack, const int* __restrict__ cnt,
    const float* __restrict__ invdeg, const float* __restrict__ h,
    const float* __restrict__ Ws, const float* __restrict__ bs,
    const float* __restrict__ Wn, const float* __restrict__ bn,
    const float* __restrict__ cres, float* __restrict__ out)
{
  __shared__ float sh[64], sp2[64];
  int i = blockIdx.x, t = threadIdx.x;
  sh[t] = h[i * CH + t];
  int n = cnt[i];
  float acc = 0.0f;
  for (int q = 0; q < n; q++) {
    int2 p = pack[i * 64 + q];
    acc += __int_as_float(p.y) * h[(size_t)p.x * CH + t];
  }
  sp2[t] = acc * invdeg[i];
  __syncthreads();
  float a = bs[t] + bn[t] + 0.1f * cres[0] * sh[t];
  for (int k = 0; k < 64; k++) a += sh[k] * Ws[k * CH + t] + sp2[k] * Wn[k * CH + t];
  out[i * CH + t] = a / (1.0f + expf(-a));
}

__global__ __launch_bounds__(64) void pg_difffuse(
    const float* __restrict__ h2, const float* __restrict__ hd,
    const float* __restrict__ dW, const float* __restrict__ db, float* __restrict__ out)
{
  __shared__ float sh[3][64];
  int i = blockIdx.x, t = threadIdx.x;
  for (int s = 0; s < 3; s++) sh[s][t] = hd[(size_t)s * NPT * CH + i * CH + t];
  __syncthreads();
  float a = h2[i * CH + t] + db[t];
  for (int s = 0; s < 3; s++) {
    const float* w = dW + s * CH * CH;
    for (int k = 0; k < 64; k++) a += sh[s][k] * w[k * CH + t];
  }
  out[i * CH + t] = a;
}

// fused tanh-matvec + normalized-Laplacian gather + reaction-diffusion + LN
__global__ __launch_bounds__(64) void pg_tlr(
    const int2* __restrict__ pack, const int* __restrict__ cnt,
    const float* __restrict__ Dis, const float* __restrict__ cvec,
    const float* __restrict__ h3,
    const float* __restrict__ W1, const float* __restrict__ b1,
    const float* __restrict__ W2, const float* __restrict__ b2,
    const float* __restrict__ rdc,
    const float* __restrict__ g, const float* __restrict__ b,
    float* __restrict__ hio)
{
  __shared__ float sh[64], st[64];
  int i = blockIdx.x, t = threadIdx.x;
  sh[t] = h3[i * CH + t];
  __syncthreads();
  float a = b1[t];
  for (int k = 0; k < 64; k++) a += sh[k] * W1[k * CH + t];
  st[t] = tanhf(a);
  int n = cnt[i];
  float accL = 0.0f;
  for (int q = 0; q < n; q++) {
    int2 p = pack[i * 64 + q];
    accL += __int_as_float(p.y) * Dis[p.x] * h3[(size_t)p.x * CH + t];
  }
  float tLv = accL * Dis[i] - cvec[i] * sh[t];
  __syncthreads();
  float react = b2[t];
  for (int k = 0; k < 64; k++) react += st[k] * W2[k * CH + t];
  float x = sh[t] + 0.1f * (rdc[t] * tLv + react) + hio[i * CH + t];
  float s = x;
  for (int off = 1; off < 64; off <<= 1) s += __shfl_xor(s, off);
  float mu = s * (1.0f / 64.0f);
  float d = x - mu;
  float v = d * d;
  for (int off = 1; off < 64; off <<= 1) v += __shfl_xor(v, off);
  v *= (1.0f / 64.0f);
  hio[i * CH + t] = d * (1.0f / sqrtf(v + 1e-5f)) * g[t] + b[t];
}

// ---------------------------------------------------------------- attention ---
__global__ __launch_bounds__(64) void pg_qkv(
    const float* __restrict__ h,
    const float* __restrict__ Wq, const float* __restrict__ bq,
    const float* __restrict__ Wk, const float* __restrict__ bk,
    const float* __restrict__ Wv, const float* __restrict__ bv,
    float* __restrict__ q, float* __restrict__ kb, float* __restrict__ vb)
{
  __shared__ float sh[64];
  int i = blockIdx.x, t = threadIdx.x;
  sh[t] = h[i * CH + t];
  __syncthreads();
  float aq = bq[t], ak = bk[t], avv = bv[t];
  for (int k = 0; k < 64; k++) {
    float x = sh[k];
    aq += x * Wq[k * CH + t];
    ak += x * Wk[k * CH + t];
    avv += x * Wv[k * CH + t];
  }
  q[i * CH + t] = aq;
  kb[i * CH + t] = ak;
  vb[i * CH + t] = avv;
}

// CSR-masked attention + output projection + final linear, fused
__global__ __launch_bounds__(256) void pg_attn_out(
    const float* __restrict__ q, const float* __restrict__ kb, const float* __restrict__ vb,
    const int* __restrict__ nbr, const int* __restrict__ cnt,
    const float* __restrict__ Hc, const float* __restrict__ beta,
    const float* __restrict__ h,
    const float* __restrict__ Wo, const float* __restrict__ bo,
    const float* __restrict__ Wout, const float* __restrict__ bout,
    float* __restrict__ out)
{
  __shared__ float av_s[64];
  int i = blockIdx.x;
  int t = threadIdx.x;
  int head = t >> 6, lane = t & 63;
  float sp_b = logf(1.0f + expf(beta[head]));
  float hci = Hc[i];
  const float* qp = q + i * CH + head * 16;
  float qr[16];
#pragma unroll
  for (int d = 0; d < 16; d++) qr[d] = qp[d];
  int n = cnt[i];
  int K = n + 1;
  float mx = -1e30f, den = 0.0f;
  float vac[16];
#pragma unroll
  for (int d = 0; d < 16; d++) vac[d] = 0.0f;
  for (int m = lane; m < K; m += 64) {
    int j = (m == n) ? i : nbr[i * 64 + m];
    const float* kp = kb + (size_t)j * CH + head * 16;
    float sc = 0.0f;
#pragma unroll
    for (int d = 0; d < 16; d++) sc += qr[d] * kp[d];
    sc *= 0.25f;
    sc -= sp_b * fabsf(hci - Hc[j]);
    float nm = fmaxf(mx, sc);
    float corr = expf(mx - nm);
    float p = expf(sc - nm);
    den = den * corr + p;
    const float* vp = vb + (size_t)j * CH + head * 16;
#pragma unroll
    for (int d = 0; d < 16; d++) vac[d] = vac[d] * corr + p * vp[d];
    mx = nm;
  }
  for (int off = 32; off > 0; off >>= 1) {
    float omx = __shfl_down(mx, off);
    float oden = __shfl_down(den, off);
    float ov[16];
#pragma unroll
    for (int d = 0; d < 16; d++) ov[d] = __shfl_down(vac[d], off);
    float nm = fmaxf(mx, omx);
    float c1 = expf(mx - nm), c2 = expf(omx - nm);
    den = den * c1 + oden * c2;
#pragma unroll
    for (int d = 0; d < 16; d++) vac[d] = vac[d] * c1 + ov[d] * c2;
    mx = nm;
  }
  if (lane == 0) {
    float inv = 1.0f / den;
    for (int d = 0; d < 16; d++) av_s[head * 16 + d] = vac[d] * inv;
  }
  __syncthreads();
  if (t < 64) {
    float a = h[i * CH + t] + bo[t];
    for (int k = 0; k < 64; k++) a += av_s[k] * Wo[k * CH + t];
    float s = a * Wout[t];
    for (int off = 1; off < 64; off <<= 1) s += __shfl_xor(s, off);
    if (t == 0) out[i] = s + bout[0];
  }
}

// ------------------------------------------------------------------- launch ---
extern "C" void kernel_launch(void* const* d_in, const int* in_sizes, int n_in,
                              void* d_out, int out_size, void* d_ws, size_t ws_size,
                              hipStream_t stream)
{
  const float* pos   = (const float*)d_in[0];
  const float* adj   = (const float*)d_in[1];
  const float* Wc1   = (const float*)d_in[2];
  const float* bc1   = (const float*)d_in[3];
  const float* Wc2   = (const float*)d_in[4];
  const float* bc2   = (const float*)d_in[5];
  const float* Win   = (const float*)d_in[6];
  const float* b_in  = (const float*)d_in[7];
  const float* cWs   = (const float*)d_in[8];
  const float* cbs   = (const float*)d_in[9];
  const float* cWn   = (const float*)d_in[10];
  const float* cbn   = (const float*)d_in[11];
  const float* cres  = (const float*)d_in[12];
  const float* dW    = (const float*)d_in[13];
  const float* db    = (const float*)d_in[14];
  const float* rW1   = (const float*)d_in[15];
  const float* rb1   = (const float*)d_in[16];
  const float* rW2   = (const float*)d_in[17];
  const float* rb2   = (const float*)d_in[18];
  const float* rdc   = (const float*)d_in[19];
  const float* lng   = (const float*)d_in[20];
  const float* lnb   = (const float*)d_in[21];
  const float* Wq    = (const float*)d_in[22];
  const float* bq    = (const float*)d_in[23];
  const float* Wk    = (const float*)d_in[24];
  const float* bk    = (const float*)d_in[25];
  const float* Wv    = (const float*)d_in[26];
  const float* bv    = (const float*)d_in[27];
  const float* Wo    = (const float*)d_in[28];
  const float* bo    = (const float*)d_in[29];
  const float* abeta = (const float*)d_in[30];
  const float* Wout  = (const float*)d_in[31];
  const float* bout  = (const float*)d_in[32];

  const size_t NNe = (size_t)NPT * NPT;
  const size_t NC  = (size_t)NPT * CH;
  const size_t P   = NNe * 2;   // bytes per bf16 plane (8 MB)

  char* base = (char*)d_ws;
  bf16_t* E05h = (bf16_t*)(base + 0 * P);
  bf16_t* E05l = (bf16_t*)(base + 1 * P);
  bf16_t* E2h  = (bf16_t*)(base + 2 * P);
  bf16_t* E2l  = (bf16_t*)(base + 3 * P);
  bf16_t* E8h  = (bf16_t*)(base + 4 * P);
  bf16_t* E8l  = (bf16_t*)(base + 5 * P);
  bf16_t* SAh  = (bf16_t*)(base + 6 * P);
  bf16_t* SAl  = (bf16_t*)(base + 7 * P);
  bf16_t* SBh  = (bf16_t*)(base + 8 * P);
  bf16_t* SBl  = (bf16_t*)(base + 9 * P);
  // Horner ping-pong aliases E05/E2 planes (dead until squarings write them)
  float*  M0   = (float*)(base + 0 * P);    // 16 MB = planes 0,1
  float*  M1   = (float*)(base + 2 * P);    // 16 MB = planes 2,3
  bf16_t* XTh  = (bf16_t*)(base + 12 * P);
  bf16_t* XTl  = (bf16_t*)(base + 12 * P + NPT * CH * 2);
  float*  smb  = (float*)(base + 12 * P + 1024 * 1024);

  float* h   = smb;
  float* tA  = h + NC;
  float* tB  = tA + NC;
  float* hd  = tB + NC;        // 3*NC
  float* q   = hd + 3 * NC;
  float* kbf = q + NC;
  float* vbf = kbf + NC;
  float* raw = vbf + NC;
  float* sm  = raw + 8 * NPT;
  float* sumA   = sm;
  float* sumAD  = sm + NPT;
  float* wdeg   = sm + 2 * NPT;
  float* invdeg = sm + 3 * NPT;
  float* Dis    = sm + 4 * NPT;
  float* cvec   = sm + 5 * NPT;
  float* Hc     = sm + 6 * NPT;
  float* stats  = sm + 7 * NPT;
  int*   nbr    = (int*)(sm + 8 * NPT);
  int*   cnt    = nbr + (size_t)NPT * 64;
  int2*  pack   = (int2*)(cnt + NPT);

  size_t need = 12 * P + 1024 * 1024
              + (9 * NC + 16 * (size_t)NPT) * 4
              + (size_t)NPT * 64 * 4 + NPT * 4 + (size_t)NPT * 64 * 8 + 256;
  if (ws_size < need) return;

  // geometry + CSR + features
  pg_geom_csr<<<NPT, 256, 0, stream>>>(pos, adj, raw, Hc, sumA, sumAD, nbr, cnt);
  pg_stats<<<1, 256, 0, stream>>>(raw, sumA, sumAD, stats);
  pg_wdeg<<<NPT, 64, 0, stream>>>(pos, nbr, cnt, stats, pack, wdeg, invdeg, Dis, cvec);
  pg_curv_mlp<<<NPT, 64, 0, stream>>>(pos, raw, stats, Wc1, bc1, Wc2, bc2, Win, b_in, h);

  // T = exp(L/16): global ping-pong Taylor-Horner, XCD column stripes
  pg_hinit<<<NPT, 256, 0, stream>>>(pack, cnt, wdeg, M0);
  float* cur = M0;
  float* nxt = M1;
  for (int k = TDEG - 1; k >= 2; k--) {
    pg_hstep<false><<<NPT, 256, 0, stream>>>(pack, cnt, wdeg, cur, nxt,
                                             1.0f / (SCL * (float)k), nullptr, nullptr);
    float* tmp = cur; cur = nxt; nxt = tmp;
  }
  pg_hstep<true><<<NPT, 256, 0, stream>>>(pack, cnt, wdeg, cur, nullptr,
                                          1.0f / SCL, SAh, SAl);

  // squaring chain (symmetric): exp(L/16) -> ... -> exp(8L)  (7 squarings)
  pg_sq<<<256, 256, 0, stream>>>(SAh, SAl, SBh, SBl);     // L/8
  pg_sq<<<256, 256, 0, stream>>>(SBh, SBl, SAh, SAl);     // L/4
  pg_sq<<<256, 256, 0, stream>>>(SAh, SAl, E05h, E05l);   // L/2
  pg_sq<<<256, 256, 0, stream>>>(E05h, E05l, SBh, SBl);   // L
  pg_sq<<<256, 256, 0, stream>>>(SBh, SBl, E2h, E2l);     // 2L
  pg_sq<<<256, 256, 0, stream>>>(E2h, E2l, SAh, SAl);     // 4L
  pg_sq<<<256, 256, 0, stream>>>(SAh, SAl, E8h, E8l);     // 8L

  // NL layers
  for (int i = 0; i < 4; i++) {
    pg_convP<<<NPT, 64, 0, stream>>>(pack, cnt, invdeg, h,
                                     cWs + i * 4096, cbs + i * 64,
                                     cWn + i * 4096, cbn + i * 64, cres + i, tA);
    float* h3 = tA;
    if ((i & 1) == 0) {
      int j = i >> 1;
      pg_splitx<<<32, 256, 0, stream>>>(tA, XTh, XTl);
      pg_emm<<<dim3(32, 3), 256, 0, stream>>>(E05h, E05l, E2h, E2l, E8h, E8l,
                                              XTh, XTl, hd);
      pg_difffuse<<<NPT, 64, 0, stream>>>(tA, hd, dW + j * 3 * 4096, db + j * 64, tB);
      h3 = tB;
    }
    pg_tlr<<<NPT, 64, 0, stream>>>(pack, cnt, Dis, cvec, h3,
                                   rW1 + i * 4096, rb1 + i * 64,
                                   rW2 + i * 4096, rb2 + i * 64,
                                   rdc + i * 64, lng + i * 64, lnb + i * 64, h);
  }

  // attention + output
  pg_qkv<<<NPT, 64, 0, stream>>>(h, Wq, bq, Wk, bk, Wv, bv, q, kbf, vbf);
  pg_attn_out<<<NPT, 256, 0, stream>>>(q, kbf, vbf, nbr, cnt, Hc, abeta,
                                       h, Wo, bo, Wout, bout, (float*)d_out);
}